// Round 11
// baseline (795.788 us; speedup 1.0000x reference)
//
#include <hip/hip_runtime.h>
#include <stdint.h>

#define TT   12
#define BB   2
#define NN   1024
#define MM   2048
#define TM   24576      // TT*MM
#define DIN  64
#define DH   128
#define DOUT 32
#define CAP  64
#define NSPL 4

typedef __attribute__((ext_vector_type(8))) short short8;
typedef __attribute__((ext_vector_type(4))) short short4v;
typedef __attribute__((ext_vector_type(4))) float f32x4;

#define MFMA(a,b,c) __builtin_amdgcn_mfma_f32_16x16x32_bf16((a),(b),(c),0,0,0)

__device__ __forceinline__ float bf2f(unsigned short u){
  union { uint32_t i; float f; } x; x.i = ((uint32_t)u) << 16; return x.f;
}
__device__ __forceinline__ unsigned short f2bf(float f){
  union { float f; uint32_t i; } x; x.f = f;
  uint32_t u = x.i + 0x7FFFu + ((x.i >> 16) & 1u);   // RNE
  return (unsigned short)(u >> 16);
}
__device__ __forceinline__ float LD(const void* p, size_t i, int mode){
  return mode ? ((const float*)p)[i] : bf2f(((const unsigned short*)p)[i]);
}

// ---------------- sentinel fill (fp32 output) ----------------
__global__ void k_fill(float* __restrict__ out, int n, float val){
  int i = blockIdx.x*blockDim.x + threadIdx.x;
  if(i < n) out[i] = val;
}

// ---------------- input dtype detection (bf16 vs fp32), on x ----------------
__global__ void k_dtype(const unsigned short* __restrict__ x, int* __restrict__ dtf){
  __shared__ int cnt_s;
  if(threadIdx.x==0) cnt_s = 0;
  __syncthreads();
  int c = 0;
  for(int i=threadIdx.x; i<6144; i+=blockDim.x){
    unsigned short h = x[i*2];
    unsigned e = (h >> 7) & 0xFF;
    if(h==0 || (e >= 0x60 && e <= 0x9F)) c++;
  }
  atomicAdd(&cnt_s, c);
  __syncthreads();
  if(threadIdx.x==0) *dtf = (cnt_s > 4000) ? 0 : 1;   // 0=bf16, 1=fp32
}

// ---------------- mask dtype detection: byte-pattern classifier ----------------
// modes: 0=i32, 1=u8, 2=bf16, 3=f32, 4=i64, 5=f64
__global__ void k_detect(const unsigned char* __restrict__ p, int* __restrict__ flag){
  __shared__ int pres_s, ge2_s;
  if(threadIdx.x==0){ pres_s=0; ge2_s=0; }
  __syncthreads();
  int pres=0, ge2=0;
  for(int i=threadIdx.x; i<24576; i+=blockDim.x){
    unsigned v = p[i];
    if(v){ pres |= 1 << (i & 7); if(v >= 2u) ge2 = 1; }
  }
  if(pres) atomicOr(&pres_s, pres);
  if(ge2)  atomicOr(&ge2_s, 1);
  __syncthreads();
  if(threadIdx.x==0){
    int pr = pres_s, g2 = ge2_s, mode;
    if(!g2){
      if((pr & ~0x01) == 0)      mode = 4;   // i64
      else if((pr & ~0x11) == 0) mode = 0;   // i32
      else                       mode = 1;   // u8
    } else {
      if((pr & ~0xC0) == 0)      mode = 5;   // f64
      else if((pr & ~0xCC) == 0) mode = 3;   // f32
      else                       mode = 2;   // bf16
    }
    *flag = mode;
  }
}

// m[t][node] = ego_mask[b][t][n] as 0/1 float; zero cnt and nact
__global__ void k_mask(const void* __restrict__ egom, const int* __restrict__ flag,
                       float* __restrict__ m, int* __restrict__ cnt,
                       int* __restrict__ nact){
  int idx = blockIdx.x*blockDim.x + threadIdx.x;   // < TM
  int t = idx / MM, node = idx % MM;
  int b = node / NN, n = node % NN;
  int src = (b*TT + t)*NN + n;
  int mode = *flag;
  int v;
  if(mode==0)      v = ((const int*)egom)[src] != 0;
  else if(mode==1) v = ((const unsigned char*)egom)[src] != 0;
  else if(mode==2) v = ((const unsigned short*)egom)[src] != 0;
  else if(mode==3) v = ((const float*)egom)[src] != 0.f;
  else if(mode==4) v = ((const long long*)egom)[src] != 0;
  else             v = ((const double*)egom)[src] != 0.0;
  m[idx] = v ? 1.f : 0.f;
  cnt[idx] = 0;
  if(idx < TT) nact[idx] = 0;
}

// active-key index build (order-independent math downstream)
__global__ void k_compact(const float* __restrict__ m, int* __restrict__ nact,
                          int* __restrict__ aidx){
  int idx = blockIdx.x*blockDim.x + threadIdx.x;   // < TM
  int t = idx / MM, node = idx % MM;
  if(m[idx] != 0.f){
    int s = atomicAdd(&nact[t], 1);
    aidx[(size_t)t*MM + s] = node;
  }
}

// ---------------- convert x to bf16 workspace buffer ----------------
__global__ void k_conv(const void* __restrict__ x, const int* __restrict__ dtf,
                       unsigned short* __restrict__ xb){
  int i0 = (blockIdx.x*blockDim.x + threadIdx.x)*8;
  if(i0 >= TM*DIN) return;
  if(*dtf){
    const float4* xf = (const float4*)((const float*)x + i0);
    float4 a = xf[0], b = xf[1];
    short8 o;
    o[0]=(short)f2bf(a.x); o[1]=(short)f2bf(a.y); o[2]=(short)f2bf(a.z); o[3]=(short)f2bf(a.w);
    o[4]=(short)f2bf(b.x); o[5]=(short)f2bf(b.y); o[6]=(short)f2bf(b.z); o[7]=(short)f2bf(b.w);
    *(short8*)(xb + i0) = o;
  } else {
    *(short8*)(xb + i0) = *(const short8*)((const unsigned short*)x + i0);
  }
}

// ---------------- weight prep: transposes + folded weights/biases ----------------
__global__ void k_prepw(
  const void* __restrict__ w1, const void* __restrict__ w2,
  const void* __restrict__ qw, const void* __restrict__ kw, const void* __restrict__ vw,
  const void* __restrict__ qb0, const void* __restrict__ kb0, const void* __restrict__ vb0,
  const void* __restrict__ ow, const void* __restrict__ ob,
  const void* __restrict__ fw, const void* __restrict__ fb,
  const void* __restrict__ tw, const void* __restrict__ tb,
  const void* __restrict__ b1, const void* __restrict__ b2,
  const int* __restrict__ dtf,
  unsigned short* __restrict__ W1t, unsigned short* __restrict__ W2t,
  unsigned short* __restrict__ Wqt, unsigned short* __restrict__ Wkt,
  unsigned short* __restrict__ Wvt, unsigned short* __restrict__ Wct,
  float* __restrict__ qbf, float* __restrict__ kbf, float* __restrict__ vbf,
  float* __restrict__ bcf, float* __restrict__ b1f, float* __restrict__ b2f)
{
  const int md = *dtf;
  int id = blockIdx.x*blockDim.x + threadIdx.x;
  if(id < 8192){ int n=id/64, k2=id%64; W1t[n*64+k2]=f2bf(LD(w1,(size_t)k2*128+n,md)); return; }
  id -= 8192;
  if(id < 16384){ int n=id/128,k2=id%128; W2t[n*128+k2]=f2bf(LD(w2,(size_t)k2*128+n,md)); return; }
  id -= 16384;
  if(id < 16384){ int n=id/128,k2=id%128; Wqt[n*128+k2]=f2bf(LD(qw,(size_t)k2*128+n,md)); return; }
  id -= 16384;
  if(id < 16384){ int n=id/128,k2=id%128; Wkt[n*128+k2]=f2bf(LD(kw,(size_t)k2*128+n,md)); return; }
  id -= 16384;
  if(id < 16384){ int n=id/128,k2=id%128; Wvt[n*128+k2]=f2bf(LD(vw,(size_t)k2*128+n,md)); return; }
  id -= 16384;
  if(id < 4096){  // Wc = o_w @ fc_w, stored [oc][c]
    int oc=id/128, c=id%128; float s=0.f;
    for(int r=0;r<128;r++) s += LD(ow,(size_t)c*128+r,md)*LD(fw,(size_t)r*32+oc,md);
    Wct[oc*128+c]=f2bf(s); return;
  }
  id -= 4096;
  if(id < 32){    // bc = o_b @ fc_w + fc_b
    float s = LD(fb,id,md);
    for(int r=0;r<128;r++) s += LD(ob,r,md)*LD(fw,(size_t)r*32+id,md);
    bcf[id]=s; return;
  }
  id -= 32;
  if(id < 4608){  // per-t fused QKV bias: b + t_vec @ W[128:144]
    int which = id/1536, rem=id%1536, t=rem/128, n=rem%128;
    const void* W  = which==0?qw:(which==1?kw:vw);
    const void* Bs = which==0?qb0:(which==1?kb0:vb0);
    float s = LD(Bs,n,md);
    for(int d=0;d<16;d++){
      float tv = sinf((float)t*LD(tw,d,md) + LD(tb,d,md));
      s += tv * LD(W,(size_t)(128+d)*128+n,md);
    }
    float* dst = which==0?qbf:(which==1?kbf:vbf);
    dst[t*128+n]=s; return;
  }
  id -= 4608;
  if(id < 256){   // GCN biases to fp32
    if(id<128) b1f[id] = LD(b1,id,md);
    else       b2f[id-128] = LD(b2,id-128,md);
    return;
  }
}

// ---------------- edge-list build: one pass over A ----------------
__global__ __launch_bounds__(256) void k_edges(const void* __restrict__ A,
    const int* __restrict__ dtf, const float* __restrict__ m,
    int* __restrict__ cnt, int* __restrict__ edges){
  int id = blockIdx.x*blockDim.x + threadIdx.x;   // TM*64 threads
  int seg = id & 63; int row = id >> 6;           // row = t*MM + j
  int t = row / MM, j = row % MM;
  if(m[row]==0.f) return;                         // masked source rows are dead
  int* cb = cnt + (size_t)t*MM;
  int* eb = edges + (size_t)t*MM*CAP;
  if(*dtf){   // fp32 adjacency
    const float4* p4 = (const float4*)((const float*)A + (size_t)row*MM + seg*32);
    #pragma unroll
    for(int u=0;u<8;u++){
      float4 v = p4[u];
      float wd[4]={v.x,v.y,v.z,v.w};
      #pragma unroll
      for(int q=0;q<4;q++){
        int ib = seg*32 + u*4 + q;
        if(wd[q]!=0.f){ int s=atomicAdd(&cb[ib],1); if(s<CAP) eb[(size_t)ib*CAP+s]=j; }
      }
    }
  } else {    // bf16 adjacency
    const uint4* p4 = (const uint4*)((const unsigned short*)A + (size_t)row*MM + seg*32);
    #pragma unroll
    for(int u=0;u<4;u++){
      uint4 v = p4[u];
      unsigned wd[4]={v.x,v.y,v.z,v.w};
      #pragma unroll
      for(int q=0;q<4;q++){
        int ib = seg*32 + u*8 + q*2;
        if(wd[q] & 0xFFFFu){ int s=atomicAdd(&cb[ib],1);   if(s<CAP) eb[(size_t)ib*CAP+s]=j; }
        if(wd[q] >> 16)    { int s=atomicAdd(&cb[ib+1],1); if(s<CAP) eb[(size_t)(ib+1)*CAP+s]=j; }
      }
    }
  }
}

// ---------------- dense GEMM  g = X @ Wt^T   (Wt is [128][KD], k-contiguous) ----------------
template<int KD>
__global__ __launch_bounds__(256) void k_gemm_f32(const unsigned short* __restrict__ X,
    const unsigned short* __restrict__ Wt, float* __restrict__ g)
{
  constexpr int KS = KD/32;
  const int tid=threadIdx.x, wv=tid>>6, lane=tid&63, l15=lane&15, quad=lane>>4;
  const int r0 = blockIdx.x*64 + (wv>>1)*32;
  const int c0 = (wv&1)*64;
  short8 bf[KS][4];
  #pragma unroll
  for(int kk=0;kk<KS;kk++)
    #pragma unroll
    for(int nt=0;nt<4;nt++)
      bf[kk][nt] = *(const short8*)(Wt + (size_t)(c0+nt*16+l15)*KD + kk*32 + quad*8);
  f32x4 z = {0.f,0.f,0.f,0.f};
  f32x4 acc[2][4];
  #pragma unroll
  for(int i=0;i<2;i++){ acc[i][0]=z; acc[i][1]=z; acc[i][2]=z; acc[i][3]=z; }
  #pragma unroll
  for(int kk=0;kk<KS;kk++){
    short8 a0 = *(const short8*)(X + (size_t)(r0+l15)*KD    + kk*32 + quad*8);
    short8 a1 = *(const short8*)(X + (size_t)(r0+16+l15)*KD + kk*32 + quad*8);
    #pragma unroll
    for(int nt=0;nt<4;nt++){
      acc[0][nt]=MFMA(a0,bf[kk][nt],acc[0][nt]);
      acc[1][nt]=MFMA(a1,bf[kk][nt],acc[1][nt]);
    }
  }
  #pragma unroll
  for(int mt=0;mt<2;mt++)
    #pragma unroll
    for(int nt=0;nt<4;nt++){
      int col = c0+nt*16+l15;
      #pragma unroll
      for(int r=0;r<4;r++){
        int row = r0 + mt*16 + quad*4 + r;
        g[(size_t)row*DH + col] = acc[mt][nt][r];
      }
    }
}

// ---------------- sparse GCN aggregation + epilogue -> h (bf16) ----------------
__global__ __launch_bounds__(256) void k_gather(const float* __restrict__ g,
    const int* __restrict__ edges, const int* __restrict__ cnt,
    const float* __restrict__ m, const float* __restrict__ bias,
    unsigned short* __restrict__ h)
{
  int wv = threadIdx.x>>6, lane = threadIdx.x&63;
  int gi = blockIdx.x*4 + wv;           // global row, < TM
  int t = gi / MM;
  float a0=0.f, a1=0.f;
  int cn = cnt[gi]; if(cn>CAP) cn=CAP;
  const int* eb = edges + (size_t)gi*CAP;
  for(int e=0;e<cn;e++){
    int j = eb[e];
    float nj = rsqrtf((float)cnt[(size_t)t*MM+j] + 1.f);
    const float* gr = g + ((size_t)t*MM + j)*DH;
    a0 += nj*gr[lane]; a1 += nj*gr[64+lane];
  }
  float ni = (m[gi]!=0.f) ? rsqrtf((float)cnt[gi] + 1.f) : 0.f;
  const float* gs = g + (size_t)gi*DH;
  float h0 = ni*(a0 + ni*gs[lane])    + bias[lane];
  float h1 = ni*(a1 + ni*gs[64+lane]) + bias[64+lane];
  h0 = h0>0.f?h0:0.f; h1 = h1>0.f?h1:0.f;
  h[(size_t)gi*DH + lane]      = f2bf(h0);
  h[(size_t)gi*DH + 64 + lane] = f2bf(h1);
}

// ---------------- Q/K/V GEMMs: all three row-major now ----------------
__global__ __launch_bounds__(256) void k_gemm_qkv(const unsigned short* __restrict__ X,
    const unsigned short* __restrict__ Wq, const unsigned short* __restrict__ Wk,
    const unsigned short* __restrict__ Wv,
    const float* __restrict__ qb, const float* __restrict__ kb, const float* __restrict__ vb,
    unsigned short* __restrict__ Qo, unsigned short* __restrict__ Ko,
    unsigned short* __restrict__ Vr)
{
  const int which = blockIdx.z;
  const unsigned short* Wt = which==0?Wq:(which==1?Wk:Wv);
  const float* bias = which==0?qb:(which==1?kb:vb);
  unsigned short* o = which==0?Qo:(which==1?Ko:Vr);
  const int tid=threadIdx.x, wv=tid>>6, lane=tid&63, l15=lane&15, quad=lane>>4;
  const int r0 = blockIdx.x*64 + (wv>>1)*32;
  const int c0 = (wv&1)*64;
  short8 bf[4][4];
  #pragma unroll
  for(int kk=0;kk<4;kk++)
    #pragma unroll
    for(int nt=0;nt<4;nt++)
      bf[kk][nt] = *(const short8*)(Wt + (size_t)(c0+nt*16+l15)*DH + kk*32 + quad*8);
  f32x4 z = {0.f,0.f,0.f,0.f};
  f32x4 acc[2][4];
  #pragma unroll
  for(int i=0;i<2;i++){ acc[i][0]=z; acc[i][1]=z; acc[i][2]=z; acc[i][3]=z; }
  #pragma unroll
  for(int kk=0;kk<4;kk++){
    short8 a0 = *(const short8*)(X + (size_t)(r0+l15)*DH    + kk*32 + quad*8);
    short8 a1 = *(const short8*)(X + (size_t)(r0+16+l15)*DH + kk*32 + quad*8);
    #pragma unroll
    for(int nt=0;nt<4;nt++){
      acc[0][nt]=MFMA(a0,bf[kk][nt],acc[0][nt]);
      acc[1][nt]=MFMA(a1,bf[kk][nt],acc[1][nt]);
    }
  }
  const int t = (blockIdx.x*64)/MM;
  #pragma unroll
  for(int mt=0;mt<2;mt++)
    #pragma unroll
    for(int nt=0;nt<4;nt++){
      int col = c0+nt*16+l15;
      float bb = bias[t*DH+col];
      #pragma unroll
      for(int r=0;r<4;r++){
        int row = r0 + mt*16 + quad*4 + r;
        o[(size_t)row*DH + col] = f2bf(acc[mt][nt][r] + bb);
      }
    }
}

// ---------------- repack: gather active K rows -> Kc; gather+transpose V -> Vtc ----------------
// grid (MM/64, TT), 64 threads (1 wave). Pads [nact, ceil64(nact)) with zeros.
__global__ __launch_bounds__(64) void k_repack(const unsigned short* __restrict__ K,
    const unsigned short* __restrict__ Vr, const int* __restrict__ aidx,
    const int* __restrict__ nact, unsigned short* __restrict__ Kc,
    unsigned short* __restrict__ Vtc)
{
  __shared__ unsigned short tl[64][130];
  const int i0 = blockIdx.x*64, t = blockIdx.y, l = threadIdx.x;
  const int na = nact[t];
  const int padded = (na + 63) & ~63;
  if(i0 >= padded) return;
  for(int r=0;r<64;r++){
    int i = i0 + r;
    uint32_t kv = 0, vv = 0;
    if(i < na){
      int node = aidx[(size_t)t*MM + i];
      kv = *(const uint32_t*)(K  + ((size_t)t*MM + node)*DH + 2*l);
      vv = *(const uint32_t*)(Vr + ((size_t)t*MM + node)*DH + 2*l);
    }
    *(uint32_t*)(Kc + ((size_t)t*MM + i)*DH + 2*l) = kv;
    tl[r][2*l]   = (unsigned short)(vv & 0xFFFFu);
    tl[r][2*l+1] = (unsigned short)(vv >> 16);
  }
  __syncthreads();
  for(int c=0;c<DH;c++)
    Vtc[(size_t)t*DH*MM + (size_t)c*MM + i0 + l] = tl[l][c];
}

// ---------------- attention, key-split over COMPACT keys ----------------
// grid (MM/16, TT, NSPL), 64 threads.
__global__ __launch_bounds__(64) void k_attn_split(
  const unsigned short* __restrict__ Q, const unsigned short* __restrict__ Kc,
  const unsigned short* __restrict__ Vtc, const int* __restrict__ nact,
  float* __restrict__ part, float* __restrict__ lpart)
{
  __shared__ short Pl[16][72];
  const int lane=threadIdx.x&63, l15=lane&15, quad=lane>>4;
  const int t = blockIdx.y;
  const int qbase = blockIdx.x*16;
  const int z = blockIdx.z;
  const float scale = 0.088388347648318447f;  // 1/sqrt(128)
  const int na = nact[t];
  const int nkt = (na + 63) >> 6;
  const int chunk = (nkt + NSPL - 1) / NSPL;
  const int kt0 = z*chunk;
  int kt1 = kt0 + chunk; if(kt1 > nkt) kt1 = nkt;

  short8 bq[4];
  #pragma unroll
  for(int kk=0;kk<4;kk++)
    bq[kk] = *(const short8*)(Q + ((size_t)t*MM + qbase + l15)*DH + kk*32 + quad*8);

  f32x4 zz = {0.f,0.f,0.f,0.f};
  f32x4 accPV[8];
  #pragma unroll
  for(int i=0;i<8;i++) accPV[i]=zz;
  float l_run = 0.f;

  for(int kt=kt0; kt<kt1; kt++){
    const int key0 = kt*64;
    // S^T = Kc · Q^T  (D[m=key_local][n=q])
    #pragma unroll
    for(int mt=0;mt<4;mt++){
      f32x4 s = zz;
      const unsigned short* Krow = Kc + ((size_t)t*MM + key0 + mt*16 + l15)*DH;
      #pragma unroll
      for(int kk=0;kk<4;kk++){
        short8 ak = *(const short8*)(Krow + kk*32 + quad*8);
        s = MFMA(ak, bq[kk], s);
      }
      short4v pk;
      #pragma unroll
      for(int r=0;r<4;r++){
        float sv = fminf(fmaxf(s[r]*scale, -15.f), 15.f);
        float valid = (key0 + mt*16 + quad*4 + r < na) ? 1.f : 0.f;
        float p = __expf(sv) * valid;
        pk[r] = (short)f2bf(p);
        l_run += bf2f((unsigned short)pk[r]);   // denominator == what PV consumes
      }
      *(short4v*)&Pl[l15][mt*16 + quad*4] = pk;
    }
    // PV accumulate (A-op = P from LDS, B-op = Vtc rows)
    #pragma unroll
    for(int kk=0;kk<2;kk++){
      short8 ap = *(const short8*)&Pl[l15][kk*32 + quad*8];
      const unsigned short* Vb = Vtc + (size_t)t*DH*MM + key0 + kk*32 + quad*8;
      #pragma unroll
      for(int nt=0;nt<8;nt++){
        short8 bv = *(const short8*)(Vb + (size_t)(nt*16 + l15)*MM);
        accPV[nt] = MFMA(ap, bv, accPV[nt]);
      }
    }
  }
  // per-q denominator partial: sum the 4 quads (lanes sharing l15)
  l_run += __shfl_xor(l_run, 16, 64);
  l_run += __shfl_xor(l_run, 32, 64);

  // store fp32 partials (zeros for empty kt ranges -- fin sums unconditionally)
  const size_t pbase = (size_t)(z*TT + t)*MM + qbase;
  #pragma unroll
  for(int nt=0;nt<8;nt++)
    #pragma unroll
    for(int r=0;r<4;r++)
      part[(pbase + quad*4 + r)*128 + nt*16 + l15] = accPV[nt][r];
  if(lane < 16) lpart[pbase + lane] = l_run;
}

// ---------------- attention combine + final projection ----------------
__global__ __launch_bounds__(64) void k_attn_fin(
  const float* __restrict__ part, const float* __restrict__ lpart,
  const float* __restrict__ m, const unsigned short* __restrict__ Wct,
  const float* __restrict__ bc, float* __restrict__ out)
{
  __shared__ short Al[16][136];
  __shared__ float lbuf[16];
  const int lane=threadIdx.x&63, l15=lane&15, quad=lane>>4;
  const int t = blockIdx.y, qbase = blockIdx.x*16;
  f32x4 acc4[8];
  f32x4 zz = {0.f,0.f,0.f,0.f};
  #pragma unroll
  for(int i=0;i<8;i++) acc4[i]=zz;
  #pragma unroll
  for(int s=0;s<NSPL;s++){
    const float* pb = part + ((size_t)(s*TT + t)*MM + qbase)*128;
    #pragma unroll
    for(int i=0;i<8;i++){
      int flat = i*64 + lane;         // 0..511
      int q = flat >> 5, c4 = (flat & 31) << 2;
      acc4[i] += *(const f32x4*)(pb + q*128 + c4);
    }
  }
  if(lane < 16){
    float ls = 0.f;
    #pragma unroll
    for(int s=0;s<NSPL;s++) ls += lpart[(size_t)(s*TT + t)*MM + qbase + lane];
    lbuf[lane] = ls;
  }
  #pragma unroll
  for(int i=0;i<8;i++){
    int flat = i*64 + lane;
    int q = flat >> 5, c4 = (flat & 31) << 2;
    short4v pk;
    #pragma unroll
    for(int r=0;r<4;r++){
      float av = fminf(fmaxf(acc4[i][r], -1e30f), 1e30f);
      pk[r] = (short)f2bf(av);
    }
    *(short4v*)&Al[q][c4] = pk;
  }
  __syncthreads();

  const float* mrow = m + (size_t)t*MM;
  const float lsv = lbuf[l15];
  const float linv = (lsv > 0.f) ? 1.f/lsv : 0.f;
  const int node = qbase + l15;
  const float mq = mrow[node];
  #pragma unroll
  for(int mt2=0;mt2<2;mt2++){
    f32x4 d = zz;
    #pragma unroll
    for(int kk=0;kk<4;kk++){
      short8 aw = *(const short8*)(Wct + (size_t)(mt2*16+l15)*DH + kk*32 + quad*8);
      short8 bl = *(const short8*)&Al[l15][kk*32 + quad*8];
      d = MFMA(aw, bl, d);
    }
    f32x4 bcv = *(const f32x4*)(bc + mt2*16 + quad*4);
    f32x4 o4;
    #pragma unroll
    for(int r=0;r<4;r++){
      float val = d[r]*linv + bcv[r];
      o4[r] = (mq != 0.f) ? val : 0.f;
    }
    *(f32x4*)(out + (size_t)node*(TT*DOUT) + (size_t)t*DOUT + mt2*16 + quad*4) = o4;
  }
}

// ---------------- launch ----------------
extern "C" void kernel_launch(void* const* d_in, const int* in_sizes, int n_in,
                              void* d_out, int out_size, void* d_ws, size_t ws_size,
                              hipStream_t stream)
{
  float* outp = (float*)d_out;   // reference output dtype is float32
  static const int EXP[19] = {1572864,50331648,24576,8192,128,16384,128,16,16,
                              18432,128,18432,128,18432,128,16384,128,4096,32};
  bool ok = (n_in >= 19) && (out_size == 786432);
  if(ok) for(int i=0;i<19;i++) if(in_sizes[i] != EXP[i]) { ok = false; break; }
  if(!ok){
    k_fill<<<(out_size+255)/256,256,0,stream>>>(outp, out_size, 1000.f);
    return;
  }
  const void* x   = d_in[0];
  const void* A   = d_in[1];
  const void* eg  = d_in[2];
  const void* w1  = d_in[3];
  const void* b1  = d_in[4];
  const void* w2  = d_in[5];
  const void* b2  = d_in[6];
  const void* tw  = d_in[7];
  const void* tb  = d_in[8];
  const void* qw  = d_in[9];
  const void* qb0 = d_in[10];
  const void* kw  = d_in[11];
  const void* kb0 = d_in[12];
  const void* vw  = d_in[13];
  const void* vb0 = d_in[14];
  const void* ow  = d_in[15];
  const void* ob  = d_in[16];
  const void* fw  = d_in[17];
  const void* fb  = d_in[18];

  char* w = (char*)d_ws;
  size_t off = 0;
  auto alloc = [&](size_t sz)->char*{
    char* p = w + off; off = (off + sz + 255) & ~(size_t)255; return p; };
  int*   flag  = (int*)  alloc(4);
  int*   dtf   = (int*)  alloc(4);
  int*   nactb = (int*)  alloc(TT*4);
  float* mbuf  = (float*)alloc((size_t)TM*4);
  int*   cnt   = (int*)  alloc((size_t)TM*4);
  int*   aidx  = (int*)  alloc((size_t)TM*4);
  int*   edges = (int*)  alloc((size_t)TM*CAP*4);
  float* g     = (float*)alloc((size_t)TM*DH*4);   // reused as Qb+Kb after 2nd gather
  unsigned short* h   = (unsigned short*)alloc((size_t)TM*DH*2);
  unsigned short* xb  = (unsigned short*)alloc((size_t)TM*DIN*2);
  unsigned short* Vr  = (unsigned short*)alloc((size_t)TM*DH*2);
  unsigned short* Kc  = (unsigned short*)alloc((size_t)TM*DH*2);
  unsigned short* Vtc = (unsigned short*)alloc((size_t)TT*DH*MM*2);
  unsigned short* W1t = (unsigned short*)alloc(DH*DIN*2);
  unsigned short* W2t = (unsigned short*)alloc(DH*DH*2);
  unsigned short* Wqt = (unsigned short*)alloc(DH*DH*2);
  unsigned short* Wkt = (unsigned short*)alloc(DH*DH*2);
  unsigned short* Wvt = (unsigned short*)alloc(DH*DH*2);
  unsigned short* Wct = (unsigned short*)alloc(DOUT*DH*2);
  float* qbf = (float*)alloc(TT*DH*4);
  float* kbf = (float*)alloc(TT*DH*4);
  float* vbf = (float*)alloc(TT*DH*4);
  float* bcf = (float*)alloc(DOUT*4);
  float* b1f = (float*)alloc(DH*4);
  float* b2f = (float*)alloc(DH*4);
  float* part  = (float*)alloc((size_t)NSPL*TM*DH*4);
  float* lpart = (float*)alloc((size_t)NSPL*TM*4);
  if(off > ws_size){
    k_fill<<<(out_size+255)/256,256,0,stream>>>(outp, out_size, 500.f);
    return;
  }

  unsigned short* Qb = (unsigned short*)g;                       // TM*DH*2 bytes
  unsigned short* Kb = (unsigned short*)((char*)g + (size_t)TM*DH*2);

  k_dtype<<<1,256,0,stream>>>((const unsigned short*)x, dtf);
  k_detect<<<1,256,0,stream>>>((const unsigned char*)eg, flag);
  k_mask<<<TM/256,256,0,stream>>>(eg, flag, mbuf, cnt, nactb);
  k_compact<<<TM/256,256,0,stream>>>(mbuf, nactb, aidx);
  k_conv<<<(TM*DIN/8+255)/256,256,0,stream>>>(x, dtf, xb);
  k_prepw<<<(82720+255)/256,256,0,stream>>>(w1,w2,qw,kw,vw,qb0,kb0,vb0,ow,ob,fw,fb,tw,tb,
                                            b1,b2,dtf,
                                            W1t,W2t,Wqt,Wkt,Wvt,Wct,qbf,kbf,vbf,bcf,b1f,b2f);
  k_edges<<<TM*64/256,256,0,stream>>>(A, dtf, mbuf, cnt, edges);
  k_gemm_f32<DIN><<<TM/64,256,0,stream>>>(xb, W1t, g);
  k_gather<<<TM/4,256,0,stream>>>(g, edges, cnt, mbuf, b1f, h);
  k_gemm_f32<DH><<<TM/64,256,0,stream>>>(h, W2t, g);
  k_gather<<<TM/4,256,0,stream>>>(g, edges, cnt, mbuf, b2f, h);
  k_gemm_qkv<<<dim3(TM/64,1,3),256,0,stream>>>(h, Wqt,Wkt,Wvt, qbf,kbf,vbf, Qb,Kb,Vr);
  k_repack<<<dim3(MM/64,TT),64,0,stream>>>(Kb, Vr, aidx, nactb, Kc, Vtc);
  k_attn_split<<<dim3(MM/16,TT,NSPL),64,0,stream>>>(Qb, Kc, Vtc, nactb, part, lpart);
  k_attn_fin<<<dim3(MM/16,TT),64,0,stream>>>(part, lpart, mbuf, Wct, bcf, outp);
}

// Round 12
// 651.733 us; speedup vs baseline: 1.2210x; 1.2210x over previous
//
#include <hip/hip_runtime.h>
#include <stdint.h>

#define TT   12
#define BB   2
#define NN   1024
#define MM   2048
#define TM   24576      // TT*MM
#define DIN  64
#define DH   128
#define DOUT 32
#define CAP  64
#define NSPL 4

typedef __attribute__((ext_vector_type(8))) short short8;
typedef __attribute__((ext_vector_type(4))) short short4v;
typedef __attribute__((ext_vector_type(4))) float f32x4;

#define MFMA(a,b,c) __builtin_amdgcn_mfma_f32_16x16x32_bf16((a),(b),(c),0,0,0)

__device__ __forceinline__ float bf2f(unsigned short u){
  union { uint32_t i; float f; } x; x.i = ((uint32_t)u) << 16; return x.f;
}
__device__ __forceinline__ unsigned short f2bf(float f){
  union { float f; uint32_t i; } x; x.f = f;
  uint32_t u = x.i + 0x7FFFu + ((x.i >> 16) & 1u);   // RNE
  return (unsigned short)(u >> 16);
}
__device__ __forceinline__ float LD(const void* p, size_t i, int mode){
  return mode ? ((const float*)p)[i] : bf2f(((const unsigned short*)p)[i]);
}

// ---------------- sentinel fill (fp32 output) ----------------
__global__ void k_fill(float* __restrict__ out, int n, float val){
  int i = blockIdx.x*blockDim.x + threadIdx.x;
  if(i < n) out[i] = val;
}

// ---------------- input dtype detection; also zero nact ----------------
__global__ void k_dtype(const unsigned short* __restrict__ x, int* __restrict__ dtf,
                        int* __restrict__ nact){
  __shared__ int cnt_s;
  if(threadIdx.x==0) cnt_s = 0;
  if(threadIdx.x < TT) nact[threadIdx.x] = 0;
  __syncthreads();
  int c = 0;
  for(int i=threadIdx.x; i<6144; i+=blockDim.x){
    unsigned short h = x[i*2];
    unsigned e = (h >> 7) & 0xFF;
    if(h==0 || (e >= 0x60 && e <= 0x9F)) c++;
  }
  atomicAdd(&cnt_s, c);
  __syncthreads();
  if(threadIdx.x==0) *dtf = (cnt_s > 4000) ? 0 : 1;   // 0=bf16, 1=fp32
}

// ---------------- mask dtype detection: byte-pattern classifier ----------------
// modes: 0=i32, 1=u8, 2=bf16, 3=f32, 4=i64, 5=f64
__global__ void k_detect(const unsigned char* __restrict__ p, int* __restrict__ flag){
  __shared__ int pres_s, ge2_s;
  if(threadIdx.x==0){ pres_s=0; ge2_s=0; }
  __syncthreads();
  int pres=0, ge2=0;
  for(int i=threadIdx.x; i<24576; i+=blockDim.x){
    unsigned v = p[i];
    if(v){ pres |= 1 << (i & 7); if(v >= 2u) ge2 = 1; }
  }
  if(pres) atomicOr(&pres_s, pres);
  if(ge2)  atomicOr(&ge2_s, 1);
  __syncthreads();
  if(threadIdx.x==0){
    int pr = pres_s, g2 = ge2_s, mode;
    if(!g2){
      if((pr & ~0x01) == 0)      mode = 4;   // i64
      else if((pr & ~0x11) == 0) mode = 0;   // i32
      else                       mode = 1;   // u8
    } else {
      if((pr & ~0xC0) == 0)      mode = 5;   // f64
      else if((pr & ~0xCC) == 0) mode = 3;   // f32
      else                       mode = 2;   // bf16
    }
    *flag = mode;
  }
}

// m[t][node] = ego_mask[b][t][n] as 0/1 float; zero cnt; wave-aggregated
// active-index compaction (1 atomic per wave instead of 1 per active node --
// round-11's k_compact burned 141 us on 12-address atomic serialization).
__global__ void k_mask(const void* __restrict__ egom, const int* __restrict__ flag,
                       float* __restrict__ m, int* __restrict__ cnt,
                       int* __restrict__ nact, int* __restrict__ aidx){
  int idx = blockIdx.x*blockDim.x + threadIdx.x;   // < TM
  int t = idx / MM, node = idx % MM;               // wave = 64 consecutive nodes, same t
  int b = node / NN, n = node % NN;
  int src = (b*TT + t)*NN + n;
  int mode = *flag;
  int v;
  if(mode==0)      v = ((const int*)egom)[src] != 0;
  else if(mode==1) v = ((const unsigned char*)egom)[src] != 0;
  else if(mode==2) v = ((const unsigned short*)egom)[src] != 0;
  else if(mode==3) v = ((const float*)egom)[src] != 0.f;
  else if(mode==4) v = ((const long long*)egom)[src] != 0;
  else             v = ((const double*)egom)[src] != 0.0;
  m[idx] = v ? 1.f : 0.f;
  cnt[idx] = 0;
  // wave-ballot compaction
  unsigned long long bal = __ballot(v != 0);
  int lane = threadIdx.x & 63;
  int base = 0;
  if(lane == 0 && bal) base = atomicAdd(&nact[t], __popcll(bal));
  base = __shfl(base, 0, 64);
  if(v){
    int pfx = __popcll(bal & ((1ULL << lane) - 1ULL));
    aidx[(size_t)t*MM + base + pfx] = node;
  }
}

// ---------------- convert x to bf16 workspace buffer ----------------
__global__ void k_conv(const void* __restrict__ x, const int* __restrict__ dtf,
                       unsigned short* __restrict__ xb){
  int i0 = (blockIdx.x*blockDim.x + threadIdx.x)*8;
  if(i0 >= TM*DIN) return;
  if(*dtf){
    const float4* xf = (const float4*)((const float*)x + i0);
    float4 a = xf[0], b = xf[1];
    short8 o;
    o[0]=(short)f2bf(a.x); o[1]=(short)f2bf(a.y); o[2]=(short)f2bf(a.z); o[3]=(short)f2bf(a.w);
    o[4]=(short)f2bf(b.x); o[5]=(short)f2bf(b.y); o[6]=(short)f2bf(b.z); o[7]=(short)f2bf(b.w);
    *(short8*)(xb + i0) = o;
  } else {
    *(short8*)(xb + i0) = *(const short8*)((const unsigned short*)x + i0);
  }
}

// ---------------- weight prep: transposes + folded weights/biases ----------------
__global__ void k_prepw(
  const void* __restrict__ w1, const void* __restrict__ w2,
  const void* __restrict__ qw, const void* __restrict__ kw, const void* __restrict__ vw,
  const void* __restrict__ qb0, const void* __restrict__ kb0, const void* __restrict__ vb0,
  const void* __restrict__ ow, const void* __restrict__ ob,
  const void* __restrict__ fw, const void* __restrict__ fb,
  const void* __restrict__ tw, const void* __restrict__ tb,
  const void* __restrict__ b1, const void* __restrict__ b2,
  const int* __restrict__ dtf,
  unsigned short* __restrict__ W1t, unsigned short* __restrict__ W2t,
  unsigned short* __restrict__ Wqt, unsigned short* __restrict__ Wkt,
  unsigned short* __restrict__ Wvt, unsigned short* __restrict__ Wct,
  float* __restrict__ qbf, float* __restrict__ kbf, float* __restrict__ vbf,
  float* __restrict__ bcf, float* __restrict__ b1f, float* __restrict__ b2f)
{
  const int md = *dtf;
  int id = blockIdx.x*blockDim.x + threadIdx.x;
  if(id < 8192){ int n=id/64, k2=id%64; W1t[n*64+k2]=f2bf(LD(w1,(size_t)k2*128+n,md)); return; }
  id -= 8192;
  if(id < 16384){ int n=id/128,k2=id%128; W2t[n*128+k2]=f2bf(LD(w2,(size_t)k2*128+n,md)); return; }
  id -= 16384;
  if(id < 16384){ int n=id/128,k2=id%128; Wqt[n*128+k2]=f2bf(LD(qw,(size_t)k2*128+n,md)); return; }
  id -= 16384;
  if(id < 16384){ int n=id/128,k2=id%128; Wkt[n*128+k2]=f2bf(LD(kw,(size_t)k2*128+n,md)); return; }
  id -= 16384;
  if(id < 16384){ int n=id/128,k2=id%128; Wvt[n*128+k2]=f2bf(LD(vw,(size_t)k2*128+n,md)); return; }
  id -= 16384;
  if(id < 4096){  // Wc = o_w @ fc_w, stored [oc][c]
    int oc=id/128, c=id%128; float s=0.f;
    for(int r=0;r<128;r++) s += LD(ow,(size_t)c*128+r,md)*LD(fw,(size_t)r*32+oc,md);
    Wct[oc*128+c]=f2bf(s); return;
  }
  id -= 4096;
  if(id < 32){    // bc = o_b @ fc_w + fc_b
    float s = LD(fb,id,md);
    for(int r=0;r<128;r++) s += LD(ob,r,md)*LD(fw,(size_t)r*32+id,md);
    bcf[id]=s; return;
  }
  id -= 32;
  if(id < 4608){  // per-t fused QKV bias: b + t_vec @ W[128:144]
    int which = id/1536, rem=id%1536, t=rem/128, n=rem%128;
    const void* W  = which==0?qw:(which==1?kw:vw);
    const void* Bs = which==0?qb0:(which==1?kb0:vb0);
    float s = LD(Bs,n,md);
    for(int d=0;d<16;d++){
      float tv = sinf((float)t*LD(tw,d,md) + LD(tb,d,md));
      s += tv * LD(W,(size_t)(128+d)*128+n,md);
    }
    float* dst = which==0?qbf:(which==1?kbf:vbf);
    dst[t*128+n]=s; return;
  }
  id -= 4608;
  if(id < 256){   // GCN biases to fp32
    if(id<128) b1f[id] = LD(b1,id,md);
    else       b2f[id-128] = LD(b2,id-128,md);
    return;
  }
}

// ---------------- edge-list build: one pass over A ----------------
__global__ __launch_bounds__(256) void k_edges(const void* __restrict__ A,
    const int* __restrict__ dtf, const float* __restrict__ m,
    int* __restrict__ cnt, int* __restrict__ edges){
  int id = blockIdx.x*blockDim.x + threadIdx.x;   // TM*64 threads
  int seg = id & 63; int row = id >> 6;           // row = t*MM + j
  int t = row / MM, j = row % MM;
  if(m[row]==0.f) return;                         // masked source rows are dead
  int* cb = cnt + (size_t)t*MM;
  int* eb = edges + (size_t)t*MM*CAP;
  if(*dtf){   // fp32 adjacency
    const float4* p4 = (const float4*)((const float*)A + (size_t)row*MM + seg*32);
    #pragma unroll
    for(int u=0;u<8;u++){
      float4 v = p4[u];
      float wd[4]={v.x,v.y,v.z,v.w};
      #pragma unroll
      for(int q=0;q<4;q++){
        int ib = seg*32 + u*4 + q;
        if(wd[q]!=0.f){ int s=atomicAdd(&cb[ib],1); if(s<CAP) eb[(size_t)ib*CAP+s]=j; }
      }
    }
  } else {    // bf16 adjacency
    const uint4* p4 = (const uint4*)((const unsigned short*)A + (size_t)row*MM + seg*32);
    #pragma unroll
    for(int u=0;u<4;u++){
      uint4 v = p4[u];
      unsigned wd[4]={v.x,v.y,v.z,v.w};
      #pragma unroll
      for(int q=0;q<4;q++){
        int ib = seg*32 + u*8 + q*2;
        if(wd[q] & 0xFFFFu){ int s=atomicAdd(&cb[ib],1);   if(s<CAP) eb[(size_t)ib*CAP+s]=j; }
        if(wd[q] >> 16)    { int s=atomicAdd(&cb[ib+1],1); if(s<CAP) eb[(size_t)(ib+1)*CAP+s]=j; }
      }
    }
  }
}

// ---------------- dense GEMM  g = X @ Wt^T   (Wt is [128][KD], k-contiguous) ----------------
template<int KD>
__global__ __launch_bounds__(256) void k_gemm_f32(const unsigned short* __restrict__ X,
    const unsigned short* __restrict__ Wt, float* __restrict__ g)
{
  constexpr int KS = KD/32;
  const int tid=threadIdx.x, wv=tid>>6, lane=tid&63, l15=lane&15, quad=lane>>4;
  const int r0 = blockIdx.x*64 + (wv>>1)*32;
  const int c0 = (wv&1)*64;
  short8 bf[KS][4];
  #pragma unroll
  for(int kk=0;kk<KS;kk++)
    #pragma unroll
    for(int nt=0;nt<4;nt++)
      bf[kk][nt] = *(const short8*)(Wt + (size_t)(c0+nt*16+l15)*KD + kk*32 + quad*8);
  f32x4 z = {0.f,0.f,0.f,0.f};
  f32x4 acc[2][4];
  #pragma unroll
  for(int i=0;i<2;i++){ acc[i][0]=z; acc[i][1]=z; acc[i][2]=z; acc[i][3]=z; }
  #pragma unroll
  for(int kk=0;kk<KS;kk++){
    short8 a0 = *(const short8*)(X + (size_t)(r0+l15)*KD    + kk*32 + quad*8);
    short8 a1 = *(const short8*)(X + (size_t)(r0+16+l15)*KD + kk*32 + quad*8);
    #pragma unroll
    for(int nt=0;nt<4;nt++){
      acc[0][nt]=MFMA(a0,bf[kk][nt],acc[0][nt]);
      acc[1][nt]=MFMA(a1,bf[kk][nt],acc[1][nt]);
    }
  }
  #pragma unroll
  for(int mt=0;mt<2;mt++)
    #pragma unroll
    for(int nt=0;nt<4;nt++){
      int col = c0+nt*16+l15;
      #pragma unroll
      for(int r=0;r<4;r++){
        int row = r0 + mt*16 + quad*4 + r;
        g[(size_t)row*DH + col] = acc[mt][nt][r];
      }
    }
}

// ---------------- sparse GCN aggregation + epilogue -> h (bf16) ----------------
__global__ __launch_bounds__(256) void k_gather(const float* __restrict__ g,
    const int* __restrict__ edges, const int* __restrict__ cnt,
    const float* __restrict__ m, const float* __restrict__ bias,
    unsigned short* __restrict__ h)
{
  int wv = threadIdx.x>>6, lane = threadIdx.x&63;
  int gi = blockIdx.x*4 + wv;           // global row, < TM
  int t = gi / MM;
  float a0=0.f, a1=0.f;
  int cn = cnt[gi]; if(cn>CAP) cn=CAP;
  const int* eb = edges + (size_t)gi*CAP;
  for(int e=0;e<cn;e++){
    int j = eb[e];
    float nj = rsqrtf((float)cnt[(size_t)t*MM+j] + 1.f);
    const float* gr = g + ((size_t)t*MM + j)*DH;
    a0 += nj*gr[lane]; a1 += nj*gr[64+lane];
  }
  float ni = (m[gi]!=0.f) ? rsqrtf((float)cnt[gi] + 1.f) : 0.f;
  const float* gs = g + (size_t)gi*DH;
  float h0 = ni*(a0 + ni*gs[lane])    + bias[lane];
  float h1 = ni*(a1 + ni*gs[64+lane]) + bias[64+lane];
  h0 = h0>0.f?h0:0.f; h1 = h1>0.f?h1:0.f;
  h[(size_t)gi*DH + lane]      = f2bf(h0);
  h[(size_t)gi*DH + 64 + lane] = f2bf(h1);
}

// ---------------- Q/K/V GEMMs: all three row-major ----------------
__global__ __launch_bounds__(256) void k_gemm_qkv(const unsigned short* __restrict__ X,
    const unsigned short* __restrict__ Wq, const unsigned short* __restrict__ Wk,
    const unsigned short* __restrict__ Wv,
    const float* __restrict__ qb, const float* __restrict__ kb, const float* __restrict__ vb,
    unsigned short* __restrict__ Qo, unsigned short* __restrict__ Ko,
    unsigned short* __restrict__ Vr)
{
  const int which = blockIdx.z;
  const unsigned short* Wt = which==0?Wq:(which==1?Wk:Wv);
  const float* bias = which==0?qb:(which==1?kb:vb);
  unsigned short* o = which==0?Qo:(which==1?Ko:Vr);
  const int tid=threadIdx.x, wv=tid>>6, lane=tid&63, l15=lane&15, quad=lane>>4;
  const int r0 = blockIdx.x*64 + (wv>>1)*32;
  const int c0 = (wv&1)*64;
  short8 bf[4][4];
  #pragma unroll
  for(int kk=0;kk<4;kk++)
    #pragma unroll
    for(int nt=0;nt<4;nt++)
      bf[kk][nt] = *(const short8*)(Wt + (size_t)(c0+nt*16+l15)*DH + kk*32 + quad*8);
  f32x4 z = {0.f,0.f,0.f,0.f};
  f32x4 acc[2][4];
  #pragma unroll
  for(int i=0;i<2;i++){ acc[i][0]=z; acc[i][1]=z; acc[i][2]=z; acc[i][3]=z; }
  #pragma unroll
  for(int kk=0;kk<4;kk++){
    short8 a0 = *(const short8*)(X + (size_t)(r0+l15)*DH    + kk*32 + quad*8);
    short8 a1 = *(const short8*)(X + (size_t)(r0+16+l15)*DH + kk*32 + quad*8);
    #pragma unroll
    for(int nt=0;nt<4;nt++){
      acc[0][nt]=MFMA(a0,bf[kk][nt],acc[0][nt]);
      acc[1][nt]=MFMA(a1,bf[kk][nt],acc[1][nt]);
    }
  }
  const int t = (blockIdx.x*64)/MM;
  #pragma unroll
  for(int mt=0;mt<2;mt++)
    #pragma unroll
    for(int nt=0;nt<4;nt++){
      int col = c0+nt*16+l15;
      float bb = bias[t*DH+col];
      #pragma unroll
      for(int r=0;r<4;r++){
        int row = r0 + mt*16 + quad*4 + r;
        o[(size_t)row*DH + col] = f2bf(acc[mt][nt][r] + bb);
      }
    }
}

// ---------------- repack: gather active K rows -> Kc; gather+transpose V -> Vtc ----------------
// grid (MM/64, TT), 64 threads (1 wave). Pads [nact, ceil64(nact)) with zeros.
__global__ __launch_bounds__(64) void k_repack(const unsigned short* __restrict__ K,
    const unsigned short* __restrict__ Vr, const int* __restrict__ aidx,
    const int* __restrict__ nact, unsigned short* __restrict__ Kc,
    unsigned short* __restrict__ Vtc)
{
  __shared__ unsigned short tl[64][130];
  const int i0 = blockIdx.x*64, t = blockIdx.y, l = threadIdx.x;
  const int na = nact[t];
  const int padded = (na + 63) & ~63;
  if(i0 >= padded) return;
  for(int r=0;r<64;r++){
    int i = i0 + r;
    uint32_t kv = 0, vv = 0;
    if(i < na){
      int node = aidx[(size_t)t*MM + i];
      kv = *(const uint32_t*)(K  + ((size_t)t*MM + node)*DH + 2*l);
      vv = *(const uint32_t*)(Vr + ((size_t)t*MM + node)*DH + 2*l);
    }
    *(uint32_t*)(Kc + ((size_t)t*MM + i)*DH + 2*l) = kv;
    tl[r][2*l]   = (unsigned short)(vv & 0xFFFFu);
    tl[r][2*l+1] = (unsigned short)(vv >> 16);
  }
  __syncthreads();
  for(int c=0;c<DH;c++)
    Vtc[(size_t)t*DH*MM + (size_t)c*MM + i0 + l] = tl[l][c];
}

// ---------------- attention, key-split over COMPACT keys ----------------
// grid (MM/16, TT, NSPL), 64 threads.
__global__ __launch_bounds__(64) void k_attn_split(
  const unsigned short* __restrict__ Q, const unsigned short* __restrict__ Kc,
  const unsigned short* __restrict__ Vtc, const int* __restrict__ nact,
  float* __restrict__ part, float* __restrict__ lpart)
{
  __shared__ short Pl[16][72];
  const int lane=threadIdx.x&63, l15=lane&15, quad=lane>>4;
  const int t = blockIdx.y;
  const int qbase = blockIdx.x*16;
  const int z = blockIdx.z;
  const float scale = 0.088388347648318447f;  // 1/sqrt(128)
  const int na = nact[t];
  const int nkt = (na + 63) >> 6;
  const int chunk = (nkt + NSPL - 1) / NSPL;
  const int kt0 = z*chunk;
  int kt1 = kt0 + chunk; if(kt1 > nkt) kt1 = nkt;

  short8 bq[4];
  #pragma unroll
  for(int kk=0;kk<4;kk++)
    bq[kk] = *(const short8*)(Q + ((size_t)t*MM + qbase + l15)*DH + kk*32 + quad*8);

  f32x4 zz = {0.f,0.f,0.f,0.f};
  f32x4 accPV[8];
  #pragma unroll
  for(int i=0;i<8;i++) accPV[i]=zz;
  float l_run = 0.f;

  for(int kt=kt0; kt<kt1; kt++){
    const int key0 = kt*64;
    // S^T = Kc · Q^T  (D[m=key_local][n=q])
    #pragma unroll
    for(int mt=0;mt<4;mt++){
      f32x4 s = zz;
      const unsigned short* Krow = Kc + ((size_t)t*MM + key0 + mt*16 + l15)*DH;
      #pragma unroll
      for(int kk=0;kk<4;kk++){
        short8 ak = *(const short8*)(Krow + kk*32 + quad*8);
        s = MFMA(ak, bq[kk], s);
      }
      short4v pk;
      #pragma unroll
      for(int r=0;r<4;r++){
        float sv = fminf(fmaxf(s[r]*scale, -15.f), 15.f);
        float valid = (key0 + mt*16 + quad*4 + r < na) ? 1.f : 0.f;
        float p = __expf(sv) * valid;
        pk[r] = (short)f2bf(p);
        l_run += bf2f((unsigned short)pk[r]);   // denominator == what PV consumes
      }
      *(short4v*)&Pl[l15][mt*16 + quad*4] = pk;
    }
    // PV accumulate (A-op = P from LDS, B-op = Vtc rows)
    #pragma unroll
    for(int kk=0;kk<2;kk++){
      short8 ap = *(const short8*)&Pl[l15][kk*32 + quad*8];
      const unsigned short* Vb = Vtc + (size_t)t*DH*MM + key0 + kk*32 + quad*8;
      #pragma unroll
      for(int nt=0;nt<8;nt++){
        short8 bv = *(const short8*)(Vb + (size_t)(nt*16 + l15)*MM);
        accPV[nt] = MFMA(ap, bv, accPV[nt]);
      }
    }
  }
  // per-q denominator partial: sum the 4 quads (lanes sharing l15)
  l_run += __shfl_xor(l_run, 16, 64);
  l_run += __shfl_xor(l_run, 32, 64);

  // store fp32 partials (zeros for empty kt ranges -- fin sums unconditionally)
  const size_t pbase = (size_t)(z*TT + t)*MM + qbase;
  #pragma unroll
  for(int nt=0;nt<8;nt++)
    #pragma unroll
    for(int r=0;r<4;r++)
      part[(pbase + quad*4 + r)*128 + nt*16 + l15] = accPV[nt][r];
  if(lane < 16) lpart[pbase + lane] = l_run;
}

// ---------------- attention combine + final projection ----------------
__global__ __launch_bounds__(64) void k_attn_fin(
  const float* __restrict__ part, const float* __restrict__ lpart,
  const float* __restrict__ m, const unsigned short* __restrict__ Wct,
  const float* __restrict__ bc, float* __restrict__ out)
{
  __shared__ short Al[16][136];
  __shared__ float lbuf[16];
  const int lane=threadIdx.x&63, l15=lane&15, quad=lane>>4;
  const int t = blockIdx.y, qbase = blockIdx.x*16;
  f32x4 acc4[8];
  f32x4 zz = {0.f,0.f,0.f,0.f};
  #pragma unroll
  for(int i=0;i<8;i++) acc4[i]=zz;
  #pragma unroll
  for(int s=0;s<NSPL;s++){
    const float* pb = part + ((size_t)(s*TT + t)*MM + qbase)*128;
    #pragma unroll
    for(int i=0;i<8;i++){
      int flat = i*64 + lane;         // 0..511
      int q = flat >> 5, c4 = (flat & 31) << 2;
      acc4[i] += *(const f32x4*)(pb + q*128 + c4);
    }
  }
  if(lane < 16){
    float ls = 0.f;
    #pragma unroll
    for(int s=0;s<NSPL;s++) ls += lpart[(size_t)(s*TT + t)*MM + qbase + lane];
    lbuf[lane] = ls;
  }
  #pragma unroll
  for(int i=0;i<8;i++){
    int flat = i*64 + lane;
    int q = flat >> 5, c4 = (flat & 31) << 2;
    short4v pk;
    #pragma unroll
    for(int r=0;r<4;r++){
      float av = fminf(fmaxf(acc4[i][r], -1e30f), 1e30f);
      pk[r] = (short)f2bf(av);
    }
    *(short4v*)&Al[q][c4] = pk;
  }
  __syncthreads();

  const float* mrow = m + (size_t)t*MM;
  const float lsv = lbuf[l15];
  const float linv = (lsv > 0.f) ? 1.f/lsv : 0.f;
  const int node = qbase + l15;
  const float mq = mrow[node];
  #pragma unroll
  for(int mt2=0;mt2<2;mt2++){
    f32x4 d = zz;
    #pragma unroll
    for(int kk=0;kk<4;kk++){
      short8 aw = *(const short8*)(Wct + (size_t)(mt2*16+l15)*DH + kk*32 + quad*8);
      short8 bl = *(const short8*)&Al[l15][kk*32 + quad*8];
      d = MFMA(aw, bl, d);
    }
    f32x4 bcv = *(const f32x4*)(bc + mt2*16 + quad*4);
    f32x4 o4;
    #pragma unroll
    for(int r=0;r<4;r++){
      float val = d[r]*linv + bcv[r];
      o4[r] = (mq != 0.f) ? val : 0.f;
    }
    *(f32x4*)(out + (size_t)node*(TT*DOUT) + (size_t)t*DOUT + mt2*16 + quad*4) = o4;
  }
}

// ---------------- launch ----------------
extern "C" void kernel_launch(void* const* d_in, const int* in_sizes, int n_in,
                              void* d_out, int out_size, void* d_ws, size_t ws_size,
                              hipStream_t stream)
{
  float* outp = (float*)d_out;   // reference output dtype is float32
  static const int EXP[19] = {1572864,50331648,24576,8192,128,16384,128,16,16,
                              18432,128,18432,128,18432,128,16384,128,4096,32};
  bool ok = (n_in >= 19) && (out_size == 786432);
  if(ok) for(int i=0;i<19;i++) if(in_sizes[i] != EXP[i]) { ok = false; break; }
  if(!ok){
    k_fill<<<(out_size+255)/256,256,0,stream>>>(outp, out_size, 1000.f);
    return;
  }
  const void* x   = d_in[0];
  const void* A   = d_in[1];
  const void* eg  = d_in[2];
  const void* w1  = d_in[3];
  const void* b1  = d_in[4];
  const void* w2  = d_in[5];
  const void* b2  = d_in[6];
  const void* tw  = d_in[7];
  const void* tb  = d_in[8];
  const void* qw  = d_in[9];
  const void* qb0 = d_in[10];
  const void* kw  = d_in[11];
  const void* kb0 = d_in[12];
  const void* vw  = d_in[13];
  const void* vb0 = d_in[14];
  const void* ow  = d_in[15];
  const void* ob  = d_in[16];
  const void* fw  = d_in[17];
  const void* fb  = d_in[18];

  char* w = (char*)d_ws;
  size_t off = 0;
  auto alloc = [&](size_t sz)->char*{
    char* p = w + off; off = (off + sz + 255) & ~(size_t)255; return p; };
  int*   flag  = (int*)  alloc(4);
  int*   dtf   = (int*)  alloc(4);
  int*   nactb = (int*)  alloc(TT*4);
  float* mbuf  = (float*)alloc((size_t)TM*4);
  int*   cnt   = (int*)  alloc((size_t)TM*4);
  int*   aidx  = (int*)  alloc((size_t)TM*4);
  int*   edges = (int*)  alloc((size_t)TM*CAP*4);
  float* g     = (float*)alloc((size_t)TM*DH*4);   // reused as Qb+Kb after 2nd gather
  unsigned short* h   = (unsigned short*)alloc((size_t)TM*DH*2);
  unsigned short* xb  = (unsigned short*)alloc((size_t)TM*DIN*2);
  unsigned short* Vr  = (unsigned short*)alloc((size_t)TM*DH*2);
  unsigned short* Kc  = (unsigned short*)alloc((size_t)TM*DH*2);
  unsigned short* Vtc = (unsigned short*)alloc((size_t)TT*DH*MM*2);
  unsigned short* W1t = (unsigned short*)alloc(DH*DIN*2);
  unsigned short* W2t = (unsigned short*)alloc(DH*DH*2);
  unsigned short* Wqt = (unsigned short*)alloc(DH*DH*2);
  unsigned short* Wkt = (unsigned short*)alloc(DH*DH*2);
  unsigned short* Wvt = (unsigned short*)alloc(DH*DH*2);
  unsigned short* Wct = (unsigned short*)alloc(DOUT*DH*2);
  float* qbf = (float*)alloc(TT*DH*4);
  float* kbf = (float*)alloc(TT*DH*4);
  float* vbf = (float*)alloc(TT*DH*4);
  float* bcf = (float*)alloc(DOUT*4);
  float* b1f = (float*)alloc(DH*4);
  float* b2f = (float*)alloc(DH*4);
  float* part  = (float*)alloc((size_t)NSPL*TM*DH*4);
  float* lpart = (float*)alloc((size_t)NSPL*TM*4);
  if(off > ws_size){
    k_fill<<<(out_size+255)/256,256,0,stream>>>(outp, out_size, 500.f);
    return;
  }

  unsigned short* Qb = (unsigned short*)g;                       // TM*DH*2 bytes
  unsigned short* Kb = (unsigned short*)((char*)g + (size_t)TM*DH*2);

  k_dtype<<<1,256,0,stream>>>((const unsigned short*)x, dtf, nactb);
  k_detect<<<1,256,0,stream>>>((const unsigned char*)eg, flag);
  k_mask<<<TM/256,256,0,stream>>>(eg, flag, mbuf, cnt, nactb, aidx);
  k_conv<<<(TM*DIN/8+255)/256,256,0,stream>>>(x, dtf, xb);
  k_prepw<<<(82720+255)/256,256,0,stream>>>(w1,w2,qw,kw,vw,qb0,kb0,vb0,ow,ob,fw,fb,tw,tb,
                                            b1,b2,dtf,
                                            W1t,W2t,Wqt,Wkt,Wvt,Wct,qbf,kbf,vbf,bcf,b1f,b2f);
  k_edges<<<TM*64/256,256,0,stream>>>(A, dtf, mbuf, cnt, edges);
  k_gemm_f32<DIN><<<TM/64,256,0,stream>>>(xb, W1t, g);
  k_gather<<<TM/4,256,0,stream>>>(g, edges, cnt, mbuf, b1f, h);
  k_gemm_f32<DH><<<TM/64,256,0,stream>>>(h, W2t, g);
  k_gather<<<TM/4,256,0,stream>>>(g, edges, cnt, mbuf, b2f, h);
  k_gemm_qkv<<<dim3(TM/64,1,3),256,0,stream>>>(h, Wqt,Wkt,Wvt, qbf,kbf,vbf, Qb,Kb,Vr);
  k_repack<<<dim3(MM/64,TT),64,0,stream>>>(Kb, Vr, aidx, nactb, Kc, Vtc);
  k_attn_split<<<dim3(MM/16,TT,NSPL),64,0,stream>>>(Qb, Kc, Vtc, nactb, part, lpart);
  k_attn_fin<<<dim3(MM/16,TT),64,0,stream>>>(part, lpart, mbuf, Wct, bcf, outp);
}

// Round 14
// 571.663 us; speedup vs baseline: 1.3921x; 1.1401x over previous
//
#include <hip/hip_runtime.h>
#include <stdint.h>

#define TT   12
#define BB   2
#define NN   1024
#define MM   2048
#define TM   24576      // TT*MM
#define DIN  64
#define DH   128
#define DOUT 32
#define CAP  64
#define NSPL 4

typedef __attribute__((ext_vector_type(8))) short short8;
typedef __attribute__((ext_vector_type(4))) short short4v;
typedef __attribute__((ext_vector_type(4))) float f32x4;

#define MFMA(a,b,c) __builtin_amdgcn_mfma_f32_16x16x32_bf16((a),(b),(c),0,0,0)

__device__ __forceinline__ float bf2f(unsigned short u){
  union { uint32_t i; float f; } x; x.i = ((uint32_t)u) << 16; return x.f;
}
__device__ __forceinline__ unsigned short f2bf(float f){
  union { float f; uint32_t i; } x; x.f = f;
  uint32_t u = x.i + 0x7FFFu + ((x.i >> 16) & 1u);   // RNE
  return (unsigned short)(u >> 16);
}
__device__ __forceinline__ float LD(const void* p, size_t i, int mode){
  return mode ? ((const float*)p)[i] : bf2f(((const unsigned short*)p)[i]);
}

// ---------------- fill (fp32) ----------------
__global__ void k_fill(float* __restrict__ out, int n, float val){
  int i = blockIdx.x*blockDim.x + threadIdx.x;
  if(i < n) out[i] = val;
}

// ---------------- input dtype detection; also zero nact ----------------
__global__ void k_dtype(const unsigned short* __restrict__ x, int* __restrict__ dtf,
                        int* __restrict__ nact){
  __shared__ int cnt_s;
  if(threadIdx.x==0) cnt_s = 0;
  if(threadIdx.x < TT) nact[threadIdx.x] = 0;
  __syncthreads();
  int c = 0;
  for(int i=threadIdx.x; i<6144; i+=blockDim.x){
    unsigned short h = x[i*2];
    unsigned e = (h >> 7) & 0xFF;
    if(h==0 || (e >= 0x60 && e <= 0x9F)) c++;
  }
  atomicAdd(&cnt_s, c);
  __syncthreads();
  if(threadIdx.x==0) *dtf = (cnt_s > 4000) ? 0 : 1;   // 0=bf16, 1=fp32
}

// ---------------- mask dtype detection: byte-pattern classifier ----------------
// modes: 0=i32, 1=u8, 2=bf16, 3=f32, 4=i64, 5=f64
__global__ void k_detect(const unsigned char* __restrict__ p, int* __restrict__ flag){
  __shared__ int pres_s, ge2_s;
  if(threadIdx.x==0){ pres_s=0; ge2_s=0; }
  __syncthreads();
  int pres=0, ge2=0;
  for(int i=threadIdx.x; i<24576; i+=blockDim.x){
    unsigned v = p[i];
    if(v){ pres |= 1 << (i & 7); if(v >= 2u) ge2 = 1; }
  }
  if(pres) atomicOr(&pres_s, pres);
  if(ge2)  atomicOr(&ge2_s, 1);
  __syncthreads();
  if(threadIdx.x==0){
    int pr = pres_s, g2 = ge2_s, mode;
    if(!g2){
      if((pr & ~0x01) == 0)      mode = 4;   // i64
      else if((pr & ~0x11) == 0) mode = 0;   // i32
      else                       mode = 1;   // u8
    } else {
      if((pr & ~0xC0) == 0)      mode = 5;   // f64
      else if((pr & ~0xCC) == 0) mode = 3;   // f32
      else                       mode = 2;   // bf16
    }
    *flag = mode;
  }
}

// mask decode + wave-ballot compaction: aidx (compact->orig), inv (orig->compact or -1)
__global__ void k_mask(const void* __restrict__ egom, const int* __restrict__ flag,
                       int* __restrict__ cnt, int* __restrict__ nact,
                       int* __restrict__ aidx, int* __restrict__ inv){
  int idx = blockIdx.x*blockDim.x + threadIdx.x;   // < TM; wave = 64 consecutive nodes, one t
  int t = idx / MM, node = idx % MM;
  int b = node / NN, n = node % NN;
  int src = (b*TT + t)*NN + n;
  int mode = *flag;
  int v;
  if(mode==0)      v = ((const int*)egom)[src] != 0;
  else if(mode==1) v = ((const unsigned char*)egom)[src] != 0;
  else if(mode==2) v = ((const unsigned short*)egom)[src] != 0;
  else if(mode==3) v = ((const float*)egom)[src] != 0.f;
  else if(mode==4) v = ((const long long*)egom)[src] != 0;
  else             v = ((const double*)egom)[src] != 0.0;
  cnt[idx] = 0;
  unsigned long long bal = __ballot(v != 0);
  int lane = threadIdx.x & 63;
  int base = 0;
  if(lane == 0 && bal) base = atomicAdd(&nact[t], __popcll(bal));
  base = __shfl(base, 0, 64);
  int ic = -1;
  if(v){
    int pfx = __popcll(bal & ((1ULL << lane) - 1ULL));
    ic = base + pfx;
    aidx[(size_t)t*MM + ic] = node;
  }
  inv[idx] = ic;
}

// ---------------- gather active x rows -> xc (bf16, compact, zero-padded) ----------------
__global__ void k_conv(const void* __restrict__ x, const int* __restrict__ dtf,
                       const int* __restrict__ nact, const int* __restrict__ aidx,
                       unsigned short* __restrict__ xc){
  int id = blockIdx.x*blockDim.x + threadIdx.x;   // TM*8 threads
  int rowc = id >> 3, seg = id & 7;
  int t = rowc / MM, ic = rowc % MM;
  int na = nact[t];
  if(ic >= ((na+63)&~63)) return;
  short8 o = {0,0,0,0,0,0,0,0};
  if(ic < na){
    int node = aidx[(size_t)t*MM + ic];
    size_t src = ((size_t)t*MM + node)*DIN + seg*8;
    if(*dtf){
      const float4* xf = (const float4*)((const float*)x + src);
      float4 a = xf[0], b = xf[1];
      o[0]=(short)f2bf(a.x); o[1]=(short)f2bf(a.y); o[2]=(short)f2bf(a.z); o[3]=(short)f2bf(a.w);
      o[4]=(short)f2bf(b.x); o[5]=(short)f2bf(b.y); o[6]=(short)f2bf(b.z); o[7]=(short)f2bf(b.w);
    } else {
      o = *(const short8*)((const unsigned short*)x + src);
    }
  }
  *(short8*)(xc + (size_t)rowc*DIN + seg*8) = o;
}

// ---------------- weight prep (unchanged) ----------------
__global__ void k_prepw(
  const void* __restrict__ w1, const void* __restrict__ w2,
  const void* __restrict__ qw, const void* __restrict__ kw, const void* __restrict__ vw,
  const void* __restrict__ qb0, const void* __restrict__ kb0, const void* __restrict__ vb0,
  const void* __restrict__ ow, const void* __restrict__ ob,
  const void* __restrict__ fw, const void* __restrict__ fb,
  const void* __restrict__ tw, const void* __restrict__ tb,
  const void* __restrict__ b1, const void* __restrict__ b2,
  const int* __restrict__ dtf,
  unsigned short* __restrict__ W1t, unsigned short* __restrict__ W2t,
  unsigned short* __restrict__ Wqt, unsigned short* __restrict__ Wkt,
  unsigned short* __restrict__ Wvt, unsigned short* __restrict__ Wct,
  float* __restrict__ qbf, float* __restrict__ kbf, float* __restrict__ vbf,
  float* __restrict__ bcf, float* __restrict__ b1f, float* __restrict__ b2f)
{
  const int md = *dtf;
  int id = blockIdx.x*blockDim.x + threadIdx.x;
  if(id < 8192){ int n=id/64, k2=id%64; W1t[n*64+k2]=f2bf(LD(w1,(size_t)k2*128+n,md)); return; }
  id -= 8192;
  if(id < 16384){ int n=id/128,k2=id%128; W2t[n*128+k2]=f2bf(LD(w2,(size_t)k2*128+n,md)); return; }
  id -= 16384;
  if(id < 16384){ int n=id/128,k2=id%128; Wqt[n*128+k2]=f2bf(LD(qw,(size_t)k2*128+n,md)); return; }
  id -= 16384;
  if(id < 16384){ int n=id/128,k2=id%128; Wkt[n*128+k2]=f2bf(LD(kw,(size_t)k2*128+n,md)); return; }
  id -= 16384;
  if(id < 16384){ int n=id/128,k2=id%128; Wvt[n*128+k2]=f2bf(LD(vw,(size_t)k2*128+n,md)); return; }
  id -= 16384;
  if(id < 4096){  // Wc = o_w @ fc_w, stored [oc][c]
    int oc=id/128, c=id%128; float s=0.f;
    for(int r=0;r<128;r++) s += LD(ow,(size_t)c*128+r,md)*LD(fw,(size_t)r*32+oc,md);
    Wct[oc*128+c]=f2bf(s); return;
  }
  id -= 4096;
  if(id < 32){    // bc = o_b @ fc_w + fc_b
    float s = LD(fb,id,md);
    for(int r=0;r<128;r++) s += LD(ob,r,md)*LD(fw,(size_t)r*32+id,md);
    bcf[id]=s; return;
  }
  id -= 32;
  if(id < 4608){  // per-t fused QKV bias: b + t_vec @ W[128:144]
    int which = id/1536, rem=id%1536, t=rem/128, n=rem%128;
    const void* W  = which==0?qw:(which==1?kw:vw);
    const void* Bs = which==0?qb0:(which==1?kb0:vb0);
    float s = LD(Bs,n,md);
    for(int d=0;d<16;d++){
      float tv = sinf((float)t*LD(tw,d,md) + LD(tb,d,md));
      s += tv * LD(W,(size_t)(128+d)*128+n,md);
    }
    float* dst = which==0?qbf:(which==1?kbf:vbf);
    dst[t*128+n]=s; return;
  }
  id -= 4608;
  if(id < 256){   // GCN biases to fp32
    if(id<128) b1f[id] = LD(b1,id,md);
    else       b2f[id-128] = LD(b2,id-128,md);
    return;
  }
}

// ---------------- edge-list build: compact source+target ----------------
__global__ __launch_bounds__(256) void k_edges(const void* __restrict__ A,
    const int* __restrict__ dtf, const int* __restrict__ inv,
    int* __restrict__ cnt, int* __restrict__ edges){
  int id = blockIdx.x*blockDim.x + threadIdx.x;   // TM*64 threads
  int seg = id & 63; int row = id >> 6;           // row = t*MM + j (orig)
  int t = row / MM;
  int jc = inv[row];
  if(jc < 0) return;                              // inactive source
  const int* invt = inv + (size_t)t*MM;
  int* cb = cnt + (size_t)t*MM;
  int* eb = edges + (size_t)t*MM*CAP;
  if(*dtf){   // fp32 adjacency
    const float4* p4 = (const float4*)((const float*)A + (size_t)row*MM + seg*32);
    #pragma unroll
    for(int u=0;u<8;u++){
      float4 v = p4[u];
      float wd[4]={v.x,v.y,v.z,v.w};
      #pragma unroll
      for(int q=0;q<4;q++){
        if(wd[q]!=0.f){
          int ibc = invt[seg*32 + u*4 + q];
          if(ibc >= 0){ int s=atomicAdd(&cb[ibc],1); if(s<CAP) eb[(size_t)ibc*CAP+s]=jc; }
        }
      }
    }
  } else {    // bf16 adjacency
    const uint4* p4 = (const uint4*)((const unsigned short*)A + (size_t)row*MM + seg*32);
    #pragma unroll
    for(int u=0;u<4;u++){
      uint4 v = p4[u];
      unsigned wd[4]={v.x,v.y,v.z,v.w};
      #pragma unroll
      for(int q=0;q<4;q++){
        int ib = seg*32 + u*8 + q*2;
        if(wd[q] & 0xFFFFu){
          int ibc = invt[ib];
          if(ibc >= 0){ int s=atomicAdd(&cb[ibc],1); if(s<CAP) eb[(size_t)ibc*CAP+s]=jc; }
        }
        if(wd[q] >> 16){
          int ibc = invt[ib+1];
          if(ibc >= 0){ int s=atomicAdd(&cb[ibc],1); if(s<CAP) eb[(size_t)ibc*CAP+s]=jc; }
        }
      }
    }
  }
}

// ---------------- dense GEMM on compact rows ----------------
template<int KD>
__global__ __launch_bounds__(256) void k_gemm_f32(const unsigned short* __restrict__ X,
    const unsigned short* __restrict__ Wt, float* __restrict__ g,
    const int* __restrict__ nact)
{
  constexpr int KS = KD/32;
  const int tile = blockIdx.x*64;
  const int t = tile / MM, il = tile % MM;
  const int na = nact[t];
  if(il >= ((na+63)&~63)) return;
  const int tid=threadIdx.x, wv=tid>>6, lane=tid&63, l15=lane&15, quad=lane>>4;
  const int r0 = tile + (wv>>1)*32;
  const int c0 = (wv&1)*64;
  short8 bf[KS][4];
  #pragma unroll
  for(int kk=0;kk<KS;kk++)
    #pragma unroll
    for(int nt=0;nt<4;nt++)
      bf[kk][nt] = *(const short8*)(Wt + (size_t)(c0+nt*16+l15)*KD + kk*32 + quad*8);
  f32x4 z = {0.f,0.f,0.f,0.f};
  f32x4 acc[2][4];
  #pragma unroll
  for(int i=0;i<2;i++){ acc[i][0]=z; acc[i][1]=z; acc[i][2]=z; acc[i][3]=z; }
  #pragma unroll
  for(int kk=0;kk<KS;kk++){
    short8 a0 = *(const short8*)(X + (size_t)(r0+l15)*KD    + kk*32 + quad*8);
    short8 a1 = *(const short8*)(X + (size_t)(r0+16+l15)*KD + kk*32 + quad*8);
    #pragma unroll
    for(int nt=0;nt<4;nt++){
      acc[0][nt]=MFMA(a0,bf[kk][nt],acc[0][nt]);
      acc[1][nt]=MFMA(a1,bf[kk][nt],acc[1][nt]);
    }
  }
  #pragma unroll
  for(int mt=0;mt<2;mt++)
    #pragma unroll
    for(int nt=0;nt<4;nt++){
      int col = c0+nt*16+l15;
      #pragma unroll
      for(int r=0;r<4;r++){
        int row = r0 + mt*16 + quad*4 + r;
        g[(size_t)row*DH + col] = acc[mt][nt][r];
      }
    }
}

// ---------------- sparse GCN aggregation on compact rows -> h (bf16) ----------------
__global__ __launch_bounds__(256) void k_gather(const float* __restrict__ g,
    const int* __restrict__ edges, const int* __restrict__ cnt,
    const int* __restrict__ nact, const float* __restrict__ bias,
    unsigned short* __restrict__ h)
{
  int wv = threadIdx.x>>6, lane = threadIdx.x&63;
  int gi = blockIdx.x*4 + wv;           // compact row, < TM
  int t = gi / MM, ic = gi % MM;
  int na = nact[t];
  if(ic >= ((na+63)&~63)) return;
  if(ic >= na){                         // pad row: finite zeros
    h[(size_t)gi*DH + lane] = 0; h[(size_t)gi*DH + 64 + lane] = 0;
    return;
  }
  float a0=0.f, a1=0.f;
  int cn = cnt[gi]; if(cn>CAP) cn=CAP;
  const int* eb = edges + (size_t)gi*CAP;
  for(int e=0;e<cn;e++){
    int jc = eb[e];                     // compact source
    float nj = rsqrtf((float)cnt[(size_t)t*MM+jc] + 1.f);
    const float* gr = g + ((size_t)t*MM + jc)*DH;
    a0 += nj*gr[lane]; a1 += nj*gr[64+lane];
  }
  float ni = rsqrtf((float)cn + 1.f);   // own row always active here
  const float* gs = g + (size_t)gi*DH;
  float h0 = ni*(a0 + ni*gs[lane])    + bias[lane];
  float h1 = ni*(a1 + ni*gs[64+lane]) + bias[64+lane];
  h0 = h0>0.f?h0:0.f; h1 = h1>0.f?h1:0.f;
  h[(size_t)gi*DH + lane]      = f2bf(h0);
  h[(size_t)gi*DH + 64 + lane] = f2bf(h1);
}

// ---------------- Q/K/V GEMMs on compact rows, row-major ----------------
__global__ __launch_bounds__(256) void k_gemm_qkv(const unsigned short* __restrict__ X,
    const unsigned short* __restrict__ Wq, const unsigned short* __restrict__ Wk,
    const unsigned short* __restrict__ Wv,
    const float* __restrict__ qb, const float* __restrict__ kb, const float* __restrict__ vb,
    unsigned short* __restrict__ Qo, unsigned short* __restrict__ Ko,
    unsigned short* __restrict__ Vr, const int* __restrict__ nact)
{
  const int tile = blockIdx.x*64;
  const int t = tile / MM, il = tile % MM;
  const int na = nact[t];
  if(il >= ((na+63)&~63)) return;
  const int which = blockIdx.z;
  const unsigned short* Wt = which==0?Wq:(which==1?Wk:Wv);
  const float* bias = which==0?qb:(which==1?kb:vb);
  unsigned short* o = which==0?Qo:(which==1?Ko:Vr);
  const int tid=threadIdx.x, wv=tid>>6, lane=tid&63, l15=lane&15, quad=lane>>4;
  const int r0 = tile + (wv>>1)*32;
  const int c0 = (wv&1)*64;
  short8 bf[4][4];
  #pragma unroll
  for(int kk=0;kk<4;kk++)
    #pragma unroll
    for(int nt=0;nt<4;nt++)
      bf[kk][nt] = *(const short8*)(Wt + (size_t)(c0+nt*16+l15)*DH + kk*32 + quad*8);
  f32x4 z = {0.f,0.f,0.f,0.f};
  f32x4 acc[2][4];
  #pragma unroll
  for(int i=0;i<2;i++){ acc[i][0]=z; acc[i][1]=z; acc[i][2]=z; acc[i][3]=z; }
  #pragma unroll
  for(int kk=0;kk<4;kk++){
    short8 a0 = *(const short8*)(X + (size_t)(r0+l15)*DH    + kk*32 + quad*8);
    short8 a1 = *(const short8*)(X + (size_t)(r0+16+l15)*DH + kk*32 + quad*8);
    #pragma unroll
    for(int nt=0;nt<4;nt++){
      acc[0][nt]=MFMA(a0,bf[kk][nt],acc[0][nt]);
      acc[1][nt]=MFMA(a1,bf[kk][nt],acc[1][nt]);
    }
  }
  #pragma unroll
  for(int mt=0;mt<2;mt++)
    #pragma unroll
    for(int nt=0;nt<4;nt++){
      int col = c0+nt*16+l15;
      float bb = bias[t*DH+col];
      #pragma unroll
      for(int r=0;r<4;r++){
        int row = r0 + mt*16 + quad*4 + r;
        o[(size_t)row*DH + col] = f2bf(acc[mt][nt][r] + bb);
      }
    }
}

// ---------------- V transpose (compact): Vr rows -> Vtc columns ----------------
__global__ __launch_bounds__(64) void k_vtrans(const unsigned short* __restrict__ Vr,
    const int* __restrict__ nact, unsigned short* __restrict__ Vtc)
{
  __shared__ unsigned short tl[64][130];
  const int i0 = blockIdx.x*64, t = blockIdx.y, l = threadIdx.x;
  const int na = nact[t];
  if(i0 >= ((na+63)&~63)) return;
  for(int r=0;r<64;r++){
    uint32_t vv = *(const uint32_t*)(Vr + ((size_t)t*MM + i0 + r)*DH + 2*l);
    tl[r][2*l]   = (unsigned short)(vv & 0xFFFFu);
    tl[r][2*l+1] = (unsigned short)(vv >> 16);
  }
  __syncthreads();
  for(int c=0;c<DH;c++)
    Vtc[(size_t)t*DH*MM + (size_t)c*MM + i0 + l] = tl[l][c];
}

// ---------------- attention, key-split, compact queries+keys ----------------
__global__ __launch_bounds__(64) void k_attn_split(
  const unsigned short* __restrict__ Q, const unsigned short* __restrict__ Kc,
  const unsigned short* __restrict__ Vtc, const int* __restrict__ nact,
  float* __restrict__ part, float* __restrict__ lpart)
{
  __shared__ short Pl[16][72];
  const int lane=threadIdx.x&63, l15=lane&15, quad=lane>>4;
  const int t = blockIdx.y;
  const int qbase = blockIdx.x*16;
  const int z = blockIdx.z;
  const float scale = 0.088388347648318447f;  // 1/sqrt(128)
  const int na = nact[t];
  if(qbase >= na) return;                     // wave-uniform exit (safe before MFMA)
  const int nkt = (na + 63) >> 6;
  const int chunk = (nkt + NSPL - 1) / NSPL;
  const int kt0 = z*chunk;
  int kt1 = kt0 + chunk; if(kt1 > nkt) kt1 = nkt;

  short8 bq[4];
  #pragma unroll
  for(int kk=0;kk<4;kk++)
    bq[kk] = *(const short8*)(Q + ((size_t)t*MM + qbase + l15)*DH + kk*32 + quad*8);

  f32x4 zz = {0.f,0.f,0.f,0.f};
  f32x4 accPV[8];
  #pragma unroll
  for(int i=0;i<8;i++) accPV[i]=zz;
  float l_run = 0.f;

  for(int kt=kt0; kt<kt1; kt++){
    const int key0 = kt*64;
    #pragma unroll
    for(int mt=0;mt<4;mt++){
      f32x4 s = zz;
      const unsigned short* Krow = Kc + ((size_t)t*MM + key0 + mt*16 + l15)*DH;
      #pragma unroll
      for(int kk=0;kk<4;kk++){
        short8 ak = *(const short8*)(Krow + kk*32 + quad*8);
        s = MFMA(ak, bq[kk], s);
      }
      short4v pk;
      #pragma unroll
      for(int r=0;r<4;r++){
        float sv = fminf(fmaxf(s[r]*scale, -15.f), 15.f);
        float valid = (key0 + mt*16 + quad*4 + r < na) ? 1.f : 0.f;
        float p = __expf(sv) * valid;
        pk[r] = (short)f2bf(p);
        l_run += bf2f((unsigned short)pk[r]);
      }
      *(short4v*)&Pl[l15][mt*16 + quad*4] = pk;
    }
    #pragma unroll
    for(int kk=0;kk<2;kk++){
      short8 ap = *(const short8*)&Pl[l15][kk*32 + quad*8];
      const unsigned short* Vb = Vtc + (size_t)t*DH*MM + key0 + kk*32 + quad*8;
      #pragma unroll
      for(int nt=0;nt<8;nt++){
        short8 bv = *(const short8*)(Vb + (size_t)(nt*16 + l15)*MM);
        accPV[nt] = MFMA(ap, bv, accPV[nt]);
      }
    }
  }
  l_run += __shfl_xor(l_run, 16, 64);
  l_run += __shfl_xor(l_run, 32, 64);

  const size_t pbase = (size_t)(z*TT + t)*MM + qbase;
  #pragma unroll
  for(int nt=0;nt<8;nt++)
    #pragma unroll
    for(int r=0;r<4;r++)
      part[(pbase + quad*4 + r)*128 + nt*16 + l15] = accPV[nt][r];
  if(lane < 16) lpart[pbase + lane] = l_run;
}

// ---------------- attention combine + final projection, scatter to orig nodes ----------------
// NOTE: no per-lane early return before the MFMA loop -- MFMA is per-wave; exited
// lanes would feed stale-register garbage into the fragments (round-13 NaN bug).
__global__ __launch_bounds__(64) void k_attn_fin(
  const float* __restrict__ part, const float* __restrict__ lpart,
  const int* __restrict__ aidx, const int* __restrict__ nact,
  const unsigned short* __restrict__ Wct, const float* __restrict__ bc,
  float* __restrict__ out)
{
  __shared__ short Al[16][136];
  __shared__ float lbuf[16];
  const int lane=threadIdx.x&63, l15=lane&15, quad=lane>>4;
  const int t = blockIdx.y, qbase = blockIdx.x*16;
  const int na = nact[t];
  if(qbase >= na) return;                    // wave-uniform: safe
  f32x4 acc4[8];
  f32x4 zz = {0.f,0.f,0.f,0.f};
  #pragma unroll
  for(int i=0;i<8;i++) acc4[i]=zz;
  #pragma unroll
  for(int s=0;s<NSPL;s++){
    const float* pb = part + ((size_t)(s*TT + t)*MM + qbase)*128;
    #pragma unroll
    for(int i=0;i<8;i++){
      int flat = i*64 + lane;
      int q = flat >> 5, c4 = (flat & 31) << 2;
      acc4[i] += *(const f32x4*)(pb + q*128 + c4);
    }
  }
  if(lane < 16){
    float ls = 0.f;
    #pragma unroll
    for(int s=0;s<NSPL;s++) ls += lpart[(size_t)(s*TT + t)*MM + qbase + lane];
    lbuf[lane] = ls;
  }
  #pragma unroll
  for(int i=0;i<8;i++){
    int flat = i*64 + lane;
    int q = flat >> 5, c4 = (flat & 31) << 2;
    short4v pk;
    #pragma unroll
    for(int r=0;r<4;r++){
      float av = fminf(fmaxf(acc4[i][r], -1e30f), 1e30f);
      pk[r] = (short)f2bf(av);
    }
    *(short4v*)&Al[q][c4] = pk;
  }
  __syncthreads();

  const int qc = qbase + l15;
  const bool qok = (qc < na);                // predicate stores only; all lanes run MFMA
  const float lsv = lbuf[l15];
  const float linv = (lsv > 0.f) ? 1.f/lsv : 0.f;
  const int node = aidx[(size_t)t*MM + (qok ? qc : 0)];
  #pragma unroll
  for(int mt2=0;mt2<2;mt2++){
    f32x4 d = zz;
    #pragma unroll
    for(int kk=0;kk<4;kk++){
      short8 aw = *(const short8*)(Wct + (size_t)(mt2*16+l15)*DH + kk*32 + quad*8);
      short8 bl = *(const short8*)&Al[l15][kk*32 + quad*8];
      d = MFMA(aw, bl, d);
    }
    f32x4 bcv = *(const f32x4*)(bc + mt2*16 + quad*4);
    f32x4 o4;
    #pragma unroll
    for(int r=0;r<4;r++) o4[r] = d[r]*linv + bcv[r];
    if(qok)
      *(f32x4*)(out + (size_t)node*(TT*DOUT) + (size_t)t*DOUT + mt2*16 + quad*4) = o4;
  }
}

// ---------------- launch ----------------
extern "C" void kernel_launch(void* const* d_in, const int* in_sizes, int n_in,
                              void* d_out, int out_size, void* d_ws, size_t ws_size,
                              hipStream_t stream)
{
  float* outp = (float*)d_out;   // reference output dtype is float32
  static const int EXP[19] = {1572864,50331648,24576,8192,128,16384,128,16,16,
                              18432,128,18432,128,18432,128,16384,128,4096,32};
  bool ok = (n_in >= 19) && (out_size == 786432);
  if(ok) for(int i=0;i<19;i++) if(in_sizes[i] != EXP[i]) { ok = false; break; }
  if(!ok){
    k_fill<<<(out_size+255)/256,256,0,stream>>>(outp, out_size, 1000.f);
    return;
  }
  const void* x   = d_in[0];
  const void* A   = d_in[1];
  const void* eg  = d_in[2];
  const void* w1  = d_in[3];
  const void* b1  = d_in[4];
  const void* w2  = d_in[5];
  const void* b2  = d_in[6];
  const void* tw  = d_in[7];
  const void* tb  = d_in[8];
  const void* qw  = d_in[9];
  const void* qb0 = d_in[10];
  const void* kw  = d_in[11];
  const void* kb0 = d_in[12];
  const void* vw  = d_in[13];
  const void* vb0 = d_in[14];
  const void* ow  = d_in[15];
  const void* ob  = d_in[16];
  const void* fw  = d_in[17];
  const void* fb  = d_in[18];

  char* w = (char*)d_ws;
  size_t off = 0;
  auto alloc = [&](size_t sz)->char*{
    char* p = w + off; off = (off + sz + 255) & ~(size_t)255; return p; };
  int*   flag  = (int*)  alloc(4);
  int*   dtf   = (int*)  alloc(4);
  int*   nactb = (int*)  alloc(TT*4);
  int*   cnt   = (int*)  alloc((size_t)TM*4);
  int*   aidx  = (int*)  alloc((size_t)TM*4);
  int*   inv   = (int*)  alloc((size_t)TM*4);
  int*   edges = (int*)  alloc((size_t)TM*CAP*4);
  float* g     = (float*)alloc((size_t)TM*DH*4);   // reused as Qb+Kb after 2nd gather
  unsigned short* h   = (unsigned short*)alloc((size_t)TM*DH*2);
  unsigned short* xc  = (unsigned short*)alloc((size_t)TM*DIN*2);
  unsigned short* Vr  = (unsigned short*)alloc((size_t)TM*DH*2);
  unsigned short* Vtc = (unsigned short*)alloc((size_t)TT*DH*MM*2);
  unsigned short* W1t = (unsigned short*)alloc(DH*DIN*2);
  unsigned short* W2t = (unsigned short*)alloc(DH*DH*2);
  unsigned short* Wqt = (unsigned short*)alloc(DH*DH*2);
  unsigned short* Wkt = (unsigned short*)alloc(DH*DH*2);
  unsigned short* Wvt = (unsigned short*)alloc(DH*DH*2);
  unsigned short* Wct = (unsigned short*)alloc(DOUT*DH*2);
  float* qbf = (float*)alloc(TT*DH*4);
  float* kbf = (float*)alloc(TT*DH*4);
  float* vbf = (float*)alloc(TT*DH*4);
  float* bcf = (float*)alloc(DOUT*4);
  float* b1f = (float*)alloc(DH*4);
  float* b2f = (float*)alloc(DH*4);
  float* part  = (float*)alloc((size_t)NSPL*TM*DH*4);
  float* lpart = (float*)alloc((size_t)NSPL*TM*4);
  if(off > ws_size){
    k_fill<<<(out_size+255)/256,256,0,stream>>>(outp, out_size, 500.f);
    return;
  }

  unsigned short* Qb = (unsigned short*)g;                       // TM*DH*2 bytes
  unsigned short* Kb = (unsigned short*)((char*)g + (size_t)TM*DH*2);

  k_fill<<<(out_size+255)/256,256,0,stream>>>(outp, out_size, 0.f);  // inactive nodes = 0
  k_dtype<<<1,256,0,stream>>>((const unsigned short*)x, dtf, nactb);
  k_detect<<<1,256,0,stream>>>((const unsigned char*)eg, flag);
  k_mask<<<TM/256,256,0,stream>>>(eg, flag, cnt, nactb, aidx, inv);
  k_conv<<<TM*8/256,256,0,stream>>>(x, dtf, nactb, aidx, xc);
  k_prepw<<<(82720+255)/256,256,0,stream>>>(w1,w2,qw,kw,vw,qb0,kb0,vb0,ow,ob,fw,fb,tw,tb,
                                            b1,b2,dtf,
                                            W1t,W2t,Wqt,Wkt,Wvt,Wct,qbf,kbf,vbf,bcf,b1f,b2f);
  k_edges<<<TM*64/256,256,0,stream>>>(A, dtf, inv, cnt, edges);
  k_gemm_f32<DIN><<<TM/64,256,0,stream>>>(xc, W1t, g, nactb);
  k_gather<<<TM/4,256,0,stream>>>(g, edges, cnt, nactb, b1f, h);
  k_gemm_f32<DH><<<TM/64,256,0,stream>>>(h, W2t, g, nactb);
  k_gather<<<TM/4,256,0,stream>>>(g, edges, cnt, nactb, b2f, h);
  k_gemm_qkv<<<dim3(TM/64,1,3),256,0,stream>>>(h, Wqt,Wkt,Wvt, qbf,kbf,vbf, Qb,Kb,Vr, nactb);
  k_vtrans<<<dim3(MM/64,TT),64,0,stream>>>(Vr, nactb, Vtc);
  k_attn_split<<<dim3(MM/16,TT,NSPL),64,0,stream>>>(Qb, Kb, Vtc, nactb, part, lpart);
  k_attn_fin<<<dim3(MM/16,TT),64,0,stream>>>(part, lpart, aidx, nactb, Wct, bcf, outp);
}

// Round 15
// 562.282 us; speedup vs baseline: 1.4153x; 1.0167x over previous
//
#include <hip/hip_runtime.h>
#include <stdint.h>

#define TT   12
#define BB   2
#define NN   1024
#define MM   2048
#define TM   24576      // TT*MM
#define DIN  64
#define DH   128
#define DOUT 32
#define CAP  64
#define NSPL 4
#define OUTSZ 786432

typedef __attribute__((ext_vector_type(8))) short short8;
typedef __attribute__((ext_vector_type(4))) short short4v;
typedef __attribute__((ext_vector_type(4))) float f32x4;

#define MFMA(a,b,c) __builtin_amdgcn_mfma_f32_16x16x32_bf16((a),(b),(c),0,0,0)

__device__ __forceinline__ float bf2f(unsigned short u){
  union { uint32_t i; float f; } x; x.i = ((uint32_t)u) << 16; return x.f;
}
__device__ __forceinline__ unsigned short f2bf(float f){
  union { float f; uint32_t i; } x; x.f = f;
  uint32_t u = x.i + 0x7FFFu + ((x.i >> 16) & 1u);   // RNE
  return (unsigned short)(u >> 16);
}
__device__ __forceinline__ float LD(const void* p, size_t i, int mode){
  return mode ? ((const float*)p)[i] : bf2f(((const unsigned short*)p)[i]);
}
// gather-load 8 input elements as bf16 (mode 1 = fp32 source)
__device__ __forceinline__ short8 ldx8(const void* x, size_t off, int md){
  if(md){
    const float4* xf = (const float4*)((const float*)x + off);
    float4 a = xf[0], b = xf[1];
    short8 o;
    o[0]=(short)f2bf(a.x); o[1]=(short)f2bf(a.y); o[2]=(short)f2bf(a.z); o[3]=(short)f2bf(a.w);
    o[4]=(short)f2bf(b.x); o[5]=(short)f2bf(b.y); o[6]=(short)f2bf(b.z); o[7]=(short)f2bf(b.w);
    return o;
  }
  return *(const short8*)((const unsigned short*)x + off);
}

// ---------------- fill (fp32, sentinels only) ----------------
__global__ void k_fill(float* __restrict__ out, int n, float val){
  int i = blockIdx.x*blockDim.x + threadIdx.x;
  if(i < n) out[i] = val;
}

// ---------------- fused detectors: block 0 = x dtype (+nact zero), block 1 = mask dtype ----------------
__global__ void k_detect2(const unsigned short* __restrict__ x,
                          const unsigned char* __restrict__ eg,
                          int* __restrict__ dtf, int* __restrict__ flag,
                          int* __restrict__ nact){
  if(blockIdx.x == 0){
    __shared__ int cnt_s;
    if(threadIdx.x==0) cnt_s = 0;
    if(threadIdx.x < TT) nact[threadIdx.x] = 0;
    __syncthreads();
    int c = 0;
    for(int i=threadIdx.x; i<6144; i+=blockDim.x){
      unsigned short h = x[i*2];
      unsigned e = (h >> 7) & 0xFF;
      if(h==0 || (e >= 0x60 && e <= 0x9F)) c++;
    }
    atomicAdd(&cnt_s, c);
    __syncthreads();
    if(threadIdx.x==0) *dtf = (cnt_s > 4000) ? 0 : 1;   // 0=bf16, 1=fp32
  } else {
    __shared__ int pres_s, ge2_s;
    if(threadIdx.x==0){ pres_s=0; ge2_s=0; }
    __syncthreads();
    int pres=0, ge2=0;
    for(int i=threadIdx.x; i<24576; i+=blockDim.x){
      unsigned v = eg[i];
      if(v){ pres |= 1 << (i & 7); if(v >= 2u) ge2 = 1; }
    }
    if(pres) atomicOr(&pres_s, pres);
    if(ge2)  atomicOr(&ge2_s, 1);
    __syncthreads();
    if(threadIdx.x==0){
      int pr = pres_s, g2 = ge2_s, mode;
      if(!g2){
        if((pr & ~0x01) == 0)      mode = 4;   // i64
        else if((pr & ~0x11) == 0) mode = 0;   // i32
        else                       mode = 1;   // u8
      } else {
        if((pr & ~0xC0) == 0)      mode = 5;   // f64
        else if((pr & ~0xCC) == 0) mode = 3;   // f32
        else                       mode = 2;   // bf16
      }
      *flag = mode;
    }
  }
}

// mask decode + wave-ballot compaction + d_out zero (grid covers OUTSZ)
__global__ void k_mask(const void* __restrict__ egom, const int* __restrict__ flag,
                       int* __restrict__ cnt, int* __restrict__ nact,
                       int* __restrict__ aidx, int* __restrict__ inv,
                       float* __restrict__ out){
  int idx = blockIdx.x*blockDim.x + threadIdx.x;   // < OUTSZ
  out[idx] = 0.f;                                  // inactive nodes stay 0
  if(idx >= TM) return;
  int t = idx / MM, node = idx % MM;               // wave = 64 consecutive nodes, one t
  int b = node / NN, n = node % NN;
  int src = (b*TT + t)*NN + n;
  int mode = *flag;
  int v;
  if(mode==0)      v = ((const int*)egom)[src] != 0;
  else if(mode==1) v = ((const unsigned char*)egom)[src] != 0;
  else if(mode==2) v = ((const unsigned short*)egom)[src] != 0;
  else if(mode==3) v = ((const float*)egom)[src] != 0.f;
  else if(mode==4) v = ((const long long*)egom)[src] != 0;
  else             v = ((const double*)egom)[src] != 0.0;
  cnt[idx] = 0;
  unsigned long long bal = __ballot(v != 0);
  int lane = threadIdx.x & 63;
  int base = 0;
  if(lane == 0 && bal) base = atomicAdd(&nact[t], __popcll(bal));
  base = __shfl(base, 0, 64);
  int ic = -1;
  if(v){
    int pfx = __popcll(bal & ((1ULL << lane) - 1ULL));
    ic = base + pfx;
    aidx[(size_t)t*MM + ic] = node;
  }
  inv[idx] = ic;
}

// ---------------- weight prep: coalesced-read transposes + folded weights/biases ----------------
__global__ void k_prepw(
  const void* __restrict__ w1, const void* __restrict__ w2,
  const void* __restrict__ qw, const void* __restrict__ kw, const void* __restrict__ vw,
  const void* __restrict__ qb0, const void* __restrict__ kb0, const void* __restrict__ vb0,
  const void* __restrict__ ow, const void* __restrict__ ob,
  const void* __restrict__ fw, const void* __restrict__ fb,
  const void* __restrict__ tw, const void* __restrict__ tb,
  const void* __restrict__ b1, const void* __restrict__ b2,
  const int* __restrict__ dtf,
  unsigned short* __restrict__ W1t, unsigned short* __restrict__ W2t,
  unsigned short* __restrict__ Wqt, unsigned short* __restrict__ Wkt,
  unsigned short* __restrict__ Wvt, unsigned short* __restrict__ Wct,
  float* __restrict__ qbf, float* __restrict__ kbf, float* __restrict__ vbf,
  float* __restrict__ bcf, float* __restrict__ b1f, float* __restrict__ b2f)
{
  const int md = *dtf;
  int id = blockIdx.x*blockDim.x + threadIdx.x;
  if(id < 8192){  // coalesced read: consecutive id -> consecutive n
    int n=id&127, k2=id>>7; W1t[n*64+k2]=f2bf(LD(w1,(size_t)k2*128+n,md)); return; }
  id -= 8192;
  if(id < 16384){ int n=id&127,k2=id>>7; W2t[n*128+k2]=f2bf(LD(w2,(size_t)k2*128+n,md)); return; }
  id -= 16384;
  if(id < 16384){ int n=id&127,k2=id>>7; Wqt[n*128+k2]=f2bf(LD(qw,(size_t)k2*128+n,md)); return; }
  id -= 16384;
  if(id < 16384){ int n=id&127,k2=id>>7; Wkt[n*128+k2]=f2bf(LD(kw,(size_t)k2*128+n,md)); return; }
  id -= 16384;
  if(id < 16384){ int n=id&127,k2=id>>7; Wvt[n*128+k2]=f2bf(LD(vw,(size_t)k2*128+n,md)); return; }
  id -= 16384;
  if(id < 4096){  // Wc = o_w @ fc_w, stored [oc][c]; ow broadcast, fw coalesced
    int oc=id&31, c=id>>5; float s=0.f;
    for(int r=0;r<128;r++) s += LD(ow,(size_t)c*128+r,md)*LD(fw,(size_t)r*32+oc,md);
    Wct[oc*128+c]=f2bf(s); return;
  }
  id -= 4096;
  if(id < 32){    // bc = o_b @ fc_w + fc_b
    float s = LD(fb,id,md);
    for(int r=0;r<128;r++) s += LD(ob,r,md)*LD(fw,(size_t)r*32+id,md);
    bcf[id]=s; return;
  }
  id -= 32;
  if(id < 4608){  // per-t fused QKV bias: b + t_vec @ W[128:144]
    int which = id/1536, rem=id%1536, t=rem/128, n=rem%128;
    const void* W  = which==0?qw:(which==1?kw:vw);
    const void* Bs = which==0?qb0:(which==1?kb0:vb0);
    float s = LD(Bs,n,md);
    for(int d=0;d<16;d++){
      float tv = sinf((float)t*LD(tw,d,md) + LD(tb,d,md));
      s += tv * LD(W,(size_t)(128+d)*128+n,md);
    }
    float* dst = which==0?qbf:(which==1?kbf:vbf);
    dst[t*128+n]=s; return;
  }
  id -= 4608;
  if(id < 256){   // GCN biases to fp32
    if(id<128) b1f[id] = LD(b1,id,md);
    else       b2f[id-128] = LD(b2,id-128,md);
    return;
  }
}

// ---------------- edge-list build: compact source+target ----------------
__global__ __launch_bounds__(256) void k_edges(const void* __restrict__ A,
    const int* __restrict__ dtf, const int* __restrict__ inv,
    int* __restrict__ cnt, int* __restrict__ edges){
  int id = blockIdx.x*blockDim.x + threadIdx.x;   // TM*64 threads
  int seg = id & 63; int row = id >> 6;           // row = t*MM + j (orig)
  int t = row / MM;
  int jc = inv[row];
  if(jc < 0) return;                              // inactive source
  const int* invt = inv + (size_t)t*MM;
  int* cb = cnt + (size_t)t*MM;
  int* eb = edges + (size_t)t*MM*CAP;
  if(*dtf){   // fp32 adjacency
    const float4* p4 = (const float4*)((const float*)A + (size_t)row*MM + seg*32);
    #pragma unroll
    for(int u=0;u<8;u++){
      float4 v = p4[u];
      float wd[4]={v.x,v.y,v.z,v.w};
      #pragma unroll
      for(int q=0;q<4;q++){
        if(wd[q]!=0.f){
          int ibc = invt[seg*32 + u*4 + q];
          if(ibc >= 0){ int s=atomicAdd(&cb[ibc],1); if(s<CAP) eb[(size_t)ibc*CAP+s]=jc; }
        }
      }
    }
  } else {    // bf16 adjacency
    const uint4* p4 = (const uint4*)((const unsigned short*)A + (size_t)row*MM + seg*32);
    #pragma unroll
    for(int u=0;u<4;u++){
      uint4 v = p4[u];
      unsigned wd[4]={v.x,v.y,v.z,v.w};
      #pragma unroll
      for(int q=0;q<4;q++){
        int ib = seg*32 + u*8 + q*2;
        if(wd[q] & 0xFFFFu){
          int ibc = invt[ib];
          if(ibc >= 0){ int s=atomicAdd(&cb[ibc],1); if(s<CAP) eb[(size_t)ibc*CAP+s]=jc; }
        }
        if(wd[q] >> 16){
          int ibc = invt[ib+1];
          if(ibc >= 0){ int s=atomicAdd(&cb[ibc],1); if(s<CAP) eb[(size_t)ibc*CAP+s]=jc; }
        }
      }
    }
  }
}

// ---------------- GEMM-1: gather x rows via aidx + convert + GEMM (W1t [128][64]) ----------------
__global__ __launch_bounds__(256) void k_gemm_x(const void* __restrict__ x,
    const int* __restrict__ dtf, const int* __restrict__ nact,
    const int* __restrict__ aidx, const unsigned short* __restrict__ Wt,
    float* __restrict__ g)
{
  const int tile = blockIdx.x*64;
  const int t = tile / MM, il = tile % MM;
  const int na = nact[t];
  if(il >= ((na+63)&~63)) return;
  const int md = *dtf;
  const int tid=threadIdx.x, wv=tid>>6, lane=tid&63, l15=lane&15, quad=lane>>4;
  const int r0 = tile + (wv>>1)*32;          // global compact row base
  const int c0 = (wv&1)*64;
  short8 bf[2][4];
  #pragma unroll
  for(int kk=0;kk<2;kk++)
    #pragma unroll
    for(int nt=0;nt<4;nt++)
      bf[kk][nt] = *(const short8*)(Wt + (size_t)(c0+nt*16+l15)*DIN + kk*32 + quad*8);
  // gather rows (pad rows read compact row 0 -- finite, outputs unread)
  const int il0 = (r0 % MM) + l15, il1 = (r0 % MM) + 16 + l15;
  const int n0 = aidx[(size_t)t*MM + (il0 < na ? il0 : 0)];
  const int n1 = aidx[(size_t)t*MM + (il1 < na ? il1 : 0)];
  const size_t xb0 = ((size_t)t*MM + n0)*DIN;
  const size_t xb1 = ((size_t)t*MM + n1)*DIN;
  f32x4 z = {0.f,0.f,0.f,0.f};
  f32x4 acc[2][4];
  #pragma unroll
  for(int i=0;i<2;i++){ acc[i][0]=z; acc[i][1]=z; acc[i][2]=z; acc[i][3]=z; }
  #pragma unroll
  for(int kk=0;kk<2;kk++){
    short8 a0 = ldx8(x, xb0 + kk*32 + quad*8, md);
    short8 a1 = ldx8(x, xb1 + kk*32 + quad*8, md);
    #pragma unroll
    for(int nt=0;nt<4;nt++){
      acc[0][nt]=MFMA(a0,bf[kk][nt],acc[0][nt]);
      acc[1][nt]=MFMA(a1,bf[kk][nt],acc[1][nt]);
    }
  }
  #pragma unroll
  for(int mt=0;mt<2;mt++)
    #pragma unroll
    for(int nt=0;nt<4;nt++){
      int col = c0+nt*16+l15;
      #pragma unroll
      for(int r=0;r<4;r++){
        int row = r0 + mt*16 + quad*4 + r;
        g[(size_t)row*DH + col] = acc[mt][nt][r];
      }
    }
}

// ---------------- dense GEMM on compact rows (h -> g), KD=128 ----------------
__global__ __launch_bounds__(256) void k_gemm_h(const unsigned short* __restrict__ X,
    const unsigned short* __restrict__ Wt, float* __restrict__ g,
    const int* __restrict__ nact)
{
  const int tile = blockIdx.x*64;
  const int t = tile / MM, il = tile % MM;
  const int na = nact[t];
  if(il >= ((na+63)&~63)) return;
  const int tid=threadIdx.x, wv=tid>>6, lane=tid&63, l15=lane&15, quad=lane>>4;
  const int r0 = tile + (wv>>1)*32;
  const int c0 = (wv&1)*64;
  short8 bf[4][4];
  #pragma unroll
  for(int kk=0;kk<4;kk++)
    #pragma unroll
    for(int nt=0;nt<4;nt++)
      bf[kk][nt] = *(const short8*)(Wt + (size_t)(c0+nt*16+l15)*DH + kk*32 + quad*8);
  f32x4 z = {0.f,0.f,0.f,0.f};
  f32x4 acc[2][4];
  #pragma unroll
  for(int i=0;i<2;i++){ acc[i][0]=z; acc[i][1]=z; acc[i][2]=z; acc[i][3]=z; }
  #pragma unroll
  for(int kk=0;kk<4;kk++){
    short8 a0 = *(const short8*)(X + (size_t)(r0+l15)*DH    + kk*32 + quad*8);
    short8 a1 = *(const short8*)(X + (size_t)(r0+16+l15)*DH + kk*32 + quad*8);
    #pragma unroll
    for(int nt=0;nt<4;nt++){
      acc[0][nt]=MFMA(a0,bf[kk][nt],acc[0][nt]);
      acc[1][nt]=MFMA(a1,bf[kk][nt],acc[1][nt]);
    }
  }
  #pragma unroll
  for(int mt=0;mt<2;mt++)
    #pragma unroll
    for(int nt=0;nt<4;nt++){
      int col = c0+nt*16+l15;
      #pragma unroll
      for(int r=0;r<4;r++){
        int row = r0 + mt*16 + quad*4 + r;
        g[(size_t)row*DH + col] = acc[mt][nt][r];
      }
    }
}

// ---------------- sparse GCN aggregation on compact rows -> h (bf16) ----------------
__global__ __launch_bounds__(256) void k_gather(const float* __restrict__ g,
    const int* __restrict__ edges, const int* __restrict__ cnt,
    const int* __restrict__ nact, const float* __restrict__ bias,
    unsigned short* __restrict__ h)
{
  int wv = threadIdx.x>>6, lane = threadIdx.x&63;
  int gi = blockIdx.x*4 + wv;           // compact row, < TM
  int t = gi / MM, ic = gi % MM;
  int na = nact[t];
  if(ic >= ((na+63)&~63)) return;
  if(ic >= na){                         // pad row: finite zeros
    h[(size_t)gi*DH + lane] = 0; h[(size_t)gi*DH + 64 + lane] = 0;
    return;
  }
  float a0=0.f, a1=0.f;
  int cn = cnt[gi]; if(cn>CAP) cn=CAP;
  const int* eb = edges + (size_t)gi*CAP;
  for(int e=0;e<cn;e++){
    int jc = eb[e];
    float nj = rsqrtf((float)cnt[(size_t)t*MM+jc] + 1.f);
    const float* gr = g + ((size_t)t*MM + jc)*DH;
    a0 += nj*gr[lane]; a1 += nj*gr[64+lane];
  }
  float ni = rsqrtf((float)cn + 1.f);
  const float* gs = g + (size_t)gi*DH;
  float h0 = ni*(a0 + ni*gs[lane])    + bias[lane];
  float h1 = ni*(a1 + ni*gs[64+lane]) + bias[64+lane];
  h0 = h0>0.f?h0:0.f; h1 = h1>0.f?h1:0.f;
  h[(size_t)gi*DH + lane]      = f2bf(h0);
  h[(size_t)gi*DH + 64 + lane] = f2bf(h1);
}

// ---------------- Q/K/V GEMMs: Q,K row-major; V written TRANSPOSED directly ----------------
__global__ __launch_bounds__(256) void k_gemm_qkv(const unsigned short* __restrict__ X,
    const unsigned short* __restrict__ Wq, const unsigned short* __restrict__ Wk,
    const unsigned short* __restrict__ Wv,
    const float* __restrict__ qb, const float* __restrict__ kb, const float* __restrict__ vb,
    unsigned short* __restrict__ Qo, unsigned short* __restrict__ Ko,
    unsigned short* __restrict__ Vtc, const int* __restrict__ nact)
{
  const int tile = blockIdx.x*64;
  const int t = tile / MM, il = tile % MM;
  const int na = nact[t];
  if(il >= ((na+63)&~63)) return;
  const int which = blockIdx.z;
  const unsigned short* Wt = which==0?Wq:(which==1?Wk:Wv);
  const float* bias = which==0?qb:(which==1?kb:vb);
  const int tid=threadIdx.x, wv=tid>>6, lane=tid&63, l15=lane&15, quad=lane>>4;
  const int r0 = tile + (wv>>1)*32;
  const int c0 = (wv&1)*64;
  short8 bf[4][4];
  #pragma unroll
  for(int kk=0;kk<4;kk++)
    #pragma unroll
    for(int nt=0;nt<4;nt++)
      bf[kk][nt] = *(const short8*)(Wt + (size_t)(c0+nt*16+l15)*DH + kk*32 + quad*8);
  f32x4 z = {0.f,0.f,0.f,0.f};
  f32x4 acc[2][4];
  #pragma unroll
  for(int i=0;i<2;i++){ acc[i][0]=z; acc[i][1]=z; acc[i][2]=z; acc[i][3]=z; }
  #pragma unroll
  for(int kk=0;kk<4;kk++){
    short8 a0 = *(const short8*)(X + (size_t)(r0+l15)*DH    + kk*32 + quad*8);
    short8 a1 = *(const short8*)(X + (size_t)(r0+16+l15)*DH + kk*32 + quad*8);
    #pragma unroll
    for(int nt=0;nt<4;nt++){
      acc[0][nt]=MFMA(a0,bf[kk][nt],acc[0][nt]);
      acc[1][nt]=MFMA(a1,bf[kk][nt],acc[1][nt]);
    }
  }
  if(which < 2){
    unsigned short* o = which==0 ? Qo : Ko;
    #pragma unroll
    for(int mt=0;mt<2;mt++)
      #pragma unroll
      for(int nt=0;nt<4;nt++){
        int col = c0+nt*16+l15;
        float bb = bias[t*DH+col];
        #pragma unroll
        for(int r=0;r<4;r++){
          int row = r0 + mt*16 + quad*4 + r;
          o[(size_t)row*DH + col] = f2bf(acc[mt][nt][r] + bb);
        }
      }
  } else {
    #pragma unroll
    for(int mt=0;mt<2;mt++)
      #pragma unroll
      for(int nt=0;nt<4;nt++){
        int col = c0+nt*16+l15;
        float bb = bias[t*DH+col];
        int node0 = il + (wv>>1)*32 + mt*16 + quad*4;   // compact local row
        short4v pk;
        #pragma unroll
        for(int r=0;r<4;r++) pk[r] = (short)f2bf(acc[mt][nt][r] + bb);
        *(short4v*)(Vtc + ((size_t)t*DH + col)*MM + node0) = pk;
      }
  }
}

// ---------------- attention, key-split, compact queries+keys ----------------
__global__ __launch_bounds__(64) void k_attn_split(
  const unsigned short* __restrict__ Q, const unsigned short* __restrict__ Kc,
  const unsigned short* __restrict__ Vtc, const int* __restrict__ nact,
  float* __restrict__ part, float* __restrict__ lpart)
{
  __shared__ short Pl[16][72];
  const int lane=threadIdx.x&63, l15=lane&15, quad=lane>>4;
  const int t = blockIdx.y;
  const int qbase = blockIdx.x*16;
  const int z = blockIdx.z;
  const float scale = 0.088388347648318447f;  // 1/sqrt(128)
  const int na = nact[t];
  if(qbase >= na) return;                     // wave-uniform exit
  const int nkt = (na + 63) >> 6;
  const int chunk = (nkt + NSPL - 1) / NSPL;
  const int kt0 = z*chunk;
  int kt1 = kt0 + chunk; if(kt1 > nkt) kt1 = nkt;

  short8 bq[4];
  #pragma unroll
  for(int kk=0;kk<4;kk++)
    bq[kk] = *(const short8*)(Q + ((size_t)t*MM + qbase + l15)*DH + kk*32 + quad*8);

  f32x4 zz = {0.f,0.f,0.f,0.f};
  f32x4 accPV[8];
  #pragma unroll
  for(int i=0;i<8;i++) accPV[i]=zz;
  float l_run = 0.f;

  for(int kt=kt0; kt<kt1; kt++){
    const int key0 = kt*64;
    #pragma unroll
    for(int mt=0;mt<4;mt++){
      f32x4 s = zz;
      const unsigned short* Krow = Kc + ((size_t)t*MM + key0 + mt*16 + l15)*DH;
      #pragma unroll
      for(int kk=0;kk<4;kk++){
        short8 ak = *(const short8*)(Krow + kk*32 + quad*8);
        s = MFMA(ak, bq[kk], s);
      }
      short4v pk;
      #pragma unroll
      for(int r=0;r<4;r++){
        float sv = fminf(fmaxf(s[r]*scale, -15.f), 15.f);
        float valid = (key0 + mt*16 + quad*4 + r < na) ? 1.f : 0.f;
        float p = __expf(sv) * valid;
        pk[r] = (short)f2bf(p);
        l_run += bf2f((unsigned short)pk[r]);
      }
      *(short4v*)&Pl[l15][mt*16 + quad*4] = pk;
    }
    #pragma unroll
    for(int kk=0;kk<2;kk++){
      short8 ap = *(const short8*)&Pl[l15][kk*32 + quad*8];
      const unsigned short* Vb = Vtc + (size_t)t*DH*MM + key0 + kk*32 + quad*8;
      #pragma unroll
      for(int nt=0;nt<8;nt++){
        short8 bv = *(const short8*)(Vb + (size_t)(nt*16 + l15)*MM);
        accPV[nt] = MFMA(ap, bv, accPV[nt]);
      }
    }
  }
  l_run += __shfl_xor(l_run, 16, 64);
  l_run += __shfl_xor(l_run, 32, 64);

  const size_t pbase = (size_t)(z*TT + t)*MM + qbase;
  #pragma unroll
  for(int nt=0;nt<8;nt++)
    #pragma unroll
    for(int r=0;r<4;r++)
      part[(pbase + quad*4 + r)*128 + nt*16 + l15] = accPV[nt][r];
  if(lane < 16) lpart[pbase + lane] = l_run;
}

// ---------------- attention combine + final projection, scatter to orig nodes ----------------
// NOTE: no per-lane early return before the MFMA loop (round-13 NaN lesson).
__global__ __launch_bounds__(64) void k_attn_fin(
  const float* __restrict__ part, const float* __restrict__ lpart,
  const int* __restrict__ aidx, const int* __restrict__ nact,
  const unsigned short* __restrict__ Wct, const float* __restrict__ bc,
  float* __restrict__ out)
{
  __shared__ short Al[16][136];
  __shared__ float lbuf[16];
  const int lane=threadIdx.x&63, l15=lane&15, quad=lane>>4;
  const int t = blockIdx.y, qbase = blockIdx.x*16;
  const int na = nact[t];
  if(qbase >= na) return;                    // wave-uniform: safe
  f32x4 acc4[8];
  f32x4 zz = {0.f,0.f,0.f,0.f};
  #pragma unroll
  for(int i=0;i<8;i++) acc4[i]=zz;
  #pragma unroll
  for(int s=0;s<NSPL;s++){
    const float* pb = part + ((size_t)(s*TT + t)*MM + qbase)*128;
    #pragma unroll
    for(int i=0;i<8;i++){
      int flat = i*64 + lane;
      int q = flat >> 5, c4 = (flat & 31) << 2;
      acc4[i] += *(const f32x4*)(pb + q*128 + c4);
    }
  }
  if(lane < 16){
    float ls = 0.f;
    #pragma unroll
    for(int s=0;s<NSPL;s++) ls += lpart[(size_t)(s*TT + t)*MM + qbase + lane];
    lbuf[lane] = ls;
  }
  #pragma unroll
  for(int i=0;i<8;i++){
    int flat = i*64 + lane;
    int q = flat >> 5, c4 = (flat & 31) << 2;
    short4v pk;
    #pragma unroll
    for(int r=0;r<4;r++){
      float av = fminf(fmaxf(acc4[i][r], -1e30f), 1e30f);
      pk[r] = (short)f2bf(av);
    }
    *(short4v*)&Al[q][c4] = pk;
  }
  __syncthreads();

  const int qc = qbase + l15;
  const bool qok = (qc < na);                // predicate stores only
  const float lsv = lbuf[l15];
  const float linv = (lsv > 0.f) ? 1.f/lsv : 0.f;
  const int node = aidx[(size_t)t*MM + (qok ? qc : 0)];
  #pragma unroll
  for(int mt2=0;mt2<2;mt2++){
    f32x4 d = zz;
    #pragma unroll
    for(int kk=0;kk<4;kk++){
      short8 aw = *(const short8*)(Wct + (size_t)(mt2*16+l15)*DH + kk*32 + quad*8);
      short8 bl = *(const short8*)&Al[l15][kk*32 + quad*8];
      d = MFMA(aw, bl, d);
    }
    f32x4 bcv = *(const f32x4*)(bc + mt2*16 + quad*4);
    f32x4 o4;
    #pragma unroll
    for(int r=0;r<4;r++) o4[r] = d[r]*linv + bcv[r];
    if(qok)
      *(f32x4*)(out + (size_t)node*(TT*DOUT) + (size_t)t*DOUT + mt2*16 + quad*4) = o4;
  }
}

// ---------------- launch ----------------
extern "C" void kernel_launch(void* const* d_in, const int* in_sizes, int n_in,
                              void* d_out, int out_size, void* d_ws, size_t ws_size,
                              hipStream_t stream)
{
  float* outp = (float*)d_out;   // reference output dtype is float32
  static const int EXP[19] = {1572864,50331648,24576,8192,128,16384,128,16,16,
                              18432,128,18432,128,18432,128,16384,128,4096,32};
  bool ok = (n_in >= 19) && (out_size == OUTSZ);
  if(ok) for(int i=0;i<19;i++) if(in_sizes[i] != EXP[i]) { ok = false; break; }
  if(!ok){
    k_fill<<<(out_size+255)/256,256,0,stream>>>(outp, out_size, 1000.f);
    return;
  }
  const void* x   = d_in[0];
  const void* A   = d_in[1];
  const void* eg  = d_in[2];
  const void* w1  = d_in[3];
  const void* b1  = d_in[4];
  const void* w2  = d_in[5];
  const void* b2  = d_in[6];
  const void* tw  = d_in[7];
  const void* tb  = d_in[8];
  const void* qw  = d_in[9];
  const void* qb0 = d_in[10];
  const void* kw  = d_in[11];
  const void* kb0 = d_in[12];
  const void* vw  = d_in[13];
  const void* vb0 = d_in[14];
  const void* ow  = d_in[15];
  const void* ob  = d_in[16];
  const void* fw  = d_in[17];
  const void* fb  = d_in[18];

  char* w = (char*)d_ws;
  size_t off = 0;
  auto alloc = [&](size_t sz)->char*{
    char* p = w + off; off = (off + sz + 255) & ~(size_t)255; return p; };
  int*   flag  = (int*)  alloc(4);
  int*   dtf   = (int*)  alloc(4);
  int*   nactb = (int*)  alloc(TT*4);
  int*   cnt   = (int*)  alloc((size_t)TM*4);
  int*   aidx  = (int*)  alloc((size_t)TM*4);
  int*   inv   = (int*)  alloc((size_t)TM*4);
  int*   edges = (int*)  alloc((size_t)TM*CAP*4);
  float* g     = (float*)alloc((size_t)TM*DH*4);   // reused as Qb+Kb after 2nd gather
  unsigned short* h   = (unsigned short*)alloc((size_t)TM*DH*2);
  unsigned short* Vtc = (unsigned short*)alloc((size_t)TT*DH*MM*2);
  unsigned short* W1t = (unsigned short*)alloc(DH*DIN*2);
  unsigned short* W2t = (unsigned short*)alloc(DH*DH*2);
  unsigned short* Wqt = (unsigned short*)alloc(DH*DH*2);
  unsigned short* Wkt = (unsigned short*)alloc(DH*DH*2);
  unsigned short* Wvt = (unsigned short*)alloc(DH*DH*2);
  unsigned short* Wct = (unsigned short*)alloc(DOUT*DH*2);
  float* qbf = (float*)alloc(TT*DH*4);
  float* kbf = (float*)alloc(TT*DH*4);
  float* vbf = (float*)alloc(TT*DH*4);
  float* bcf = (float*)alloc(DOUT*4);
  float* b1f = (float*)alloc(DH*4);
  float* b2f = (float*)alloc(DH*4);
  float* part  = (float*)alloc((size_t)NSPL*TM*DH*4);
  float* lpart = (float*)alloc((size_t)NSPL*TM*4);
  if(off > ws_size){
    k_fill<<<(out_size+255)/256,256,0,stream>>>(outp, out_size, 500.f);
    return;
  }

  unsigned short* Qb = (unsigned short*)g;                       // TM*DH*2 bytes
  unsigned short* Kb = (unsigned short*)((char*)g + (size_t)TM*DH*2);

  k_detect2<<<2,256,0,stream>>>((const unsigned short*)x, (const unsigned char*)eg,
                                dtf, flag, nactb);
  k_mask<<<OUTSZ/256,256,0,stream>>>(eg, flag, cnt, nactb, aidx, inv, outp);
  k_prepw<<<(82720+255)/256,256,0,stream>>>(w1,w2,qw,kw,vw,qb0,kb0,vb0,ow,ob,fw,fb,tw,tb,
                                            b1,b2,dtf,
                                            W1t,W2t,Wqt,Wkt,Wvt,Wct,qbf,kbf,vbf,bcf,b1f,b2f);
  k_edges<<<TM*64/256,256,0,stream>>>(A, dtf, inv, cnt, edges);
  k_gemm_x<<<TM/64,256,0,stream>>>(x, dtf, nactb, aidx, W1t, g);
  k_gather<<<TM/4,256,0,stream>>>(g, edges, cnt, nactb, b1f, h);
  k_gemm_h<<<TM/64,256,0,stream>>>(h, W2t, g, nactb);
  k_gather<<<TM/4,256,0,stream>>>(g, edges, cnt, nactb, b2f, h);
  k_gemm_qkv<<<dim3(TM/64,1,3),256,0,stream>>>(h, Wqt,Wkt,Wvt, qbf,kbf,vbf, Qb,Kb,Vtc, nactb);
  k_attn_split<<<dim3(MM/16,TT,NSPL),64,0,stream>>>(Qb, Kb, Vtc, nactb, part, lpart);
  k_attn_fin<<<dim3(MM/16,TT),64,0,stream>>>(part, lpart, aidx, nactb, Wct, bcf, outp);
}

// Round 16
// 541.018 us; speedup vs baseline: 1.4709x; 1.0393x over previous
//
#include <hip/hip_runtime.h>
#include <stdint.h>

#define TT   12
#define BB   2
#define NN   1024
#define MM   2048
#define TM   24576      // TT*MM
#define DIN  64
#define DH   128
#define DOUT 32
#define CAP  64
#define NSPL 4
#define OUTSZ 786432

typedef __attribute__((ext_vector_type(8))) short short8;
typedef __attribute__((ext_vector_type(4))) short short4v;
typedef __attribute__((ext_vector_type(4))) float f32x4;

#define MFMA(a,b,c) __builtin_amdgcn_mfma_f32_16x16x32_bf16((a),(b),(c),0,0,0)

__device__ __forceinline__ float bf2f(unsigned short u){
  union { uint32_t i; float f; } x; x.i = ((uint32_t)u) << 16; return x.f;
}
__device__ __forceinline__ unsigned short f2bf(float f){
  union { float f; uint32_t i; } x; x.f = f;
  uint32_t u = x.i + 0x7FFFu + ((x.i >> 16) & 1u);   // RNE
  return (unsigned short)(u >> 16);
}
__device__ __forceinline__ float LD(const void* p, size_t i, int mode){
  return mode ? ((const float*)p)[i] : bf2f(((const unsigned short*)p)[i]);
}
// gather-load 8 input elements as bf16 (mode 1 = fp32 source)
__device__ __forceinline__ short8 ldx8(const void* x, size_t off, int md){
  if(md){
    const float4* xf = (const float4*)((const float*)x + off);
    float4 a = xf[0], b = xf[1];
    short8 o;
    o[0]=(short)f2bf(a.x); o[1]=(short)f2bf(a.y); o[2]=(short)f2bf(a.z); o[3]=(short)f2bf(a.w);
    o[4]=(short)f2bf(b.x); o[5]=(short)f2bf(b.y); o[6]=(short)f2bf(b.z); o[7]=(short)f2bf(b.w);
    return o;
  }
  return *(const short8*)((const unsigned short*)x + off);
}

// ---------------- fill (fp32, sentinels only) ----------------
__global__ void k_fill(float* __restrict__ out, int n, float val){
  int i = blockIdx.x*blockDim.x + threadIdx.x;
  if(i < n) out[i] = val;
}

// ---------------- fused detectors: block 0 = x dtype (+nact zero), block 1 = mask dtype ----------------
__global__ void k_detect2(const unsigned short* __restrict__ x,
                          const unsigned char* __restrict__ eg,
                          int* __restrict__ dtf, int* __restrict__ flag,
                          int* __restrict__ nact){
  if(blockIdx.x == 0){
    __shared__ int cnt_s;
    if(threadIdx.x==0) cnt_s = 0;
    if(threadIdx.x < TT) nact[threadIdx.x] = 0;
    __syncthreads();
    int c = 0;
    for(int i=threadIdx.x; i<6144; i+=blockDim.x){
      unsigned short h = x[i*2];
      unsigned e = (h >> 7) & 0xFF;
      if(h==0 || (e >= 0x60 && e <= 0x9F)) c++;
    }
    atomicAdd(&cnt_s, c);
    __syncthreads();
    if(threadIdx.x==0) *dtf = (cnt_s > 4000) ? 0 : 1;   // 0=bf16, 1=fp32
  } else {
    __shared__ int pres_s, ge2_s;
    if(threadIdx.x==0){ pres_s=0; ge2_s=0; }
    __syncthreads();
    int pres=0, ge2=0;
    for(int i=threadIdx.x; i<24576; i+=blockDim.x){
      unsigned v = eg[i];
      if(v){ pres |= 1 << (i & 7); if(v >= 2u) ge2 = 1; }
    }
    if(pres) atomicOr(&pres_s, pres);
    if(ge2)  atomicOr(&ge2_s, 1);
    __syncthreads();
    if(threadIdx.x==0){
      int pr = pres_s, g2 = ge2_s, mode;
      if(!g2){
        if((pr & ~0x01) == 0)      mode = 4;   // i64
        else if((pr & ~0x11) == 0) mode = 0;   // i32
        else                       mode = 1;   // u8
      } else {
        if((pr & ~0xC0) == 0)      mode = 5;   // f64
        else if((pr & ~0xCC) == 0) mode = 3;   // f32
        else                       mode = 2;   // bf16
      }
      *flag = mode;
    }
  }
}

// mask decode + wave-ballot compaction + d_out zero (grid covers OUTSZ)
__global__ void k_mask(const void* __restrict__ egom, const int* __restrict__ flag,
                       int* __restrict__ cnt, int* __restrict__ nact,
                       int* __restrict__ aidx, int* __restrict__ inv,
                       float* __restrict__ out){
  int idx = blockIdx.x*blockDim.x + threadIdx.x;   // < OUTSZ
  out[idx] = 0.f;                                  // inactive nodes stay 0
  if(idx >= TM) return;
  int t = idx / MM, node = idx % MM;               // wave = 64 consecutive nodes, one t
  int b = node / NN, n = node % NN;
  int src = (b*TT + t)*NN + n;
  int mode = *flag;
  int v;
  if(mode==0)      v = ((const int*)egom)[src] != 0;
  else if(mode==1) v = ((const unsigned char*)egom)[src] != 0;
  else if(mode==2) v = ((const unsigned short*)egom)[src] != 0;
  else if(mode==3) v = ((const float*)egom)[src] != 0.f;
  else if(mode==4) v = ((const long long*)egom)[src] != 0;
  else             v = ((const double*)egom)[src] != 0.0;
  cnt[idx] = 0;
  unsigned long long bal = __ballot(v != 0);
  int lane = threadIdx.x & 63;
  int base = 0;
  if(lane == 0 && bal) base = atomicAdd(&nact[t], __popcll(bal));
  base = __shfl(base, 0, 64);
  int ic = -1;
  if(v){
    int pfx = __popcll(bal & ((1ULL << lane) - 1ULL));
    ic = base + pfx;
    aidx[(size_t)t*MM + ic] = node;
  }
  inv[idx] = ic;
}

// ---------------- weight prep: coalesced-read transposes + folded weights/biases ----------------
__global__ void k_prepw(
  const void* __restrict__ w1, const void* __restrict__ w2,
  const void* __restrict__ qw, const void* __restrict__ kw, const void* __restrict__ vw,
  const void* __restrict__ qb0, const void* __restrict__ kb0, const void* __restrict__ vb0,
  const void* __restrict__ ow, const void* __restrict__ ob,
  const void* __restrict__ fw, const void* __restrict__ fb,
  const void* __restrict__ tw, const void* __restrict__ tb,
  const void* __restrict__ b1, const void* __restrict__ b2,
  const int* __restrict__ dtf,
  unsigned short* __restrict__ W1t, unsigned short* __restrict__ W2t,
  unsigned short* __restrict__ Wqt, unsigned short* __restrict__ Wkt,
  unsigned short* __restrict__ Wvt, unsigned short* __restrict__ Wct,
  float* __restrict__ qbf, float* __restrict__ kbf, float* __restrict__ vbf,
  float* __restrict__ bcf, float* __restrict__ b1f, float* __restrict__ b2f)
{
  const int md = *dtf;
  int id = blockIdx.x*blockDim.x + threadIdx.x;
  if(id < 8192){  // coalesced read: consecutive id -> consecutive n
    int n=id&127, k2=id>>7; W1t[n*64+k2]=f2bf(LD(w1,(size_t)k2*128+n,md)); return; }
  id -= 8192;
  if(id < 16384){ int n=id&127,k2=id>>7; W2t[n*128+k2]=f2bf(LD(w2,(size_t)k2*128+n,md)); return; }
  id -= 16384;
  if(id < 16384){ int n=id&127,k2=id>>7; Wqt[n*128+k2]=f2bf(LD(qw,(size_t)k2*128+n,md)); return; }
  id -= 16384;
  if(id < 16384){ int n=id&127,k2=id>>7; Wkt[n*128+k2]=f2bf(LD(kw,(size_t)k2*128+n,md)); return; }
  id -= 16384;
  if(id < 16384){ int n=id&127,k2=id>>7; Wvt[n*128+k2]=f2bf(LD(vw,(size_t)k2*128+n,md)); return; }
  id -= 16384;
  if(id < 4096){  // Wc = o_w @ fc_w, stored [oc][c]; ow broadcast, fw coalesced
    int oc=id&31, c=id>>5; float s=0.f;
    for(int r=0;r<128;r++) s += LD(ow,(size_t)c*128+r,md)*LD(fw,(size_t)r*32+oc,md);
    Wct[oc*128+c]=f2bf(s); return;
  }
  id -= 4096;
  if(id < 32){    // bc = o_b @ fc_w + fc_b
    float s = LD(fb,id,md);
    for(int r=0;r<128;r++) s += LD(ob,r,md)*LD(fw,(size_t)r*32+id,md);
    bcf[id]=s; return;
  }
  id -= 32;
  if(id < 4608){  // per-t fused QKV bias: b + t_vec @ W[128:144]
    int which = id/1536, rem=id%1536, t=rem/128, n=rem%128;
    const void* W  = which==0?qw:(which==1?kw:vw);
    const void* Bs = which==0?qb0:(which==1?kb0:vb0);
    float s = LD(Bs,n,md);
    for(int d=0;d<16;d++){
      float tv = sinf((float)t*LD(tw,d,md) + LD(tb,d,md));
      s += tv * LD(W,(size_t)(128+d)*128+n,md);
    }
    float* dst = which==0?qbf:(which==1?kbf:vbf);
    dst[t*128+n]=s; return;
  }
  id -= 4608;
  if(id < 256){   // GCN biases to fp32
    if(id<128) b1f[id] = LD(b1,id,md);
    else       b2f[id-128] = LD(b2,id-128,md);
    return;
  }
}

// ---------------- edge-list build: compact source+target ----------------
__global__ __launch_bounds__(256) void k_edges(const void* __restrict__ A,
    const int* __restrict__ dtf, const int* __restrict__ inv,
    int* __restrict__ cnt, int* __restrict__ edges){
  int id = blockIdx.x*blockDim.x + threadIdx.x;   // TM*64 threads
  int seg = id & 63; int row = id >> 6;           // row = t*MM + j (orig)
  int t = row / MM;
  int jc = inv[row];
  if(jc < 0) return;                              // inactive source
  const int* invt = inv + (size_t)t*MM;
  int* cb = cnt + (size_t)t*MM;
  int* eb = edges + (size_t)t*MM*CAP;
  if(*dtf){   // fp32 adjacency
    const float4* p4 = (const float4*)((const float*)A + (size_t)row*MM + seg*32);
    #pragma unroll
    for(int u=0;u<8;u++){
      float4 v = p4[u];
      float wd[4]={v.x,v.y,v.z,v.w};
      #pragma unroll
      for(int q=0;q<4;q++){
        if(wd[q]!=0.f){
          int ibc = invt[seg*32 + u*4 + q];
          if(ibc >= 0){ int s=atomicAdd(&cb[ibc],1); if(s<CAP) eb[(size_t)ibc*CAP+s]=jc; }
        }
      }
    }
  } else {    // bf16 adjacency
    const uint4* p4 = (const uint4*)((const unsigned short*)A + (size_t)row*MM + seg*32);
    #pragma unroll
    for(int u=0;u<4;u++){
      uint4 v = p4[u];
      unsigned wd[4]={v.x,v.y,v.z,v.w};
      #pragma unroll
      for(int q=0;q<4;q++){
        int ib = seg*32 + u*8 + q*2;
        if(wd[q] & 0xFFFFu){
          int ibc = invt[ib];
          if(ibc >= 0){ int s=atomicAdd(&cb[ibc],1); if(s<CAP) eb[(size_t)ibc*CAP+s]=jc; }
        }
        if(wd[q] >> 16){
          int ibc = invt[ib+1];
          if(ibc >= 0){ int s=atomicAdd(&cb[ibc],1); if(s<CAP) eb[(size_t)ibc*CAP+s]=jc; }
        }
      }
    }
  }
}

// ---------------- GEMM-1: gather x rows via aidx + convert + GEMM (W1t [128][64]) ----------------
__global__ __launch_bounds__(256) void k_gemm_x(const void* __restrict__ x,
    const int* __restrict__ dtf, const int* __restrict__ nact,
    const int* __restrict__ aidx, const unsigned short* __restrict__ Wt,
    float* __restrict__ g)
{
  const int tile = blockIdx.x*64;
  const int t = tile / MM, il = tile % MM;
  const int na = nact[t];
  if(il >= ((na+63)&~63)) return;
  const int md = *dtf;
  const int tid=threadIdx.x, wv=tid>>6, lane=tid&63, l15=lane&15, quad=lane>>4;
  const int r0 = tile + (wv>>1)*32;          // global compact row base
  const int c0 = (wv&1)*64;
  short8 bf[2][4];
  #pragma unroll
  for(int kk=0;kk<2;kk++)
    #pragma unroll
    for(int nt=0;nt<4;nt++)
      bf[kk][nt] = *(const short8*)(Wt + (size_t)(c0+nt*16+l15)*DIN + kk*32 + quad*8);
  // gather rows (pad rows read compact row 0 -- finite, outputs unread)
  const int il0 = (r0 % MM) + l15, il1 = (r0 % MM) + 16 + l15;
  const int n0 = aidx[(size_t)t*MM + (il0 < na ? il0 : 0)];
  const int n1 = aidx[(size_t)t*MM + (il1 < na ? il1 : 0)];
  const size_t xb0 = ((size_t)t*MM + n0)*DIN;
  const size_t xb1 = ((size_t)t*MM + n1)*DIN;
  f32x4 z = {0.f,0.f,0.f,0.f};
  f32x4 acc[2][4];
  #pragma unroll
  for(int i=0;i<2;i++){ acc[i][0]=z; acc[i][1]=z; acc[i][2]=z; acc[i][3]=z; }
  #pragma unroll
  for(int kk=0;kk<2;kk++){
    short8 a0 = ldx8(x, xb0 + kk*32 + quad*8, md);
    short8 a1 = ldx8(x, xb1 + kk*32 + quad*8, md);
    #pragma unroll
    for(int nt=0;nt<4;nt++){
      acc[0][nt]=MFMA(a0,bf[kk][nt],acc[0][nt]);
      acc[1][nt]=MFMA(a1,bf[kk][nt],acc[1][nt]);
    }
  }
  #pragma unroll
  for(int mt=0;mt<2;mt++)
    #pragma unroll
    for(int nt=0;nt<4;nt++){
      int col = c0+nt*16+l15;
      #pragma unroll
      for(int r=0;r<4;r++){
        int row = r0 + mt*16 + quad*4 + r;
        g[(size_t)row*DH + col] = acc[mt][nt][r];
      }
    }
}

// ---------------- dense GEMM on compact rows (h -> g), KD=128 ----------------
__global__ __launch_bounds__(256) void k_gemm_h(const unsigned short* __restrict__ X,
    const unsigned short* __restrict__ Wt, float* __restrict__ g,
    const int* __restrict__ nact)
{
  const int tile = blockIdx.x*64;
  const int t = tile / MM, il = tile % MM;
  const int na = nact[t];
  if(il >= ((na+63)&~63)) return;
  const int tid=threadIdx.x, wv=tid>>6, lane=tid&63, l15=lane&15, quad=lane>>4;
  const int r0 = tile + (wv>>1)*32;
  const int c0 = (wv&1)*64;
  short8 bf[4][4];
  #pragma unroll
  for(int kk=0;kk<4;kk++)
    #pragma unroll
    for(int nt=0;nt<4;nt++)
      bf[kk][nt] = *(const short8*)(Wt + (size_t)(c0+nt*16+l15)*DH + kk*32 + quad*8);
  f32x4 z = {0.f,0.f,0.f,0.f};
  f32x4 acc[2][4];
  #pragma unroll
  for(int i=0;i<2;i++){ acc[i][0]=z; acc[i][1]=z; acc[i][2]=z; acc[i][3]=z; }
  #pragma unroll
  for(int kk=0;kk<4;kk++){
    short8 a0 = *(const short8*)(X + (size_t)(r0+l15)*DH    + kk*32 + quad*8);
    short8 a1 = *(const short8*)(X + (size_t)(r0+16+l15)*DH + kk*32 + quad*8);
    #pragma unroll
    for(int nt=0;nt<4;nt++){
      acc[0][nt]=MFMA(a0,bf[kk][nt],acc[0][nt]);
      acc[1][nt]=MFMA(a1,bf[kk][nt],acc[1][nt]);
    }
  }
  #pragma unroll
  for(int mt=0;mt<2;mt++)
    #pragma unroll
    for(int nt=0;nt<4;nt++){
      int col = c0+nt*16+l15;
      #pragma unroll
      for(int r=0;r<4;r++){
        int row = r0 + mt*16 + quad*4 + r;
        g[(size_t)row*DH + col] = acc[mt][nt][r];
      }
    }
}

// ---------------- sparse GCN aggregation on compact rows -> h (bf16) ----------------
__global__ __launch_bounds__(256) void k_gather(const float* __restrict__ g,
    const int* __restrict__ edges, const int* __restrict__ cnt,
    const int* __restrict__ nact, const float* __restrict__ bias,
    unsigned short* __restrict__ h)
{
  int wv = threadIdx.x>>6, lane = threadIdx.x&63;
  int gi = blockIdx.x*4 + wv;           // compact row, < TM
  int t = gi / MM, ic = gi % MM;
  int na = nact[t];
  if(ic >= ((na+63)&~63)) return;
  if(ic >= na){                         // pad row: finite zeros
    h[(size_t)gi*DH + lane] = 0; h[(size_t)gi*DH + 64 + lane] = 0;
    return;
  }
  float a0=0.f, a1=0.f;
  int cn = cnt[gi]; if(cn>CAP) cn=CAP;
  const int* eb = edges + (size_t)gi*CAP;
  for(int e=0;e<cn;e++){
    int jc = eb[e];
    float nj = rsqrtf((float)cnt[(size_t)t*MM+jc] + 1.f);
    const float* gr = g + ((size_t)t*MM + jc)*DH;
    a0 += nj*gr[lane]; a1 += nj*gr[64+lane];
  }
  float ni = rsqrtf((float)cn + 1.f);
  const float* gs = g + (size_t)gi*DH;
  float h0 = ni*(a0 + ni*gs[lane])    + bias[lane];
  float h1 = ni*(a1 + ni*gs[64+lane]) + bias[64+lane];
  h0 = h0>0.f?h0:0.f; h1 = h1>0.f?h1:0.f;
  h[(size_t)gi*DH + lane]      = f2bf(h0);
  h[(size_t)gi*DH + 64 + lane] = f2bf(h1);
}

// ---------------- Q/K/V GEMMs: Q,K row-major; V written TRANSPOSED directly ----------------
__global__ __launch_bounds__(256) void k_gemm_qkv(const unsigned short* __restrict__ X,
    const unsigned short* __restrict__ Wq, const unsigned short* __restrict__ Wk,
    const unsigned short* __restrict__ Wv,
    const float* __restrict__ qb, const float* __restrict__ kb, const float* __restrict__ vb,
    unsigned short* __restrict__ Qo, unsigned short* __restrict__ Ko,
    unsigned short* __restrict__ Vtc, const int* __restrict__ nact)
{
  const int tile = blockIdx.x*64;
  const int t = tile / MM, il = tile % MM;
  const int na = nact[t];
  if(il >= ((na+63)&~63)) return;
  const int which = blockIdx.z;
  const unsigned short* Wt = which==0?Wq:(which==1?Wk:Wv);
  const float* bias = which==0?qb:(which==1?kb:vb);
  const int tid=threadIdx.x, wv=tid>>6, lane=tid&63, l15=lane&15, quad=lane>>4;
  const int r0 = tile + (wv>>1)*32;
  const int c0 = (wv&1)*64;
  short8 bf[4][4];
  #pragma unroll
  for(int kk=0;kk<4;kk++)
    #pragma unroll
    for(int nt=0;nt<4;nt++)
      bf[kk][nt] = *(const short8*)(Wt + (size_t)(c0+nt*16+l15)*DH + kk*32 + quad*8);
  f32x4 z = {0.f,0.f,0.f,0.f};
  f32x4 acc[2][4];
  #pragma unroll
  for(int i=0;i<2;i++){ acc[i][0]=z; acc[i][1]=z; acc[i][2]=z; acc[i][3]=z; }
  #pragma unroll
  for(int kk=0;kk<4;kk++){
    short8 a0 = *(const short8*)(X + (size_t)(r0+l15)*DH    + kk*32 + quad*8);
    short8 a1 = *(const short8*)(X + (size_t)(r0+16+l15)*DH + kk*32 + quad*8);
    #pragma unroll
    for(int nt=0;nt<4;nt++){
      acc[0][nt]=MFMA(a0,bf[kk][nt],acc[0][nt]);
      acc[1][nt]=MFMA(a1,bf[kk][nt],acc[1][nt]);
    }
  }
  if(which < 2){
    unsigned short* o = which==0 ? Qo : Ko;
    #pragma unroll
    for(int mt=0;mt<2;mt++)
      #pragma unroll
      for(int nt=0;nt<4;nt++){
        int col = c0+nt*16+l15;
        float bb = bias[t*DH+col];
        #pragma unroll
        for(int r=0;r<4;r++){
          int row = r0 + mt*16 + quad*4 + r;
          o[(size_t)row*DH + col] = f2bf(acc[mt][nt][r] + bb);
        }
      }
  } else {
    #pragma unroll
    for(int mt=0;mt<2;mt++)
      #pragma unroll
      for(int nt=0;nt<4;nt++){
        int col = c0+nt*16+l15;
        float bb = bias[t*DH+col];
        int node0 = il + (wv>>1)*32 + mt*16 + quad*4;   // compact local row
        short4v pk;
        #pragma unroll
        for(int r=0;r<4;r++) pk[r] = (short)f2bf(acc[mt][nt][r] + bb);
        *(short4v*)(Vtc + ((size_t)t*DH + col)*MM + node0) = pk;
      }
  }
}

// ---------------- attention, key-split, LDS-staged tiles, 4 q-waves/block ----------------
// grid (MM/64, TT, NSPL), 256 threads. Each block: 64 queries (4 waves x 16),
// tiles staged cooperatively in LDS with coalesced loads (was: per-wave 16-line
// scattered L2 reads, ~400 MB -> now ~100 MB coalesced).
__global__ __launch_bounds__(256) void k_attn_split(
  const unsigned short* __restrict__ Q, const unsigned short* __restrict__ Kc,
  const unsigned short* __restrict__ Vtc, const int* __restrict__ nact,
  float* __restrict__ part, float* __restrict__ lpart)
{
  __shared__ unsigned short Kl[64][136];   // 64 keys x 128ch, row 272B (16B-mult, 2-way banks)
  __shared__ unsigned short Vl[128][72];   // 128 ch x 64 keys, row 144B
  __shared__ short Pl[4][16][72];
  const int tid=threadIdx.x, wv=tid>>6, lane=tid&63, l15=lane&15, quad=lane>>4;
  const int t = blockIdx.y, z = blockIdx.z;
  const int na = nact[t];
  const int qblk = blockIdx.x*64;
  if(qblk >= na) return;                 // block-uniform exit (before any barrier)
  const int qbase = qblk + wv*16;
  const bool qact = (qbase < na);        // wave predicate for stores only
  const float scale = 0.088388347648318447f;  // 1/sqrt(128)
  const int nkt = (na + 63) >> 6;
  const int chunk = (nkt + NSPL - 1) / NSPL;
  const int kt0 = z*chunk;
  int kt1 = kt0 + chunk; if(kt1 > nkt) kt1 = nkt;

  short8 bq[4];
  #pragma unroll
  for(int kk=0;kk<4;kk++)
    bq[kk] = *(const short8*)(Q + ((size_t)t*MM + qbase + l15)*DH + kk*32 + quad*8);

  f32x4 zz = {0.f,0.f,0.f,0.f};
  f32x4 accPV[8];
  #pragma unroll
  for(int i=0;i<8;i++) accPV[i]=zz;
  float l_run = 0.f;

  const int srow = tid >> 2, sseg = tid & 3;   // K stage: 64 rows x 4 segs (32 elems)
  const int vch  = tid >> 1, vhalf = tid & 1;  // V stage: 128 ch x 2 halves (32 keys)

  for(int kt=kt0; kt<kt1; kt++){
    const int key0 = kt*64;
    __syncthreads();   // previous tile fully consumed before restage
    {  // stage K tile (coalesced 16B)
      const unsigned short* gk = Kc + ((size_t)t*MM + key0 + srow)*DH + sseg*32;
      short8* dst = (short8*)&Kl[srow][sseg*32];
      #pragma unroll
      for(int j=0;j<4;j++) dst[j] = *(const short8*)(gk + j*8);
    }
    {  // stage V tile (coalesced 16B)
      const unsigned short* gv = Vtc + ((size_t)t*DH + vch)*MM + key0 + vhalf*32;
      short8* dst = (short8*)&Vl[vch][vhalf*32];
      #pragma unroll
      for(int j=0;j<4;j++) dst[j] = *(const short8*)(gv + j*8);
    }
    __syncthreads();
    // S^T = K · Q^T from LDS
    #pragma unroll
    for(int mt=0;mt<4;mt++){
      f32x4 s = zz;
      #pragma unroll
      for(int kk=0;kk<4;kk++){
        short8 ak = *(const short8*)&Kl[mt*16+l15][kk*32 + quad*8];
        s = MFMA(ak, bq[kk], s);
      }
      short4v pk;
      #pragma unroll
      for(int r=0;r<4;r++){
        float sv = fminf(fmaxf(s[r]*scale, -15.f), 15.f);
        float valid = (key0 + mt*16 + quad*4 + r < na) ? 1.f : 0.f;
        float p = __expf(sv) * valid;
        pk[r] = (short)f2bf(p);
        l_run += bf2f((unsigned short)pk[r]);
      }
      *(short4v*)&Pl[wv][l15][mt*16 + quad*4] = pk;
    }
    // PV from LDS
    #pragma unroll
    for(int kk=0;kk<2;kk++){
      short8 ap = *(const short8*)&Pl[wv][l15][kk*32 + quad*8];
      #pragma unroll
      for(int nt=0;nt<8;nt++){
        short8 bv = *(const short8*)&Vl[nt*16+l15][kk*32 + quad*8];
        accPV[nt] = MFMA(ap, bv, accPV[nt]);
      }
    }
  }
  l_run += __shfl_xor(l_run, 16, 64);
  l_run += __shfl_xor(l_run, 32, 64);

  if(qact){
    const size_t pbase = (size_t)(z*TT + t)*MM + qbase;
    #pragma unroll
    for(int nt=0;nt<8;nt++)
      #pragma unroll
      for(int r=0;r<4;r++)
        part[(pbase + quad*4 + r)*128 + nt*16 + l15] = accPV[nt][r];
    if(lane < 16) lpart[pbase + lane] = l_run;
  }
}

// ---------------- attention combine + final projection, scatter to orig nodes ----------------
// NOTE: no per-lane early return before the MFMA loop (round-13 NaN lesson).
__global__ __launch_bounds__(64) void k_attn_fin(
  const float* __restrict__ part, const float* __restrict__ lpart,
  const int* __restrict__ aidx, const int* __restrict__ nact,
  const unsigned short* __restrict__ Wct, const float* __restrict__ bc,
  float* __restrict__ out)
{
  __shared__ short Al[16][136];
  __shared__ float lbuf[16];
  const int lane=threadIdx.x&63, l15=lane&15, quad=lane>>4;
  const int t = blockIdx.y, qbase = blockIdx.x*16;
  const int na = nact[t];
  if(qbase >= na) return;                    // wave-uniform: safe
  f32x4 acc4[8];
  f32x4 zz = {0.f,0.f,0.f,0.f};
  #pragma unroll
  for(int i=0;i<8;i++) acc4[i]=zz;
  #pragma unroll
  for(int s=0;s<NSPL;s++){
    const float* pb = part + ((size_t)(s*TT + t)*MM + qbase)*128;
    #pragma unroll
    for(int i=0;i<8;i++){
      int flat = i*64 + lane;
      int q = flat >> 5, c4 = (flat & 31) << 2;
      acc4[i] += *(const f32x4*)(pb + q*128 + c4);
    }
  }
  if(lane < 16){
    float ls = 0.f;
    #pragma unroll
    for(int s=0;s<NSPL;s++) ls += lpart[(size_t)(s*TT + t)*MM + qbase + lane];
    lbuf[lane] = ls;
  }
  #pragma unroll
  for(int i=0;i<8;i++){
    int flat = i*64 + lane;
    int q = flat >> 5, c4 = (flat & 31) << 2;
    short4v pk;
    #pragma unroll
    for(int r=0;r<4;r++){
      float av = fminf(fmaxf(acc4[i][r], -1e30f), 1e30f);
      pk[r] = (short)f2bf(av);
    }
    *(short4v*)&Al[q][c4] = pk;
  }
  __syncthreads();

  const int qc = qbase + l15;
  const bool qok = (qc < na);                // predicate stores only
  const float lsv = lbuf[l15];
  const float linv = (lsv > 0.f) ? 1.f/lsv : 0.f;
  const int node = aidx[(size_t)t*MM + (qok ? qc : 0)];
  #pragma unroll
  for(int mt2=0;mt2<2;mt2++){
    f32x4 d = zz;
    #pragma unroll
    for(int kk=0;kk<4;kk++){
      short8 aw = *(const short8*)(Wct + (size_t)(mt2*16+l15)*DH + kk*32 + quad*8);
      short8 bl = *(const short8*)&Al[l15][kk*32 + quad*8];
      d = MFMA(aw, bl, d);
    }
    f32x4 bcv = *(const f32x4*)(bc + mt2*16 + quad*4);
    f32x4 o4;
    #pragma unroll
    for(int r=0;r<4;r++) o4[r] = d[r]*linv + bcv[r];
    if(qok)
      *(f32x4*)(out + (size_t)node*(TT*DOUT) + (size_t)t*DOUT + mt2*16 + quad*4) = o4;
  }
}

// ---------------- launch ----------------
extern "C" void kernel_launch(void* const* d_in, const int* in_sizes, int n_in,
                              void* d_out, int out_size, void* d_ws, size_t ws_size,
                              hipStream_t stream)
{
  float* outp = (float*)d_out;   // reference output dtype is float32
  static const int EXP[19] = {1572864,50331648,24576,8192,128,16384,128,16,16,
                              18432,128,18432,128,18432,128,16384,128,4096,32};
  bool ok = (n_in >= 19) && (out_size == OUTSZ);
  if(ok) for(int i=0;i<19;i++) if(in_sizes[i] != EXP[i]) { ok = false; break; }
  if(!ok){
    k_fill<<<(out_size+255)/256,256,0,stream>>>(outp, out_size, 1000.f);
    return;
  }
  const void* x   = d_in[0];
  const void* A   = d_in[1];
  const void* eg  = d_in[2];
  const void* w1  = d_in[3];
  const void* b1  = d_in[4];
  const void* w2  = d_in[5];
  const void* b2  = d_in[6];
  const void* tw  = d_in[7];
  const void* tb  = d_in[8];
  const void* qw  = d_in[9];
  const void* qb0 = d_in[10];
  const void* kw  = d_in[11];
  const void* kb0 = d_in[12];
  const void* vw  = d_in[13];
  const void* vb0 = d_in[14];
  const void* ow  = d_in[15];
  const void* ob  = d_in[16];
  const void* fw  = d_in[17];
  const void* fb  = d_in[18];

  char* w = (char*)d_ws;
  size_t off = 0;
  auto alloc = [&](size_t sz)->char*{
    char* p = w + off; off = (off + sz + 255) & ~(size_t)255; return p; };
  int*   flag  = (int*)  alloc(4);
  int*   dtf   = (int*)  alloc(4);
  int*   nactb = (int*)  alloc(TT*4);
  int*   cnt   = (int*)  alloc((size_t)TM*4);
  int*   aidx  = (int*)  alloc((size_t)TM*4);
  int*   inv   = (int*)  alloc((size_t)TM*4);
  int*   edges = (int*)  alloc((size_t)TM*CAP*4);
  float* g     = (float*)alloc((size_t)TM*DH*4);   // reused as Qb+Kb after 2nd gather
  unsigned short* h   = (unsigned short*)alloc((size_t)TM*DH*2);
  unsigned short* Vtc = (unsigned short*)alloc((size_t)TT*DH*MM*2);
  unsigned short* W1t = (unsigned short*)alloc(DH*DIN*2);
  unsigned short* W2t = (unsigned short*)alloc(DH*DH*2);
  unsigned short* Wqt = (unsigned short*)alloc(DH*DH*2);
  unsigned short* Wkt = (unsigned short*)alloc(DH*DH*2);
  unsigned short* Wvt = (unsigned short*)alloc(DH*DH*2);
  unsigned short* Wct = (unsigned short*)alloc(DOUT*DH*2);
  float* qbf = (float*)alloc(TT*DH*4);
  float* kbf = (float*)alloc(TT*DH*4);
  float* vbf = (float*)alloc(TT*DH*4);
  float* bcf = (float*)alloc(DOUT*4);
  float* b1f = (float*)alloc(DH*4);
  float* b2f = (float*)alloc(DH*4);
  float* part  = (float*)alloc((size_t)NSPL*TM*DH*4);
  float* lpart = (float*)alloc((size_t)NSPL*TM*4);
  if(off > ws_size){
    k_fill<<<(out_size+255)/256,256,0,stream>>>(outp, out_size, 500.f);
    return;
  }

  unsigned short* Qb = (unsigned short*)g;                       // TM*DH*2 bytes
  unsigned short* Kb = (unsigned short*)((char*)g + (size_t)TM*DH*2);

  k_detect2<<<2,256,0,stream>>>((const unsigned short*)x, (const unsigned char*)eg,
                                dtf, flag, nactb);
  k_mask<<<OUTSZ/256,256,0,stream>>>(eg, flag, cnt, nactb, aidx, inv, outp);
  k_prepw<<<(82720+255)/256,256,0,stream>>>(w1,w2,qw,kw,vw,qb0,kb0,vb0,ow,ob,fw,fb,tw,tb,
                                            b1,b2,dtf,
                                            W1t,W2t,Wqt,Wkt,Wvt,Wct,qbf,kbf,vbf,bcf,b1f,b2f);
  k_edges<<<TM*64/256,256,0,stream>>>(A, dtf, inv, cnt, edges);
  k_gemm_x<<<TM/64,256,0,stream>>>(x, dtf, nactb, aidx, W1t, g);
  k_gather<<<TM/4,256,0,stream>>>(g, edges, cnt, nactb, b1f, h);
  k_gemm_h<<<TM/64,256,0,stream>>>(h, W2t, g, nactb);
  k_gather<<<TM/4,256,0,stream>>>(g, edges, cnt, nactb, b2f, h);
  k_gemm_qkv<<<dim3(TM/64,1,3),256,0,stream>>>(h, Wqt,Wkt,Wvt, qbf,kbf,vbf, Qb,Kb,Vtc, nactb);
  k_attn_split<<<dim3(MM/64,TT,NSPL),256,0,stream>>>(Qb, Kb, Vtc, nactb, part, lpart);
  k_attn_fin<<<dim3(MM/16,TT),64,0,stream>>>(part, lpart, aidx, nactb, Wct, bcf, outp);
}

// Round 17
// 528.478 us; speedup vs baseline: 1.5058x; 1.0237x over previous
//
#include <hip/hip_runtime.h>
#include <stdint.h>

#define TT   12
#define BB   2
#define NN   1024
#define MM   2048
#define TM   24576      // TT*MM
#define DIN  64
#define DH   128
#define DOUT 32
#define CAP  64
#define OUTSZ 786432

typedef __attribute__((ext_vector_type(8))) short short8;
typedef __attribute__((ext_vector_type(4))) short short4v;
typedef __attribute__((ext_vector_type(4))) float f32x4;

#define MFMA(a,b,c) __builtin_amdgcn_mfma_f32_16x16x32_bf16((a),(b),(c),0,0,0)

__device__ __forceinline__ float bf2f(unsigned short u){
  union { uint32_t i; float f; } x; x.i = ((uint32_t)u) << 16; return x.f;
}
__device__ __forceinline__ unsigned short f2bf(float f){
  union { float f; uint32_t i; } x; x.f = f;
  uint32_t u = x.i + 0x7FFFu + ((x.i >> 16) & 1u);   // RNE
  return (unsigned short)(u >> 16);
}
__device__ __forceinline__ float LD(const void* p, size_t i, int mode){
  return mode ? ((const float*)p)[i] : bf2f(((const unsigned short*)p)[i]);
}
// gather-load 8 input elements as bf16 (mode 1 = fp32 source)
__device__ __forceinline__ short8 ldx8(const void* x, size_t off, int md){
  if(md){
    const float4* xf = (const float4*)((const float*)x + off);
    float4 a = xf[0], b = xf[1];
    short8 o;
    o[0]=(short)f2bf(a.x); o[1]=(short)f2bf(a.y); o[2]=(short)f2bf(a.z); o[3]=(short)f2bf(a.w);
    o[4]=(short)f2bf(b.x); o[5]=(short)f2bf(b.y); o[6]=(short)f2bf(b.z); o[7]=(short)f2bf(b.w);
    return o;
  }
  return *(const short8*)((const unsigned short*)x + off);
}

// ---------------- fill (fp32, sentinels only) ----------------
__global__ void k_fill(float* __restrict__ out, int n, float val){
  int i = blockIdx.x*blockDim.x + threadIdx.x;
  if(i < n) out[i] = val;
}

// ---------------- fused detectors: block 0 = x dtype (+nact zero), block 1 = mask dtype ----------------
__global__ void k_detect2(const unsigned short* __restrict__ x,
                          const unsigned char* __restrict__ eg,
                          int* __restrict__ dtf, int* __restrict__ flag,
                          int* __restrict__ nact){
  if(blockIdx.x == 0){
    __shared__ int cnt_s;
    if(threadIdx.x==0) cnt_s = 0;
    if(threadIdx.x < TT) nact[threadIdx.x] = 0;
    __syncthreads();
    int c = 0;
    for(int i=threadIdx.x; i<6144; i+=blockDim.x){
      unsigned short h = x[i*2];
      unsigned e = (h >> 7) & 0xFF;
      if(h==0 || (e >= 0x60 && e <= 0x9F)) c++;
    }
    atomicAdd(&cnt_s, c);
    __syncthreads();
    if(threadIdx.x==0) *dtf = (cnt_s > 4000) ? 0 : 1;   // 0=bf16, 1=fp32
  } else {
    __shared__ int pres_s, ge2_s;
    if(threadIdx.x==0){ pres_s=0; ge2_s=0; }
    __syncthreads();
    int pres=0, ge2=0;
    for(int i=threadIdx.x; i<24576; i+=blockDim.x){
      unsigned v = eg[i];
      if(v){ pres |= 1 << (i & 7); if(v >= 2u) ge2 = 1; }
    }
    if(pres) atomicOr(&pres_s, pres);
    if(ge2)  atomicOr(&ge2_s, 1);
    __syncthreads();
    if(threadIdx.x==0){
      int pr = pres_s, g2 = ge2_s, mode;
      if(!g2){
        if((pr & ~0x01) == 0)      mode = 4;   // i64
        else if((pr & ~0x11) == 0) mode = 0;   // i32
        else                       mode = 1;   // u8
      } else {
        if((pr & ~0xC0) == 0)      mode = 5;   // f64
        else if((pr & ~0xCC) == 0) mode = 3;   // f32
        else                       mode = 2;   // bf16
      }
      *flag = mode;
    }
  }
}

// mask decode + wave-ballot compaction + d_out zero (grid covers OUTSZ)
__global__ void k_mask(const void* __restrict__ egom, const int* __restrict__ flag,
                       int* __restrict__ cnt, int* __restrict__ nact,
                       int* __restrict__ aidx, int* __restrict__ inv,
                       float* __restrict__ out){
  int idx = blockIdx.x*blockDim.x + threadIdx.x;   // < OUTSZ
  out[idx] = 0.f;                                  // inactive nodes stay 0
  if(idx >= TM) return;
  int t = idx / MM, node = idx % MM;               // wave = 64 consecutive nodes, one t
  int b = node / NN, n = node % NN;
  int src = (b*TT + t)*NN + n;
  int mode = *flag;
  int v;
  if(mode==0)      v = ((const int*)egom)[src] != 0;
  else if(mode==1) v = ((const unsigned char*)egom)[src] != 0;
  else if(mode==2) v = ((const unsigned short*)egom)[src] != 0;
  else if(mode==3) v = ((const float*)egom)[src] != 0.f;
  else if(mode==4) v = ((const long long*)egom)[src] != 0;
  else             v = ((const double*)egom)[src] != 0.0;
  cnt[idx] = 0;
  unsigned long long bal = __ballot(v != 0);
  int lane = threadIdx.x & 63;
  int base = 0;
  if(lane == 0 && bal) base = atomicAdd(&nact[t], __popcll(bal));
  base = __shfl(base, 0, 64);
  int ic = -1;
  if(v){
    int pfx = __popcll(bal & ((1ULL << lane) - 1ULL));
    ic = base + pfx;
    aidx[(size_t)t*MM + ic] = node;
  }
  inv[idx] = ic;
}

// ---------------- weight prep: coalesced-read transposes + folded weights/biases ----------------
__global__ void k_prepw(
  const void* __restrict__ w1, const void* __restrict__ w2,
  const void* __restrict__ qw, const void* __restrict__ kw, const void* __restrict__ vw,
  const void* __restrict__ qb0, const void* __restrict__ kb0, const void* __restrict__ vb0,
  const void* __restrict__ ow, const void* __restrict__ ob,
  const void* __restrict__ fw, const void* __restrict__ fb,
  const void* __restrict__ tw, const void* __restrict__ tb,
  const void* __restrict__ b1, const void* __restrict__ b2,
  const int* __restrict__ dtf,
  unsigned short* __restrict__ W1t, unsigned short* __restrict__ W2t,
  unsigned short* __restrict__ Wqt, unsigned short* __restrict__ Wkt,
  unsigned short* __restrict__ Wvt, unsigned short* __restrict__ Wct,
  float* __restrict__ qbf, float* __restrict__ kbf, float* __restrict__ vbf,
  float* __restrict__ bcf, float* __restrict__ b1f, float* __restrict__ b2f)
{
  const int md = *dtf;
  int id = blockIdx.x*blockDim.x + threadIdx.x;
  if(id < 8192){  // coalesced read: consecutive id -> consecutive n
    int n=id&127, k2=id>>7; W1t[n*64+k2]=f2bf(LD(w1,(size_t)k2*128+n,md)); return; }
  id -= 8192;
  if(id < 16384){ int n=id&127,k2=id>>7; W2t[n*128+k2]=f2bf(LD(w2,(size_t)k2*128+n,md)); return; }
  id -= 16384;
  if(id < 16384){ int n=id&127,k2=id>>7; Wqt[n*128+k2]=f2bf(LD(qw,(size_t)k2*128+n,md)); return; }
  id -= 16384;
  if(id < 16384){ int n=id&127,k2=id>>7; Wkt[n*128+k2]=f2bf(LD(kw,(size_t)k2*128+n,md)); return; }
  id -= 16384;
  if(id < 16384){ int n=id&127,k2=id>>7; Wvt[n*128+k2]=f2bf(LD(vw,(size_t)k2*128+n,md)); return; }
  id -= 16384;
  if(id < 4096){  // Wc = o_w @ fc_w, stored [oc][c]; ow broadcast, fw coalesced
    int oc=id&31, c=id>>5; float s=0.f;
    for(int r=0;r<128;r++) s += LD(ow,(size_t)c*128+r,md)*LD(fw,(size_t)r*32+oc,md);
    Wct[oc*128+c]=f2bf(s); return;
  }
  id -= 4096;
  if(id < 32){    // bc = o_b @ fc_w + fc_b
    float s = LD(fb,id,md);
    for(int r=0;r<128;r++) s += LD(ob,r,md)*LD(fw,(size_t)r*32+id,md);
    bcf[id]=s; return;
  }
  id -= 32;
  if(id < 4608){  // per-t fused QKV bias: b + t_vec @ W[128:144]
    int which = id/1536, rem=id%1536, t=rem/128, n=rem%128;
    const void* W  = which==0?qw:(which==1?kw:vw);
    const void* Bs = which==0?qb0:(which==1?kb0:vb0);
    float s = LD(Bs,n,md);
    for(int d=0;d<16;d++){
      float tv = sinf((float)t*LD(tw,d,md) + LD(tb,d,md));
      s += tv * LD(W,(size_t)(128+d)*128+n,md);
    }
    float* dst = which==0?qbf:(which==1?kbf:vbf);
    dst[t*128+n]=s; return;
  }
  id -= 4608;
  if(id < 256){   // GCN biases to fp32
    if(id<128) b1f[id] = LD(b1,id,md);
    else       b2f[id-128] = LD(b2,id-128,md);
    return;
  }
}

// ---------------- edge-list build: compact source+target ----------------
__global__ __launch_bounds__(256) void k_edges(const void* __restrict__ A,
    const int* __restrict__ dtf, const int* __restrict__ inv,
    int* __restrict__ cnt, int* __restrict__ edges){
  int id = blockIdx.x*blockDim.x + threadIdx.x;   // TM*64 threads
  int seg = id & 63; int row = id >> 6;           // row = t*MM + j (orig)
  int t = row / MM;
  int jc = inv[row];
  if(jc < 0) return;                              // inactive source
  const int* invt = inv + (size_t)t*MM;
  int* cb = cnt + (size_t)t*MM;
  int* eb = edges + (size_t)t*MM*CAP;
  if(*dtf){   // fp32 adjacency
    const float4* p4 = (const float4*)((const float*)A + (size_t)row*MM + seg*32);
    #pragma unroll
    for(int u=0;u<8;u++){
      float4 v = p4[u];
      float wd[4]={v.x,v.y,v.z,v.w};
      #pragma unroll
      for(int q=0;q<4;q++){
        if(wd[q]!=0.f){
          int ibc = invt[seg*32 + u*4 + q];
          if(ibc >= 0){ int s=atomicAdd(&cb[ibc],1); if(s<CAP) eb[(size_t)ibc*CAP+s]=jc; }
        }
      }
    }
  } else {    // bf16 adjacency
    const uint4* p4 = (const uint4*)((const unsigned short*)A + (size_t)row*MM + seg*32);
    #pragma unroll
    for(int u=0;u<4;u++){
      uint4 v = p4[u];
      unsigned wd[4]={v.x,v.y,v.z,v.w};
      #pragma unroll
      for(int q=0;q<4;q++){
        int ib = seg*32 + u*8 + q*2;
        if(wd[q] & 0xFFFFu){
          int ibc = invt[ib];
          if(ibc >= 0){ int s=atomicAdd(&cb[ibc],1); if(s<CAP) eb[(size_t)ibc*CAP+s]=jc; }
        }
        if(wd[q] >> 16){
          int ibc = invt[ib+1];
          if(ibc >= 0){ int s=atomicAdd(&cb[ibc],1); if(s<CAP) eb[(size_t)ibc*CAP+s]=jc; }
        }
      }
    }
  }
}

// ---------------- GEMM-1: gather x rows via aidx + convert + GEMM (W1t [128][64]) ----------------
__global__ __launch_bounds__(256) void k_gemm_x(const void* __restrict__ x,
    const int* __restrict__ dtf, const int* __restrict__ nact,
    const int* __restrict__ aidx, const unsigned short* __restrict__ Wt,
    float* __restrict__ g)
{
  const int tile = blockIdx.x*64;
  const int t = tile / MM, il = tile % MM;
  const int na = nact[t];
  if(il >= ((na+63)&~63)) return;
  const int md = *dtf;
  const int tid=threadIdx.x, wv=tid>>6, lane=tid&63, l15=lane&15, quad=lane>>4;
  const int r0 = tile + (wv>>1)*32;          // global compact row base
  const int c0 = (wv&1)*64;
  short8 bf[2][4];
  #pragma unroll
  for(int kk=0;kk<2;kk++)
    #pragma unroll
    for(int nt=0;nt<4;nt++)
      bf[kk][nt] = *(const short8*)(Wt + (size_t)(c0+nt*16+l15)*DIN + kk*32 + quad*8);
  // gather rows (pad rows read compact row 0 -- finite, outputs unread)
  const int il0 = (r0 % MM) + l15, il1 = (r0 % MM) + 16 + l15;
  const int n0 = aidx[(size_t)t*MM + (il0 < na ? il0 : 0)];
  const int n1 = aidx[(size_t)t*MM + (il1 < na ? il1 : 0)];
  const size_t xb0 = ((size_t)t*MM + n0)*DIN;
  const size_t xb1 = ((size_t)t*MM + n1)*DIN;
  f32x4 z = {0.f,0.f,0.f,0.f};
  f32x4 acc[2][4];
  #pragma unroll
  for(int i=0;i<2;i++){ acc[i][0]=z; acc[i][1]=z; acc[i][2]=z; acc[i][3]=z; }
  #pragma unroll
  for(int kk=0;kk<2;kk++){
    short8 a0 = ldx8(x, xb0 + kk*32 + quad*8, md);
    short8 a1 = ldx8(x, xb1 + kk*32 + quad*8, md);
    #pragma unroll
    for(int nt=0;nt<4;nt++){
      acc[0][nt]=MFMA(a0,bf[kk][nt],acc[0][nt]);
      acc[1][nt]=MFMA(a1,bf[kk][nt],acc[1][nt]);
    }
  }
  #pragma unroll
  for(int mt=0;mt<2;mt++)
    #pragma unroll
    for(int nt=0;nt<4;nt++){
      int col = c0+nt*16+l15;
      #pragma unroll
      for(int r=0;r<4;r++){
        int row = r0 + mt*16 + quad*4 + r;
        g[(size_t)row*DH + col] = acc[mt][nt][r];
      }
    }
}

// ---------------- dense GEMM on compact rows (h -> g), KD=128 ----------------
__global__ __launch_bounds__(256) void k_gemm_h(const unsigned short* __restrict__ X,
    const unsigned short* __restrict__ Wt, float* __restrict__ g,
    const int* __restrict__ nact)
{
  const int tile = blockIdx.x*64;
  const int t = tile / MM, il = tile % MM;
  const int na = nact[t];
  if(il >= ((na+63)&~63)) return;
  const int tid=threadIdx.x, wv=tid>>6, lane=tid&63, l15=lane&15, quad=lane>>4;
  const int r0 = tile + (wv>>1)*32;
  const int c0 = (wv&1)*64;
  short8 bf[4][4];
  #pragma unroll
  for(int kk=0;kk<4;kk++)
    #pragma unroll
    for(int nt=0;nt<4;nt++)
      bf[kk][nt] = *(const short8*)(Wt + (size_t)(c0+nt*16+l15)*DH + kk*32 + quad*8);
  f32x4 z = {0.f,0.f,0.f,0.f};
  f32x4 acc[2][4];
  #pragma unroll
  for(int i=0;i<2;i++){ acc[i][0]=z; acc[i][1]=z; acc[i][2]=z; acc[i][3]=z; }
  #pragma unroll
  for(int kk=0;kk<4;kk++){
    short8 a0 = *(const short8*)(X + (size_t)(r0+l15)*DH    + kk*32 + quad*8);
    short8 a1 = *(const short8*)(X + (size_t)(r0+16+l15)*DH + kk*32 + quad*8);
    #pragma unroll
    for(int nt=0;nt<4;nt++){
      acc[0][nt]=MFMA(a0,bf[kk][nt],acc[0][nt]);
      acc[1][nt]=MFMA(a1,bf[kk][nt],acc[1][nt]);
    }
  }
  #pragma unroll
  for(int mt=0;mt<2;mt++)
    #pragma unroll
    for(int nt=0;nt<4;nt++){
      int col = c0+nt*16+l15;
      #pragma unroll
      for(int r=0;r<4;r++){
        int row = r0 + mt*16 + quad*4 + r;
        g[(size_t)row*DH + col] = acc[mt][nt][r];
      }
    }
}

// ---------------- sparse GCN aggregation on compact rows -> h (bf16) ----------------
__global__ __launch_bounds__(256) void k_gather(const float* __restrict__ g,
    const int* __restrict__ edges, const int* __restrict__ cnt,
    const int* __restrict__ nact, const float* __restrict__ bias,
    unsigned short* __restrict__ h)
{
  int wv = threadIdx.x>>6, lane = threadIdx.x&63;
  int gi = blockIdx.x*4 + wv;           // compact row, < TM
  int t = gi / MM, ic = gi % MM;
  int na = nact[t];
  if(ic >= ((na+63)&~63)) return;
  if(ic >= na){                         // pad row: finite zeros
    h[(size_t)gi*DH + lane] = 0; h[(size_t)gi*DH + 64 + lane] = 0;
    return;
  }
  float a0=0.f, a1=0.f;
  int cn = cnt[gi]; if(cn>CAP) cn=CAP;
  const int* eb = edges + (size_t)gi*CAP;
  for(int e=0;e<cn;e++){
    int jc = eb[e];
    float nj = rsqrtf((float)cnt[(size_t)t*MM+jc] + 1.f);
    const float* gr = g + ((size_t)t*MM + jc)*DH;
    a0 += nj*gr[lane]; a1 += nj*gr[64+lane];
  }
  float ni = rsqrtf((float)cn + 1.f);
  const float* gs = g + (size_t)gi*DH;
  float h0 = ni*(a0 + ni*gs[lane])    + bias[lane];
  float h1 = ni*(a1 + ni*gs[64+lane]) + bias[64+lane];
  h0 = h0>0.f?h0:0.f; h1 = h1>0.f?h1:0.f;
  h[(size_t)gi*DH + lane]      = f2bf(h0);
  h[(size_t)gi*DH + 64 + lane] = f2bf(h1);
}

// ---------------- Q/K/V GEMMs: Q,K row-major; V written TRANSPOSED directly ----------------
__global__ __launch_bounds__(256) void k_gemm_qkv(const unsigned short* __restrict__ X,
    const unsigned short* __restrict__ Wq, const unsigned short* __restrict__ Wk,
    const unsigned short* __restrict__ Wv,
    const float* __restrict__ qb, const float* __restrict__ kb, const float* __restrict__ vb,
    unsigned short* __restrict__ Qo, unsigned short* __restrict__ Ko,
    unsigned short* __restrict__ Vtc, const int* __restrict__ nact)
{
  const int tile = blockIdx.x*64;
  const int t = tile / MM, il = tile % MM;
  const int na = nact[t];
  if(il >= ((na+63)&~63)) return;
  const int which = blockIdx.z;
  const unsigned short* Wt = which==0?Wq:(which==1?Wk:Wv);
  const float* bias = which==0?qb:(which==1?kb:vb);
  const int tid=threadIdx.x, wv=tid>>6, lane=tid&63, l15=lane&15, quad=lane>>4;
  const int r0 = tile + (wv>>1)*32;
  const int c0 = (wv&1)*64;
  short8 bf[4][4];
  #pragma unroll
  for(int kk=0;kk<4;kk++)
    #pragma unroll
    for(int nt=0;nt<4;nt++)
      bf[kk][nt] = *(const short8*)(Wt + (size_t)(c0+nt*16+l15)*DH + kk*32 + quad*8);
  f32x4 z = {0.f,0.f,0.f,0.f};
  f32x4 acc[2][4];
  #pragma unroll
  for(int i=0;i<2;i++){ acc[i][0]=z; acc[i][1]=z; acc[i][2]=z; acc[i][3]=z; }
  #pragma unroll
  for(int kk=0;kk<4;kk++){
    short8 a0 = *(const short8*)(X + (size_t)(r0+l15)*DH    + kk*32 + quad*8);
    short8 a1 = *(const short8*)(X + (size_t)(r0+16+l15)*DH + kk*32 + quad*8);
    #pragma unroll
    for(int nt=0;nt<4;nt++){
      acc[0][nt]=MFMA(a0,bf[kk][nt],acc[0][nt]);
      acc[1][nt]=MFMA(a1,bf[kk][nt],acc[1][nt]);
    }
  }
  if(which < 2){
    unsigned short* o = which==0 ? Qo : Ko;
    #pragma unroll
    for(int mt=0;mt<2;mt++)
      #pragma unroll
      for(int nt=0;nt<4;nt++){
        int col = c0+nt*16+l15;
        float bb = bias[t*DH+col];
        #pragma unroll
        for(int r=0;r<4;r++){
          int row = r0 + mt*16 + quad*4 + r;
          o[(size_t)row*DH + col] = f2bf(acc[mt][nt][r] + bb);
        }
      }
  } else {
    #pragma unroll
    for(int mt=0;mt<2;mt++)
      #pragma unroll
      for(int nt=0;nt<4;nt++){
        int col = c0+nt*16+l15;
        float bb = bias[t*DH+col];
        int node0 = il + (wv>>1)*32 + mt*16 + quad*4;   // compact local row
        short4v pk;
        #pragma unroll
        for(int r=0;r<4;r++) pk[r] = (short)f2bf(acc[mt][nt][r] + bb);
        *(short4v*)(Vtc + ((size_t)t*DH + col)*MM + node0) = pk;
      }
  }
}

// ---------------- fused attention: LDS-staged tiles, ALL keys per block, in-kernel projection ----------------
// grid (MM/64, TT), 256 threads = 4 q-waves x 16 queries. No key-split, no partials,
// no fin kernel: each wave owns its complete numerator+denominator and projects directly.
__global__ __launch_bounds__(256) void k_attn(
  const unsigned short* __restrict__ Q, const unsigned short* __restrict__ Kc,
  const unsigned short* __restrict__ Vtc, const int* __restrict__ nact,
  const int* __restrict__ aidx, const unsigned short* __restrict__ Wct,
  const float* __restrict__ bc, float* __restrict__ out)
{
  __shared__ unsigned short Kl[64][136];   // 64 keys x 128ch (272B rows: 16B-mult)
  __shared__ unsigned short Vl[128][72];   // 128 ch x 64 keys
  __shared__ short Pl[4][16][72];          // per-wave P tile
  __shared__ short Al[4][16][136];         // per-wave accumulator (bf16) for projection
  const int tid=threadIdx.x, wv=tid>>6, lane=tid&63, l15=lane&15, quad=lane>>4;
  const int t = blockIdx.y;
  const int na = nact[t];
  const int qblk = blockIdx.x*64;
  if(qblk >= na) return;                 // block-uniform exit (before any barrier)
  const int qbase = qblk + wv*16;
  const float scale = 0.088388347648318447f;  // 1/sqrt(128)
  const int nkt = (na + 63) >> 6;

  short8 bq[4];
  #pragma unroll
  for(int kk=0;kk<4;kk++)
    bq[kk] = *(const short8*)(Q + ((size_t)t*MM + qbase + l15)*DH + kk*32 + quad*8);

  f32x4 zz = {0.f,0.f,0.f,0.f};
  f32x4 accPV[8];
  #pragma unroll
  for(int i=0;i<8;i++) accPV[i]=zz;
  float l_run = 0.f;

  const int srow = tid >> 2, sseg = tid & 3;   // K stage: 64 rows x 4 segs
  const int vch  = tid >> 1, vhalf = tid & 1;  // V stage: 128 ch x 2 halves

  for(int kt=0; kt<nkt; kt++){
    const int key0 = kt*64;
    __syncthreads();   // previous tile fully consumed before restage
    {  // stage K tile (coalesced 16B)
      const unsigned short* gk = Kc + ((size_t)t*MM + key0 + srow)*DH + sseg*32;
      short8* dst = (short8*)&Kl[srow][sseg*32];
      #pragma unroll
      for(int j=0;j<4;j++) dst[j] = *(const short8*)(gk + j*8);
    }
    {  // stage V tile (coalesced 16B)
      const unsigned short* gv = Vtc + ((size_t)t*DH + vch)*MM + key0 + vhalf*32;
      short8* dst = (short8*)&Vl[vch][vhalf*32];
      #pragma unroll
      for(int j=0;j<4;j++) dst[j] = *(const short8*)(gv + j*8);
    }
    __syncthreads();
    // S^T = K · Q^T from LDS
    #pragma unroll
    for(int mt=0;mt<4;mt++){
      f32x4 s = zz;
      #pragma unroll
      for(int kk=0;kk<4;kk++){
        short8 ak = *(const short8*)&Kl[mt*16+l15][kk*32 + quad*8];
        s = MFMA(ak, bq[kk], s);
      }
      short4v pk;
      #pragma unroll
      for(int r=0;r<4;r++){
        float sv = fminf(fmaxf(s[r]*scale, -15.f), 15.f);
        float valid = (key0 + mt*16 + quad*4 + r < na) ? 1.f : 0.f;
        float p = __expf(sv) * valid;
        pk[r] = (short)f2bf(p);
        l_run += bf2f((unsigned short)pk[r]);
      }
      *(short4v*)&Pl[wv][l15][mt*16 + quad*4] = pk;
    }
    // PV from LDS
    #pragma unroll
    for(int kk=0;kk<2;kk++){
      short8 ap = *(const short8*)&Pl[wv][l15][kk*32 + quad*8];
      #pragma unroll
      for(int nt=0;nt<8;nt++){
        short8 bv = *(const short8*)&Vl[nt*16+l15][kk*32 + quad*8];
        accPV[nt] = MFMA(ap, bv, accPV[nt]);
      }
    }
  }
  l_run += __shfl_xor(l_run, 16, 64);
  l_run += __shfl_xor(l_run, 32, 64);

  // per-wave projection (Al slice is wave-private; no cross-wave barrier needed)
  #pragma unroll
  for(int nt=0;nt<8;nt++)
    #pragma unroll
    for(int r=0;r<4;r++){
      float av = fminf(fmaxf(accPV[nt][r], -1e30f), 1e30f);
      Al[wv][quad*4+r][nt*16+l15] = (short)f2bf(av);
    }

  const int qc = qbase + l15;
  const bool qok = (qc < na);                // predicate loads of aidx + stores only
  const float linv = (l_run > 0.f) ? 1.f/l_run : 0.f;
  const int node = aidx[(size_t)t*MM + (qok ? qc : 0)];
  #pragma unroll
  for(int mt2=0;mt2<2;mt2++){
    f32x4 d = zz;
    #pragma unroll
    for(int kk=0;kk<4;kk++){
      short8 aw = *(const short8*)(Wct + (size_t)(mt2*16+l15)*DH + kk*32 + quad*8);
      short8 bl = *(const short8*)&Al[wv][l15][kk*32 + quad*8];
      d = MFMA(aw, bl, d);
    }
    f32x4 bcv = *(const f32x4*)(bc + mt2*16 + quad*4);
    f32x4 o4;
    #pragma unroll
    for(int r=0;r<4;r++) o4[r] = d[r]*linv + bcv[r];
    if(qok)
      *(f32x4*)(out + (size_t)node*(TT*DOUT) + (size_t)t*DOUT + mt2*16 + quad*4) = o4;
  }
}

// ---------------- launch ----------------
extern "C" void kernel_launch(void* const* d_in, const int* in_sizes, int n_in,
                              void* d_out, int out_size, void* d_ws, size_t ws_size,
                              hipStream_t stream)
{
  float* outp = (float*)d_out;   // reference output dtype is float32
  static const int EXP[19] = {1572864,50331648,24576,8192,128,16384,128,16,16,
                              18432,128,18432,128,18432,128,16384,128,4096,32};
  bool ok = (n_in >= 19) && (out_size == OUTSZ);
  if(ok) for(int i=0;i<19;i++) if(in_sizes[i] != EXP[i]) { ok = false; break; }
  if(!ok){
    k_fill<<<(out_size+255)/256,256,0,stream>>>(outp, out_size, 1000.f);
    return;
  }
  const void* x   = d_in[0];
  const void* A   = d_in[1];
  const void* eg  = d_in[2];
  const void* w1  = d_in[3];
  const void* b1  = d_in[4];
  const void* w2  = d_in[5];
  const void* b2  = d_in[6];
  const void* tw  = d_in[7];
  const void* tb  = d_in[8];
  const void* qw  = d_in[9];
  const void* qb0 = d_in[10];
  const void* kw  = d_in[11];
  const void* kb0 = d_in[12];
  const void* vw  = d_in[13];
  const void* vb0 = d_in[14];
  const void* ow  = d_in[15];
  const void* ob  = d_in[16];
  const void* fw  = d_in[17];
  const void* fb  = d_in[18];

  char* w = (char*)d_ws;
  size_t off = 0;
  auto alloc = [&](size_t sz)->char*{
    char* p = w + off; off = (off + sz + 255) & ~(size_t)255; return p; };
  int*   flag  = (int*)  alloc(4);
  int*   dtf   = (int*)  alloc(4);
  int*   nactb = (int*)  alloc(TT*4);
  int*   cnt   = (int*)  alloc((size_t)TM*4);
  int*   aidx  = (int*)  alloc((size_t)TM*4);
  int*   inv   = (int*)  alloc((size_t)TM*4);
  int*   edges = (int*)  alloc((size_t)TM*CAP*4);
  float* g     = (float*)alloc((size_t)TM*DH*4);   // reused as Qb+Kb after 2nd gather
  unsigned short* h   = (unsigned short*)alloc((size_t)TM*DH*2);
  unsigned short* Vtc = (unsigned short*)alloc((size_t)TT*DH*MM*2);
  unsigned short* W1t = (unsigned short*)alloc(DH*DIN*2);
  unsigned short* W2t = (unsigned short*)alloc(DH*DH*2);
  unsigned short* Wqt = (unsigned short*)alloc(DH*DH*2);
  unsigned short* Wkt = (unsigned short*)alloc(DH*DH*2);
  unsigned short* Wvt = (unsigned short*)alloc(DH*DH*2);
  unsigned short* Wct = (unsigned short*)alloc(DOUT*DH*2);
  float* qbf = (float*)alloc(TT*DH*4);
  float* kbf = (float*)alloc(TT*DH*4);
  float* vbf = (float*)alloc(TT*DH*4);
  float* bcf = (float*)alloc(DOUT*4);
  float* b1f = (float*)alloc(DH*4);
  float* b2f = (float*)alloc(DH*4);
  if(off > ws_size){
    k_fill<<<(out_size+255)/256,256,0,stream>>>(outp, out_size, 500.f);
    return;
  }

  unsigned short* Qb = (unsigned short*)g;                       // TM*DH*2 bytes
  unsigned short* Kb = (unsigned short*)((char*)g + (size_t)TM*DH*2);

  k_detect2<<<2,256,0,stream>>>((const unsigned short*)x, (const unsigned char*)eg,
                                dtf, flag, nactb);
  k_mask<<<OUTSZ/256,256,0,stream>>>(eg, flag, cnt, nactb, aidx, inv, outp);
  k_prepw<<<(82720+255)/256,256,0,stream>>>(w1,w2,qw,kw,vw,qb0,kb0,vb0,ow,ob,fw,fb,tw,tb,
                                            b1,b2,dtf,
                                            W1t,W2t,Wqt,Wkt,Wvt,Wct,qbf,kbf,vbf,bcf,b1f,b2f);
  k_edges<<<TM*64/256,256,0,stream>>>(A, dtf, inv, cnt, edges);
  k_gemm_x<<<TM/64,256,0,stream>>>(x, dtf, nactb, aidx, W1t, g);
  k_gather<<<TM/4,256,0,stream>>>(g, edges, cnt, nactb, b1f, h);
  k_gemm_h<<<TM/64,256,0,stream>>>(h, W2t, g, nactb);
  k_gather<<<TM/4,256,0,stream>>>(g, edges, cnt, nactb, b2f, h);
  k_gemm_qkv<<<dim3(TM/64,1,3),256,0,stream>>>(h, Wqt,Wkt,Wvt, qbf,kbf,vbf, Qb,Kb,Vtc, nactb);
  k_attn<<<dim3(MM/64,TT),256,0,stream>>>(Qb, Kb, Vtc, nactb, aidx, Wct, bcf, outp);
}

// Round 18
// 517.331 us; speedup vs baseline: 1.5383x; 1.0215x over previous
//
#include <hip/hip_runtime.h>
#include <stdint.h>

#define TT   12
#define BB   2
#define NN   1024
#define MM   2048
#define TM   24576      // TT*MM
#define DIN  64
#define DH   128
#define DOUT 32
#define CAP  64
#define OUTSZ 786432

typedef __attribute__((ext_vector_type(8))) short short8;
typedef __attribute__((ext_vector_type(4))) short short4v;
typedef __attribute__((ext_vector_type(4))) float f32x4;

#define MFMA(a,b,c) __builtin_amdgcn_mfma_f32_16x16x32_bf16((a),(b),(c),0,0,0)

__device__ __forceinline__ float bf2f(unsigned short u){
  union { uint32_t i; float f; } x; x.i = ((uint32_t)u) << 16; return x.f;
}
__device__ __forceinline__ unsigned short f2bf(float f){
  union { float f; uint32_t i; } x; x.f = f;
  uint32_t u = x.i + 0x7FFFu + ((x.i >> 16) & 1u);   // RNE
  return (unsigned short)(u >> 16);
}
__device__ __forceinline__ float LD(const void* p, size_t i, int mode){
  return mode ? ((const float*)p)[i] : bf2f(((const unsigned short*)p)[i]);
}
// gather-load 8 input elements as bf16 (mode 1 = fp32 source)
__device__ __forceinline__ short8 ldx8(const void* x, size_t off, int md){
  if(md){
    const float4* xf = (const float4*)((const float*)x + off);
    float4 a = xf[0], b = xf[1];
    short8 o;
    o[0]=(short)f2bf(a.x); o[1]=(short)f2bf(a.y); o[2]=(short)f2bf(a.z); o[3]=(short)f2bf(a.w);
    o[4]=(short)f2bf(b.x); o[5]=(short)f2bf(b.y); o[6]=(short)f2bf(b.z); o[7]=(short)f2bf(b.w);
    return o;
  }
  return *(const short8*)((const unsigned short*)x + off);
}

// ---------------- fill (fp32, sentinels only) ----------------
__global__ void k_fill(float* __restrict__ out, int n, float val){
  int i = blockIdx.x*blockDim.x + threadIdx.x;
  if(i < n) out[i] = val;
}

// ---------------- fused detectors: block 0 = x dtype (+nact zero), block 1 = mask dtype ----------------
__global__ void k_detect2(const unsigned short* __restrict__ x,
                          const unsigned char* __restrict__ eg,
                          int* __restrict__ dtf, int* __restrict__ flag,
                          int* __restrict__ nact){
  if(blockIdx.x == 0){
    __shared__ int cnt_s;
    if(threadIdx.x==0) cnt_s = 0;
    if(threadIdx.x < TT) nact[threadIdx.x] = 0;
    __syncthreads();
    int c = 0;
    for(int i=threadIdx.x; i<6144; i+=blockDim.x){
      unsigned short h = x[i*2];
      unsigned e = (h >> 7) & 0xFF;
      if(h==0 || (e >= 0x60 && e <= 0x9F)) c++;
    }
    atomicAdd(&cnt_s, c);
    __syncthreads();
    if(threadIdx.x==0) *dtf = (cnt_s > 4000) ? 0 : 1;   // 0=bf16, 1=fp32
  } else {
    __shared__ int pres_s, ge2_s;
    if(threadIdx.x==0){ pres_s=0; ge2_s=0; }
    __syncthreads();
    int pres=0, ge2=0;
    for(int i=threadIdx.x; i<24576; i+=blockDim.x){
      unsigned v = eg[i];
      if(v){ pres |= 1 << (i & 7); if(v >= 2u) ge2 = 1; }
    }
    if(pres) atomicOr(&pres_s, pres);
    if(ge2)  atomicOr(&ge2_s, 1);
    __syncthreads();
    if(threadIdx.x==0){
      int pr = pres_s, g2 = ge2_s, mode;
      if(!g2){
        if((pr & ~0x01) == 0)      mode = 4;   // i64
        else if((pr & ~0x11) == 0) mode = 0;   // i32
        else                       mode = 1;   // u8
      } else {
        if((pr & ~0xC0) == 0)      mode = 5;   // f64
        else if((pr & ~0xCC) == 0) mode = 3;   // f32
        else                       mode = 2;   // bf16
      }
      *flag = mode;
    }
  }
}

// mask decode + wave-ballot compaction + d_out zero (grid covers OUTSZ)
__global__ void k_mask(const void* __restrict__ egom, const int* __restrict__ flag,
                       int* __restrict__ cnt, int* __restrict__ nact,
                       int* __restrict__ aidx, int* __restrict__ inv,
                       float* __restrict__ out){
  int idx = blockIdx.x*blockDim.x + threadIdx.x;   // < OUTSZ
  out[idx] = 0.f;                                  // inactive nodes stay 0
  if(idx >= TM) return;
  int t = idx / MM, node = idx % MM;               // wave = 64 consecutive nodes, one t
  int b = node / NN, n = node % NN;
  int src = (b*TT + t)*NN + n;
  int mode = *flag;
  int v;
  if(mode==0)      v = ((const int*)egom)[src] != 0;
  else if(mode==1) v = ((const unsigned char*)egom)[src] != 0;
  else if(mode==2) v = ((const unsigned short*)egom)[src] != 0;
  else if(mode==3) v = ((const float*)egom)[src] != 0.f;
  else if(mode==4) v = ((const long long*)egom)[src] != 0;
  else             v = ((const double*)egom)[src] != 0.0;
  cnt[idx] = 0;
  unsigned long long bal = __ballot(v != 0);
  int lane = threadIdx.x & 63;
  int base = 0;
  if(lane == 0 && bal) base = atomicAdd(&nact[t], __popcll(bal));
  base = __shfl(base, 0, 64);
  int ic = -1;
  if(v){
    int pfx = __popcll(bal & ((1ULL << lane) - 1ULL));
    ic = base + pfx;
    aidx[(size_t)t*MM + ic] = node;
  }
  inv[idx] = ic;
}

// ---------------- weight prep: coalesced-read transposes + folded weights/biases ----------------
__global__ void k_prepw(
  const void* __restrict__ w1, const void* __restrict__ w2,
  const void* __restrict__ qw, const void* __restrict__ kw, const void* __restrict__ vw,
  const void* __restrict__ qb0, const void* __restrict__ kb0, const void* __restrict__ vb0,
  const void* __restrict__ ow, const void* __restrict__ ob,
  const void* __restrict__ fw, const void* __restrict__ fb,
  const void* __restrict__ tw, const void* __restrict__ tb,
  const void* __restrict__ b1, const void* __restrict__ b2,
  const int* __restrict__ dtf,
  unsigned short* __restrict__ W1t, unsigned short* __restrict__ W2t,
  unsigned short* __restrict__ Wqt, unsigned short* __restrict__ Wkt,
  unsigned short* __restrict__ Wvt, unsigned short* __restrict__ Wct,
  float* __restrict__ qbf, float* __restrict__ kbf, float* __restrict__ vbf,
  float* __restrict__ bcf, float* __restrict__ b1f, float* __restrict__ b2f)
{
  const int md = *dtf;
  int id = blockIdx.x*blockDim.x + threadIdx.x;
  if(id < 8192){  // coalesced read: consecutive id -> consecutive n
    int n=id&127, k2=id>>7; W1t[n*64+k2]=f2bf(LD(w1,(size_t)k2*128+n,md)); return; }
  id -= 8192;
  if(id < 16384){ int n=id&127,k2=id>>7; W2t[n*128+k2]=f2bf(LD(w2,(size_t)k2*128+n,md)); return; }
  id -= 16384;
  if(id < 16384){ int n=id&127,k2=id>>7; Wqt[n*128+k2]=f2bf(LD(qw,(size_t)k2*128+n,md)); return; }
  id -= 16384;
  if(id < 16384){ int n=id&127,k2=id>>7; Wkt[n*128+k2]=f2bf(LD(kw,(size_t)k2*128+n,md)); return; }
  id -= 16384;
  if(id < 16384){ int n=id&127,k2=id>>7; Wvt[n*128+k2]=f2bf(LD(vw,(size_t)k2*128+n,md)); return; }
  id -= 16384;
  if(id < 4096){  // Wc = o_w @ fc_w, stored [oc][c]; ow broadcast, fw coalesced
    int oc=id&31, c=id>>5; float s=0.f;
    for(int r=0;r<128;r++) s += LD(ow,(size_t)c*128+r,md)*LD(fw,(size_t)r*32+oc,md);
    Wct[oc*128+c]=f2bf(s); return;
  }
  id -= 4096;
  if(id < 32){    // bc = o_b @ fc_w + fc_b
    float s = LD(fb,id,md);
    for(int r=0;r<128;r++) s += LD(ob,r,md)*LD(fw,(size_t)r*32+id,md);
    bcf[id]=s; return;
  }
  id -= 32;
  if(id < 4608){  // per-t fused QKV bias: b + t_vec @ W[128:144]
    int which = id/1536, rem=id%1536, t=rem/128, n=rem%128;
    const void* W  = which==0?qw:(which==1?kw:vw);
    const void* Bs = which==0?qb0:(which==1?kb0:vb0);
    float s = LD(Bs,n,md);
    for(int d=0;d<16;d++){
      float tv = sinf((float)t*LD(tw,d,md) + LD(tb,d,md));
      s += tv * LD(W,(size_t)(128+d)*128+n,md);
    }
    float* dst = which==0?qbf:(which==1?kbf:vbf);
    dst[t*128+n]=s; return;
  }
  id -= 4608;
  if(id < 256){   // GCN biases to fp32
    if(id<128) b1f[id] = LD(b1,id,md);
    else       b2f[id-128] = LD(b2,id-128,md);
    return;
  }
}

// ---------------- edge-list build: compact source+target ----------------
__global__ __launch_bounds__(256) void k_edges(const void* __restrict__ A,
    const int* __restrict__ dtf, const int* __restrict__ inv,
    int* __restrict__ cnt, int* __restrict__ edges){
  int id = blockIdx.x*blockDim.x + threadIdx.x;   // TM*64 threads
  int seg = id & 63; int row = id >> 6;           // row = t*MM + j (orig)
  int t = row / MM;
  int jc = inv[row];
  if(jc < 0) return;                              // inactive source
  const int* invt = inv + (size_t)t*MM;
  int* cb = cnt + (size_t)t*MM;
  int* eb = edges + (size_t)t*MM*CAP;
  if(*dtf){   // fp32 adjacency
    const float4* p4 = (const float4*)((const float*)A + (size_t)row*MM + seg*32);
    #pragma unroll
    for(int u=0;u<8;u++){
      float4 v = p4[u];
      float wd[4]={v.x,v.y,v.z,v.w};
      #pragma unroll
      for(int q=0;q<4;q++){
        if(wd[q]!=0.f){
          int ibc = invt[seg*32 + u*4 + q];
          if(ibc >= 0){ int s=atomicAdd(&cb[ibc],1); if(s<CAP) eb[(size_t)ibc*CAP+s]=jc; }
        }
      }
    }
  } else {    // bf16 adjacency
    const uint4* p4 = (const uint4*)((const unsigned short*)A + (size_t)row*MM + seg*32);
    #pragma unroll
    for(int u=0;u<4;u++){
      uint4 v = p4[u];
      unsigned wd[4]={v.x,v.y,v.z,v.w};
      #pragma unroll
      for(int q=0;q<4;q++){
        int ib = seg*32 + u*8 + q*2;
        if(wd[q] & 0xFFFFu){
          int ibc = invt[ib];
          if(ibc >= 0){ int s=atomicAdd(&cb[ibc],1); if(s<CAP) eb[(size_t)ibc*CAP+s]=jc; }
        }
        if(wd[q] >> 16){
          int ibc = invt[ib+1];
          if(ibc >= 0){ int s=atomicAdd(&cb[ibc],1); if(s<CAP) eb[(size_t)ibc*CAP+s]=jc; }
        }
      }
    }
  }
}

// ---------------- GEMM-1: gather x rows via aidx + convert + GEMM (W1t [128][64]) ----------------
__global__ __launch_bounds__(256) void k_gemm_x(const void* __restrict__ x,
    const int* __restrict__ dtf, const int* __restrict__ nact,
    const int* __restrict__ aidx, const unsigned short* __restrict__ Wt,
    float* __restrict__ g)
{
  const int tile = blockIdx.x*64;
  const int t = tile / MM, il = tile % MM;
  const int na = nact[t];
  if(il >= ((na+63)&~63)) return;
  const int md = *dtf;
  const int tid=threadIdx.x, wv=tid>>6, lane=tid&63, l15=lane&15, quad=lane>>4;
  const int r0 = tile + (wv>>1)*32;          // global compact row base
  const int c0 = (wv&1)*64;
  short8 bf[2][4];
  #pragma unroll
  for(int kk=0;kk<2;kk++)
    #pragma unroll
    for(int nt=0;nt<4;nt++)
      bf[kk][nt] = *(const short8*)(Wt + (size_t)(c0+nt*16+l15)*DIN + kk*32 + quad*8);
  // gather rows (pad rows read compact row 0 -- finite, outputs unread)
  const int il0 = (r0 % MM) + l15, il1 = (r0 % MM) + 16 + l15;
  const int n0 = aidx[(size_t)t*MM + (il0 < na ? il0 : 0)];
  const int n1 = aidx[(size_t)t*MM + (il1 < na ? il1 : 0)];
  const size_t xb0 = ((size_t)t*MM + n0)*DIN;
  const size_t xb1 = ((size_t)t*MM + n1)*DIN;
  f32x4 z = {0.f,0.f,0.f,0.f};
  f32x4 acc[2][4];
  #pragma unroll
  for(int i=0;i<2;i++){ acc[i][0]=z; acc[i][1]=z; acc[i][2]=z; acc[i][3]=z; }
  #pragma unroll
  for(int kk=0;kk<2;kk++){
    short8 a0 = ldx8(x, xb0 + kk*32 + quad*8, md);
    short8 a1 = ldx8(x, xb1 + kk*32 + quad*8, md);
    #pragma unroll
    for(int nt=0;nt<4;nt++){
      acc[0][nt]=MFMA(a0,bf[kk][nt],acc[0][nt]);
      acc[1][nt]=MFMA(a1,bf[kk][nt],acc[1][nt]);
    }
  }
  #pragma unroll
  for(int mt=0;mt<2;mt++)
    #pragma unroll
    for(int nt=0;nt<4;nt++){
      int col = c0+nt*16+l15;
      #pragma unroll
      for(int r=0;r<4;r++){
        int row = r0 + mt*16 + quad*4 + r;
        g[(size_t)row*DH + col] = acc[mt][nt][r];
      }
    }
}

// ---------------- dense GEMM on compact rows (h -> g), KD=128 ----------------
__global__ __launch_bounds__(256) void k_gemm_h(const unsigned short* __restrict__ X,
    const unsigned short* __restrict__ Wt, float* __restrict__ g,
    const int* __restrict__ nact)
{
  const int tile = blockIdx.x*64;
  const int t = tile / MM, il = tile % MM;
  const int na = nact[t];
  if(il >= ((na+63)&~63)) return;
  const int tid=threadIdx.x, wv=tid>>6, lane=tid&63, l15=lane&15, quad=lane>>4;
  const int r0 = tile + (wv>>1)*32;
  const int c0 = (wv&1)*64;
  short8 bf[4][4];
  #pragma unroll
  for(int kk=0;kk<4;kk++)
    #pragma unroll
    for(int nt=0;nt<4;nt++)
      bf[kk][nt] = *(const short8*)(Wt + (size_t)(c0+nt*16+l15)*DH + kk*32 + quad*8);
  f32x4 z = {0.f,0.f,0.f,0.f};
  f32x4 acc[2][4];
  #pragma unroll
  for(int i=0;i<2;i++){ acc[i][0]=z; acc[i][1]=z; acc[i][2]=z; acc[i][3]=z; }
  #pragma unroll
  for(int kk=0;kk<4;kk++){
    short8 a0 = *(const short8*)(X + (size_t)(r0+l15)*DH    + kk*32 + quad*8);
    short8 a1 = *(const short8*)(X + (size_t)(r0+16+l15)*DH + kk*32 + quad*8);
    #pragma unroll
    for(int nt=0;nt<4;nt++){
      acc[0][nt]=MFMA(a0,bf[kk][nt],acc[0][nt]);
      acc[1][nt]=MFMA(a1,bf[kk][nt],acc[1][nt]);
    }
  }
  #pragma unroll
  for(int mt=0;mt<2;mt++)
    #pragma unroll
    for(int nt=0;nt<4;nt++){
      int col = c0+nt*16+l15;
      #pragma unroll
      for(int r=0;r<4;r++){
        int row = r0 + mt*16 + quad*4 + r;
        g[(size_t)row*DH + col] = acc[mt][nt][r];
      }
    }
}

// ---------------- sparse GCN aggregation on compact rows -> h (bf16) ----------------
// lane owns channels {2*lane, 2*lane+1}: one float2 load per edge, one packed store.
__global__ __launch_bounds__(256) void k_gather(const float* __restrict__ g,
    const int* __restrict__ edges, const int* __restrict__ cnt,
    const int* __restrict__ nact, const float* __restrict__ bias,
    unsigned short* __restrict__ h)
{
  int wv = threadIdx.x>>6, lane = threadIdx.x&63;
  int gi = blockIdx.x*4 + wv;           // compact row, < TM
  int t = gi / MM, ic = gi % MM;
  int na = nact[t];
  if(ic >= ((na+63)&~63)) return;
  unsigned int* hp = (unsigned int*)(h + (size_t)gi*DH) + lane;
  if(ic >= na){ *hp = 0; return; }      // pad row: finite zeros
  float a0=0.f, a1=0.f;
  int cn = cnt[gi]; if(cn>CAP) cn=CAP;
  const int* eb = edges + (size_t)gi*CAP;
  #pragma unroll 2
  for(int e=0;e<cn;e++){
    int jc = eb[e];
    float nj = rsqrtf((float)cnt[(size_t)t*MM+jc] + 1.f);
    float2 gr2 = *(const float2*)(g + ((size_t)t*MM + jc)*DH + 2*lane);
    a0 += nj*gr2.x; a1 += nj*gr2.y;
  }
  float ni = rsqrtf((float)cn + 1.f);
  float2 gs2 = *(const float2*)(g + (size_t)gi*DH + 2*lane);
  float h0 = ni*(a0 + ni*gs2.x) + bias[2*lane];
  float h1 = ni*(a1 + ni*gs2.y) + bias[2*lane+1];
  h0 = h0>0.f?h0:0.f; h1 = h1>0.f?h1:0.f;
  *hp = (unsigned int)f2bf(h0) | ((unsigned int)f2bf(h1) << 16);
}

// ---------------- Q/K/V GEMMs: Q,K row-major; V written TRANSPOSED directly ----------------
__global__ __launch_bounds__(256) void k_gemm_qkv(const unsigned short* __restrict__ X,
    const unsigned short* __restrict__ Wq, const unsigned short* __restrict__ Wk,
    const unsigned short* __restrict__ Wv,
    const float* __restrict__ qb, const float* __restrict__ kb, const float* __restrict__ vb,
    unsigned short* __restrict__ Qo, unsigned short* __restrict__ Ko,
    unsigned short* __restrict__ Vtc, const int* __restrict__ nact)
{
  const int tile = blockIdx.x*64;
  const int t = tile / MM, il = tile % MM;
  const int na = nact[t];
  if(il >= ((na+63)&~63)) return;
  const int which = blockIdx.z;
  const unsigned short* Wt = which==0?Wq:(which==1?Wk:Wv);
  const float* bias = which==0?qb:(which==1?kb:vb);
  const int tid=threadIdx.x, wv=tid>>6, lane=tid&63, l15=lane&15, quad=lane>>4;
  const int r0 = tile + (wv>>1)*32;
  const int c0 = (wv&1)*64;
  short8 bf[4][4];
  #pragma unroll
  for(int kk=0;kk<4;kk++)
    #pragma unroll
    for(int nt=0;nt<4;nt++)
      bf[kk][nt] = *(const short8*)(Wt + (size_t)(c0+nt*16+l15)*DH + kk*32 + quad*8);
  f32x4 z = {0.f,0.f,0.f,0.f};
  f32x4 acc[2][4];
  #pragma unroll
  for(int i=0;i<2;i++){ acc[i][0]=z; acc[i][1]=z; acc[i][2]=z; acc[i][3]=z; }
  #pragma unroll
  for(int kk=0;kk<4;kk++){
    short8 a0 = *(const short8*)(X + (size_t)(r0+l15)*DH    + kk*32 + quad*8);
    short8 a1 = *(const short8*)(X + (size_t)(r0+16+l15)*DH + kk*32 + quad*8);
    #pragma unroll
    for(int nt=0;nt<4;nt++){
      acc[0][nt]=MFMA(a0,bf[kk][nt],acc[0][nt]);
      acc[1][nt]=MFMA(a1,bf[kk][nt],acc[1][nt]);
    }
  }
  if(which < 2){
    unsigned short* o = which==0 ? Qo : Ko;
    #pragma unroll
    for(int mt=0;mt<2;mt++)
      #pragma unroll
      for(int nt=0;nt<4;nt++){
        int col = c0+nt*16+l15;
        float bb = bias[t*DH+col];
        #pragma unroll
        for(int r=0;r<4;r++){
          int row = r0 + mt*16 + quad*4 + r;
          o[(size_t)row*DH + col] = f2bf(acc[mt][nt][r] + bb);
        }
      }
  } else {
    #pragma unroll
    for(int mt=0;mt<2;mt++)
      #pragma unroll
      for(int nt=0;nt<4;nt++){
        int col = c0+nt*16+l15;
        float bb = bias[t*DH+col];
        int node0 = il + (wv>>1)*32 + mt*16 + quad*4;   // compact local row
        short4v pk;
        #pragma unroll
        for(int r=0;r<4;r++) pk[r] = (short)f2bf(acc[mt][nt][r] + bb);
        *(short4v*)(Vtc + ((size_t)t*DH + col)*MM + node0) = pk;
      }
  }
}

// ---------------- fused attention: LDS tiles + register-prefetch pipeline ----------------
// grid (MM/64, TT), 256 threads = 4 q-waves x 16 queries. Next tile's global loads
// issue right after the stage barrier and overlap the current tile's MFMA compute.
__global__ __launch_bounds__(256) void k_attn(
  const unsigned short* __restrict__ Q, const unsigned short* __restrict__ Kc,
  const unsigned short* __restrict__ Vtc, const int* __restrict__ nact,
  const int* __restrict__ aidx, const unsigned short* __restrict__ Wct,
  const float* __restrict__ bc, float* __restrict__ out)
{
  __shared__ unsigned short Kl[64][136];   // 64 keys x 128ch (272B rows: 16B-mult)
  __shared__ unsigned short Vl[128][72];   // 128 ch x 64 keys
  __shared__ short Pl[4][16][72];          // per-wave P tile
  __shared__ short Al[4][16][136];         // per-wave accumulator (bf16) for projection
  const int tid=threadIdx.x, wv=tid>>6, lane=tid&63, l15=lane&15, quad=lane>>4;
  const int t = blockIdx.y;
  const int na = nact[t];
  const int qblk = blockIdx.x*64;
  if(qblk >= na) return;                 // block-uniform exit (before any barrier)
  const int qbase = qblk + wv*16;
  const float scale = 0.088388347648318447f;  // 1/sqrt(128)
  const int nkt = (na + 63) >> 6;

  short8 bq[4];
  #pragma unroll
  for(int kk=0;kk<4;kk++)
    bq[kk] = *(const short8*)(Q + ((size_t)t*MM + qbase + l15)*DH + kk*32 + quad*8);

  f32x4 zz = {0.f,0.f,0.f,0.f};
  f32x4 accPV[8];
  #pragma unroll
  for(int i=0;i<8;i++) accPV[i]=zz;
  float l_run = 0.f;

  const int srow = tid >> 2, sseg = tid & 3;   // K stage: 64 rows x 4 segs
  const int vch  = tid >> 1, vhalf = tid & 1;  // V stage: 128 ch x 2 halves

  short8 kreg[4], vreg[4];
  {  // preload tile 0 into registers
    const unsigned short* gk = Kc + ((size_t)t*MM + srow)*DH + sseg*32;
    const unsigned short* gv = Vtc + ((size_t)t*DH + vch)*MM + vhalf*32;
    #pragma unroll
    for(int j=0;j<4;j++){ kreg[j] = *(const short8*)(gk + j*8);
                          vreg[j] = *(const short8*)(gv + j*8); }
  }

  for(int kt=0; kt<nkt; kt++){
    const int key0 = kt*64;
    __syncthreads();   // previous tile fully consumed before restage
    {  // write prefetched registers to LDS
      short8* kd = (short8*)&Kl[srow][sseg*32];
      short8* vd = (short8*)&Vl[vch][vhalf*32];
      #pragma unroll
      for(int j=0;j<4;j++){ kd[j] = kreg[j]; vd[j] = vreg[j]; }
    }
    __syncthreads();
    if(kt+1 < nkt){   // issue next tile's global loads; they overlap compute below
      const int key1 = key0 + 64;
      const unsigned short* gk = Kc + ((size_t)t*MM + key1 + srow)*DH + sseg*32;
      const unsigned short* gv = Vtc + ((size_t)t*DH + vch)*MM + key1 + vhalf*32;
      #pragma unroll
      for(int j=0;j<4;j++){ kreg[j] = *(const short8*)(gk + j*8);
                            vreg[j] = *(const short8*)(gv + j*8); }
    }
    // S^T = K · Q^T from LDS
    #pragma unroll
    for(int mt=0;mt<4;mt++){
      f32x4 s = zz;
      #pragma unroll
      for(int kk=0;kk<4;kk++){
        short8 ak = *(const short8*)&Kl[mt*16+l15][kk*32 + quad*8];
        s = MFMA(ak, bq[kk], s);
      }
      short4v pk;
      #pragma unroll
      for(int r=0;r<4;r++){
        float sv = fminf(fmaxf(s[r]*scale, -15.f), 15.f);
        float valid = (key0 + mt*16 + quad*4 + r < na) ? 1.f : 0.f;
        float p = __expf(sv) * valid;
        pk[r] = (short)f2bf(p);
        l_run += bf2f((unsigned short)pk[r]);
      }
      *(short4v*)&Pl[wv][l15][mt*16 + quad*4] = pk;
    }
    // PV from LDS
    #pragma unroll
    for(int kk=0;kk<2;kk++){
      short8 ap = *(const short8*)&Pl[wv][l15][kk*32 + quad*8];
      #pragma unroll
      for(int nt=0;nt<8;nt++){
        short8 bv = *(const short8*)&Vl[nt*16+l15][kk*32 + quad*8];
        accPV[nt] = MFMA(ap, bv, accPV[nt]);
      }
    }
  }
  l_run += __shfl_xor(l_run, 16, 64);
  l_run += __shfl_xor(l_run, 32, 64);

  // per-wave projection (Al slice is wave-private; no cross-wave barrier needed)
  #pragma unroll
  for(int nt=0;nt<8;nt++)
    #pragma unroll
    for(int r=0;r<4;r++){
      float av = fminf(fmaxf(accPV[nt][r], -1e30f), 1e30f);
      Al[wv][quad*4+r][nt*16+l15] = (short)f2bf(av);
    }

  const int qc = qbase + l15;
  const bool qok = (qc < na);                // predicate loads of aidx + stores only
  const float linv = (l_run > 0.f) ? 1.f/l_run : 0.f;
  const int node = aidx[(size_t)t*MM + (qok ? qc : 0)];
  #pragma unroll
  for(int mt2=0;mt2<2;mt2++){
    f32x4 d = zz;
    #pragma unroll
    for(int kk=0;kk<4;kk++){
      short8 aw = *(const short8*)(Wct + (size_t)(mt2*16+l15)*DH + kk*32 + quad*8);
      short8 bl = *(const short8*)&Al[wv][l15][kk*32 + quad*8];
      d = MFMA(aw, bl, d);
    }
    f32x4 bcv = *(const f32x4*)(bc + mt2*16 + quad*4);
    f32x4 o4;
    #pragma unroll
    for(int r=0;r<4;r++) o4[r] = d[r]*linv + bcv[r];
    if(qok)
      *(f32x4*)(out + (size_t)node*(TT*DOUT) + (size_t)t*DOUT + mt2*16 + quad*4) = o4;
  }
}

// ---------------- launch ----------------
extern "C" void kernel_launch(void* const* d_in, const int* in_sizes, int n_in,
                              void* d_out, int out_size, void* d_ws, size_t ws_size,
                              hipStream_t stream)
{
  float* outp = (float*)d_out;   // reference output dtype is float32
  static const int EXP[19] = {1572864,50331648,24576,8192,128,16384,128,16,16,
                              18432,128,18432,128,18432,128,16384,128,4096,32};
  bool ok = (n_in >= 19) && (out_size == OUTSZ);
  if(ok) for(int i=0;i<19;i++) if(in_sizes[i] != EXP[i]) { ok = false; break; }
  if(!ok){
    k_fill<<<(out_size+255)/256,256,0,stream>>>(outp, out_size, 1000.f);
    return;
  }
  const void* x   = d_in[0];
  const void* A   = d_in[1];
  const void* eg  = d_in[2];
  const void* w1  = d_in[3];
  const void* b1  = d_in[4];
  const void* w2  = d_in[5];
  const void* b2  = d_in[6];
  const void* tw  = d_in[7];
  const void* tb  = d_in[8];
  const void* qw  = d_in[9];
  const void* qb0 = d_in[10];
  const void* kw  = d_in[11];
  const void* kb0 = d_in[12];
  const void* vw  = d_in[13];
  const void* vb0 = d_in[14];
  const void* ow  = d_in[15];
  const void* ob  = d_in[16];
  const void* fw  = d_in[17];
  const void* fb  = d_in[18];

  char* w = (char*)d_ws;
  size_t off = 0;
  auto alloc = [&](size_t sz)->char*{
    char* p = w + off; off = (off + sz + 255) & ~(size_t)255; return p; };
  int*   flag  = (int*)  alloc(4);
  int*   dtf   = (int*)  alloc(4);
  int*   nactb = (int*)  alloc(TT*4);
  int*   cnt   = (int*)  alloc((size_t)TM*4);
  int*   aidx  = (int*)  alloc((size_t)TM*4);
  int*   inv   = (int*)  alloc((size_t)TM*4);
  int*   edges = (int*)  alloc((size_t)TM*CAP*4);
  float* g     = (float*)alloc((size_t)TM*DH*4);   // reused as Qb+Kb after 2nd gather
  unsigned short* h   = (unsigned short*)alloc((size_t)TM*DH*2);
  unsigned short* Vtc = (unsigned short*)alloc((size_t)TT*DH*MM*2);
  unsigned short* W1t = (unsigned short*)alloc(DH*DIN*2);
  unsigned short* W2t = (unsigned short*)alloc(DH*DH*2);
  unsigned short* Wqt = (unsigned short*)alloc(DH*DH*2);
  unsigned short* Wkt = (unsigned short*)alloc(DH*DH*2);
  unsigned short* Wvt = (unsigned short*)alloc(DH*DH*2);
  unsigned short* Wct = (unsigned short*)alloc(DOUT*DH*2);
  float* qbf = (float*)alloc(TT*DH*4);
  float* kbf = (float*)alloc(TT*DH*4);
  float* vbf = (float*)alloc(TT*DH*4);
  float* bcf = (float*)alloc(DOUT*4);
  float* b1f = (float*)alloc(DH*4);
  float* b2f = (float*)alloc(DH*4);
  if(off > ws_size){
    k_fill<<<(out_size+255)/256,256,0,stream>>>(outp, out_size, 500.f);
    return;
  }

  unsigned short* Qb = (unsigned short*)g;                       // TM*DH*2 bytes
  unsigned short* Kb = (unsigned short*)((char*)g + (size_t)TM*DH*2);

  k_detect2<<<2,256,0,stream>>>((const unsigned short*)x, (const unsigned char*)eg,
                                dtf, flag, nactb);
  k_mask<<<OUTSZ/256,256,0,stream>>>(eg, flag, cnt, nactb, aidx, inv, outp);
  k_prepw<<<(82720+255)/256,256,0,stream>>>(w1,w2,qw,kw,vw,qb0,kb0,vb0,ow,ob,fw,fb,tw,tb,
                                            b1,b2,dtf,
                                            W1t,W2t,Wqt,Wkt,Wvt,Wct,qbf,kbf,vbf,bcf,b1f,b2f);
  k_edges<<<TM*64/256,256,0,stream>>>(A, dtf, inv, cnt, edges);
  k_gemm_x<<<TM/64,256,0,stream>>>(x, dtf, nactb, aidx, W1t, g);
  k_gather<<<TM/4,256,0,stream>>>(g, edges, cnt, nactb, b1f, h);
  k_gemm_h<<<TM/64,256,0,stream>>>(h, W2t, g, nactb);
  k_gather<<<TM/4,256,0,stream>>>(g, edges, cnt, nactb, b2f, h);
  k_gemm_qkv<<<dim3(TM/64,1,3),256,0,stream>>>(h, Wqt,Wkt,Wvt, qbf,kbf,vbf, Qb,Kb,Vtc, nactb);
  k_attn<<<dim3(MM/64,TT),256,0,stream>>>(Qb, Kb, Vtc, nactb, aidx, Wct, bcf, outp);
}